// Round 2
// baseline (1227.741 us; speedup 1.0000x reference)
//
#include <hip/hip_runtime.h>
#include <hip/hip_bf16.h>
#include <math.h>

// ---------------- problem constants ----------------
#define BATCH   32
#define LSEQ    512
#define ENC_IN  8
#define MARKD   4
#define DMODEL  512
#define DSTATE  16
#define DINNER  1024
#define DTRANK  32
#define PREDLEN 96
#define MROWS   (BATCH * LSEQ)          // 16384
#define TSTART  (LSEQ - PREDLEN)        // 416

// ---------------- workspace layout (float units) ----------------
// total 29,541,888 floats = 112.7 MiB  (previous 304.5 MiB likely overflowed ws)
#define OFF_XN    ((size_t)0)            // 131072
#define OFF_MEAN  ((size_t)131072)       // 256
#define OFF_STD   ((size_t)131328)       // 256
#define OFF_WF    ((size_t)131584)       // 1024
#define OFF_PACC  ((size_t)132608)       // 32*96*16 = 49152
#define OFF_X     ((size_t)181760)       // 8388608   (fp32 16384x512)
#define OFF_XDBL  ((size_t)8570368)      // 1048576   (fp32 16384x64)
#define OFF_GS    ((size_t)9618944)      // 3145728   (fp32 32x96x1024, silu(z))
#define OFF_XI    ((size_t)12764672)     // 8388608 floats = 16777216 bf16 (16384x1024)
#define OFF_U     ((size_t)21153280)     // 8388608 floats = 16777216 bf16 (16384x1024)
// end: 29541888

static __device__ __forceinline__ float b2f(unsigned short h) {
    union { float f; unsigned u; } v; v.u = ((unsigned)h) << 16; return v.f;
}
static __device__ __forceinline__ unsigned short f2b(float f) {
    __hip_bfloat16 h = __float2bfloat16(f);   // RNE
    union { __hip_bfloat16 b; unsigned short s; } v; v.b = h; return v.s;
}

// ============ Kernel A: per-(b,c) mean/std + normalize ============
__global__ __launch_bounds__(64) void k_norm(const float* __restrict__ xe,
                                             float* __restrict__ xn,
                                             float* __restrict__ meanv,
                                             float* __restrict__ stdv) {
    int c = blockIdx.x;           // 0..7
    int b = blockIdx.y;           // 0..31
    int lane = threadIdx.x;       // 0..63
    const float* p = xe + ((size_t)b * LSEQ) * ENC_IN + c;
    float vals[8];
    float s = 0.f, s2 = 0.f;
#pragma unroll
    for (int i = 0; i < 8; ++i) {
        float v = p[(size_t)(lane + i * 64) * ENC_IN];
        vals[i] = v; s += v; s2 += v * v;
    }
#pragma unroll
    for (int off = 32; off; off >>= 1) {
        s  += __shfl_xor(s,  off);
        s2 += __shfl_xor(s2, off);
    }
    float mean = s * (1.f / LSEQ);
    float var  = s2 * (1.f / LSEQ) - mean * mean;
    float sd   = sqrtf(var + 1e-5f);
    float rstd = 1.f / sd;
    if (lane == 0) { meanv[b * ENC_IN + c] = mean; stdv[b * ENC_IN + c] = sd; }
#pragma unroll
    for (int i = 0; i < 8; ++i)
        xn[((size_t)b * LSEQ + lane + i * 64) * ENC_IN + c] = (vals[i] - mean) * rstd;
}

// ============ Kernel B: x = token_conv(xn) + temporal + pos_emb ============
__global__ __launch_bounds__(256) void k_build_x(const float* __restrict__ xn,
                                                 const float* __restrict__ xmark,
                                                 const float* __restrict__ convw,
                                                 const float* __restrict__ tempw,
                                                 float* __restrict__ x) {
    int d = blockIdx.x * 256 + threadIdx.x;   // 0..511
    int l = blockIdx.y;
    int b = blockIdx.z;
    int lm = (l + LSEQ - 1) & (LSEQ - 1);     // circular pad per reference
    int lp = (l + 1) & (LSEQ - 1);
    const float* r0 = xn + ((size_t)b * LSEQ + lm) * ENC_IN;
    const float* r1 = xn + ((size_t)b * LSEQ + l ) * ENC_IN;
    const float* r2 = xn + ((size_t)b * LSEQ + lp) * ENC_IN;
    const float* w  = convw + (size_t)d * (ENC_IN * 3);   // (512,8,3)
    float acc = 0.f;
#pragma unroll
    for (int i = 0; i < ENC_IN; ++i)
        acc += r0[i] * w[i * 3 + 0] + r1[i] * w[i * 3 + 1] + r2[i] * w[i * 3 + 2];
    const float* tw = tempw + (size_t)d * MARKD;
    const float* xm = xmark + ((size_t)b * LSEQ + l) * MARKD;
    acc += xm[0] * tw[0] + xm[1] * tw[1] + xm[2] * tw[2] + xm[3] * tw[3];
    float freq = __expf(-(float)(d & ~1) * (9.210340371976184f / (float)DMODEL));
    float ang  = (float)l * freq;
    acc += (d & 1) ? cosf(ang) : sinf(ang);
    x[((size_t)b * LSEQ + l) * DMODEL + d] = acc;
}

// ============ Kernel C: in_proj GEMM ============
// xz[m,n] = sum_k x[m,k]*W[n,k].  M=16384, N=2048, K=512.
// n<1024  -> xi, stored bf16 (full).
// n>=1024 -> z; only rows with t>=TSTART kept, stored as silu(z) fp32.
#define G1_BM 128
#define G1_BN 128
#define G1_BK 16
#define G1_PAD 4
__global__ __launch_bounds__(256) void k_gemm_inproj(const float* __restrict__ A,
                                                     const float* __restrict__ W,
                                                     __hip_bfloat16* __restrict__ xi,
                                                     float* __restrict__ gs) {
    const int K = 512;
    int m0 = blockIdx.y * G1_BM;
    int n0 = blockIdx.x * G1_BN;
    // skip z-side tiles whose whole t-range is below TSTART
    if (n0 >= DINNER && ((m0 & (LSEQ - 1)) + G1_BM) <= TSTART) return;

    __shared__ float As[G1_BK][G1_BM + G1_PAD];
    __shared__ float Bs[G1_BK][G1_BN + G1_PAD];
    int tid = threadIdx.x;
    int tm = tid & 15;     // row group
    int tn = tid >> 4;     // col group
    float acc[8][8] = {};
    for (int k0 = 0; k0 < K; k0 += G1_BK) {
#pragma unroll
        for (int half = 0; half < 2; ++half) {
            int f   = tid + half * 256;    // 0..511
            int row = f >> 2;              // 0..127
            int kq  = (f & 3) << 2;        // 0,4,8,12
            float4 va = *(const float4*)(A + (size_t)(m0 + row) * K + k0 + kq);
            As[kq + 0][row] = va.x; As[kq + 1][row] = va.y;
            As[kq + 2][row] = va.z; As[kq + 3][row] = va.w;
            float4 vb = *(const float4*)(W + (size_t)(n0 + row) * K + k0 + kq);
            Bs[kq + 0][row] = vb.x; Bs[kq + 1][row] = vb.y;
            Bs[kq + 2][row] = vb.z; Bs[kq + 3][row] = vb.w;
        }
        __syncthreads();
#pragma unroll
        for (int k = 0; k < G1_BK; ++k) {
            float a[8], bb[8];
            float4 a0 = *(const float4*)&As[k][tm * 8];
            float4 a1 = *(const float4*)&As[k][tm * 8 + 4];
            a[0]=a0.x; a[1]=a0.y; a[2]=a0.z; a[3]=a0.w;
            a[4]=a1.x; a[5]=a1.y; a[6]=a1.z; a[7]=a1.w;
            float4 b0 = *(const float4*)&Bs[k][tn * 8];
            float4 b1 = *(const float4*)&Bs[k][tn * 8 + 4];
            bb[0]=b0.x; bb[1]=b0.y; bb[2]=b0.z; bb[3]=b0.w;
            bb[4]=b1.x; bb[5]=b1.y; bb[6]=b1.z; bb[7]=b1.w;
#pragma unroll
            for (int i = 0; i < 8; ++i)
#pragma unroll
                for (int j = 0; j < 8; ++j)
                    acc[i][j] += a[i] * bb[j];
        }
        __syncthreads();
    }
    if (n0 < DINNER) {
        // xi side: store bf16
#pragma unroll
        for (int i = 0; i < 8; ++i) {
            int m = m0 + tm * 8 + i;
            unsigned short us[8];
#pragma unroll
            for (int j = 0; j < 8; ++j) us[j] = f2b(acc[i][j]);
            *(uint4*)(xi + (size_t)m * DINNER + n0 + tn * 8) = *(const uint4*)us;
        }
    } else {
        int nz = n0 - DINNER;
#pragma unroll
        for (int i = 0; i < 8; ++i) {
            int m = m0 + tm * 8 + i;
            int t = m & (LSEQ - 1);
            if (t < TSTART) continue;
            int b = m >> 9;
            float v[8];
#pragma unroll
            for (int j = 0; j < 8; ++j) {
                float s = 1.f / (1.f + __expf(-acc[i][j]));
                v[j] = acc[i][j] * s;
            }
            float* gp = gs + ((size_t)b * PREDLEN + (t - TSTART)) * DINNER + nz + tn * 8;
            *(float4*)gp       = make_float4(v[0], v[1], v[2], v[3]);
            *(float4*)(gp + 4) = make_float4(v[4], v[5], v[6], v[7]);
        }
    }
}

// ============ Kernel D: causal depthwise conv (k=4) + bias + silu ============
__global__ __launch_bounds__(256) void k_dwconv_silu(const __hip_bfloat16* __restrict__ xi,
                                                     const float* __restrict__ cw,
                                                     const float* __restrict__ cb,
                                                     __hip_bfloat16* __restrict__ u) {
    int d = blockIdx.x * 256 + threadIdx.x;   // 0..1023
    int l = blockIdx.y;
    int b = blockIdx.z;
    const __hip_bfloat16* base = xi + ((size_t)b * LSEQ) * DINNER + d;
    const float* w = cw + (size_t)d * 4;
    float acc = cb[d];
#pragma unroll
    for (int k = 0; k < 4; ++k) {
        int src = l - 3 + k;
        if (src >= 0) acc += __bfloat162float(base[(size_t)src * DINNER]) * w[k];
    }
    float sig = 1.f / (1.f + __expf(-acc));
    float uv = acc * sig;
    u[((size_t)b * LSEQ + l) * DINNER + d] = __float2bfloat16(uv);
}

// ============ Kernel E: x_proj GEMM  xdbl[m,j] = sum_k u[m,k]*XP[j,k] ============
// M=16384, N=64, K=1024.  A is bf16.  64x64 tile, BK=16, 256 thr, 4x4 micro.
#define G2_BM 64
#define G2_BK 16
#define G2_PAD 4
__global__ __launch_bounds__(256) void k_gemm_xproj(const __hip_bfloat16* __restrict__ A,
                                                    const float* __restrict__ W,
                                                    float* __restrict__ C) {
    __shared__ float As[G2_BK][G2_BM + G2_PAD];
    __shared__ float Bs[G2_BK][G2_BM + G2_PAD];
    const int K = 1024;
    int tid = threadIdx.x;
    int m0 = blockIdx.x * G2_BM;
    int tm = tid & 15;
    int tn = tid >> 4;
    float acc[4][4] = {};
    for (int k0 = 0; k0 < K; k0 += G2_BK) {
        {
            int f   = tid;               // 64 rows x 4 bf16 chunks
            int row = f >> 2;
            int kq  = (f & 3) << 2;
            uint2 va = *(const uint2*)(A + (size_t)(m0 + row) * K + k0 + kq);
            As[kq + 0][row] = b2f((unsigned short)(va.x & 0xffff));
            As[kq + 1][row] = b2f((unsigned short)(va.x >> 16));
            As[kq + 2][row] = b2f((unsigned short)(va.y & 0xffff));
            As[kq + 3][row] = b2f((unsigned short)(va.y >> 16));
            float4 vb = *(const float4*)(W + (size_t)row * K + k0 + kq);
            Bs[kq + 0][row] = vb.x; Bs[kq + 1][row] = vb.y;
            Bs[kq + 2][row] = vb.z; Bs[kq + 3][row] = vb.w;
        }
        __syncthreads();
#pragma unroll
        for (int k = 0; k < G2_BK; ++k) {
            float a[4], bb[4];
            float4 a0 = *(const float4*)&As[k][tm * 4];
            a[0]=a0.x; a[1]=a0.y; a[2]=a0.z; a[3]=a0.w;
            float4 b0 = *(const float4*)&Bs[k][tn * 4];
            bb[0]=b0.x; bb[1]=b0.y; bb[2]=b0.z; bb[3]=b0.w;
#pragma unroll
            for (int i = 0; i < 4; ++i)
#pragma unroll
                for (int j = 0; j < 4; ++j)
                    acc[i][j] += a[i] * bb[j];
        }
        __syncthreads();
    }
#pragma unroll
    for (int i = 0; i < 4; ++i) {
        float* cp = C + (size_t)(m0 + tm * 4 + i) * 64 + tn * 4;
        *(float4*)cp = make_float4(acc[i][0], acc[i][1], acc[i][2], acc[i][3]);
    }
}

// ============ Kernel G: selective scan (dt_proj fused, output dot fused) ============
// one thread per (b,d); h[16] in regs; dt_in/B/C wave-uniform loads.
__global__ __launch_bounds__(64) void k_scan(const __hip_bfloat16* __restrict__ ubf,
                                             const float* __restrict__ xdbl,
                                             const float* __restrict__ A_log,
                                             const float* __restrict__ dpw,
                                             const float* __restrict__ dpb,
                                             const float* __restrict__ Dvec,
                                             const float* __restrict__ wf,
                                             const float* __restrict__ gs,
                                             float* __restrict__ pacc) {
    int b = blockIdx.y;
    int lane = threadIdx.x;
    int d = blockIdx.x * 64 + lane;
    float A[DSTATE], h[DSTATE], wdt[DTRANK];
#pragma unroll
    for (int s = 0; s < DSTATE; s += 4) {
        float4 v = *(const float4*)(A_log + (size_t)d * DSTATE + s);
        A[s] = -__expf(v.x); A[s + 1] = -__expf(v.y);
        A[s + 2] = -__expf(v.z); A[s + 3] = -__expf(v.w);
    }
#pragma unroll
    for (int s = 0; s < DSTATE; ++s) h[s] = 0.f;
#pragma unroll
    for (int r = 0; r < DTRANK; r += 4) {
        float4 v = *(const float4*)(dpw + (size_t)d * DTRANK + r);
        wdt[r] = v.x; wdt[r + 1] = v.y; wdt[r + 2] = v.z; wdt[r + 3] = v.w;
    }
    float dpb_d = dpb[d];
    float Dd    = Dvec[d];
    float wfd   = wf[d];
    const __hip_bfloat16* up = ubf + (size_t)b * LSEQ * DINNER + d;
    const float* xdp = xdbl + (size_t)b * LSEQ * 64;
    for (int t = 0; t < LSEQ; ++t) {
        float u_ = __bfloat162float(up[(size_t)t * DINNER]);
        const float* xr = xdp + (size_t)t * 64;
        float dtp = dpb_d;
#pragma unroll
        for (int r = 0; r < DTRANK; r += 4) {
            float4 q = *(const float4*)(xr + r);
            dtp += q.x * wdt[r] + q.y * wdt[r + 1] + q.z * wdt[r + 2] + q.w * wdt[r + 3];
        }
        float dt_ = (dtp > 20.f) ? dtp : log1pf(__expf(dtp));
        float du = dt_ * u_;
        float4 Bq0 = *(const float4*)(xr + 32);
        float4 Bq1 = *(const float4*)(xr + 36);
        float4 Bq2 = *(const float4*)(xr + 40);
        float4 Bq3 = *(const float4*)(xr + 44);
        float4 Cq0 = *(const float4*)(xr + 48);
        float4 Cq1 = *(const float4*)(xr + 52);
        float4 Cq2 = *(const float4*)(xr + 56);
        float4 Cq3 = *(const float4*)(xr + 60);
        float Bv[16] = {Bq0.x,Bq0.y,Bq0.z,Bq0.w, Bq1.x,Bq1.y,Bq1.z,Bq1.w,
                        Bq2.x,Bq2.y,Bq2.z,Bq2.w, Bq3.x,Bq3.y,Bq3.z,Bq3.w};
        float Cv[16] = {Cq0.x,Cq0.y,Cq0.z,Cq0.w, Cq1.x,Cq1.y,Cq1.z,Cq1.w,
                        Cq2.x,Cq2.y,Cq2.z,Cq2.w, Cq3.x,Cq3.y,Cq3.z,Cq3.w};
        float y = 0.f;
#pragma unroll
        for (int s = 0; s < DSTATE; ++s) {
            h[s] = __expf(dt_ * A[s]) * h[s] + du * Bv[s];
            y += h[s] * Cv[s];
        }
        if (t >= TSTART) {
            int tl = t - TSTART;
            float g = gs[((size_t)b * PREDLEN + tl) * DINNER + d];
            float c = (y + u_ * Dd) * g * wfd;
#pragma unroll
            for (int off = 32; off; off >>= 1) c += __shfl_xor(c, off);
            if (lane == 0) pacc[((size_t)b * PREDLEN + tl) * 16 + blockIdx.x] = c;
        }
    }
}

// ============ Kernel W: w_fused[i] = sum_d out_proj_w[d,i]*out_w[d] ============
__global__ __launch_bounds__(256) void k_fusew(const float* __restrict__ opw,
                                               const float* __restrict__ ow,
                                               float* __restrict__ wf) {
    int i = blockIdx.x * 256 + threadIdx.x;
    float acc = 0.f;
    for (int dd = 0; dd < DMODEL; ++dd)
        acc += opw[(size_t)dd * DINNER + i] * ow[dd];
    wf[i] = acc;
}

// ============ Kernel H: reduce partials + de-normalize ============
__global__ __launch_bounds__(256) void k_final(const float* __restrict__ pacc,
                                               const float* __restrict__ meanv,
                                               const float* __restrict__ stdv,
                                               float* __restrict__ out) {
    int idx = blockIdx.x * 256 + threadIdx.x;   // 0..3071
    int b  = idx / PREDLEN;
    float tot = 0.f;
#pragma unroll
    for (int k = 0; k < 16; ++k) tot += pacc[(size_t)idx * 16 + k];
    out[idx] = tot * stdv[b * ENC_IN] + meanv[b * ENC_IN];
}

// ---------------- launch ----------------
extern "C" void kernel_launch(void* const* d_in, const int* in_sizes, int n_in,
                              void* d_out, int out_size, void* d_ws, size_t ws_size,
                              hipStream_t stream) {
    const float* x_enc     = (const float*)d_in[0];
    const float* x_mark    = (const float*)d_in[1];
    const float* conv_w    = (const float*)d_in[2];
    const float* temp_w    = (const float*)d_in[3];
    const float* in_proj_w = (const float*)d_in[4];
    const float* conv1d_w  = (const float*)d_in[5];
    const float* conv1d_b  = (const float*)d_in[6];
    const float* x_proj_w  = (const float*)d_in[7];
    const float* dt_proj_w = (const float*)d_in[8];
    const float* dt_proj_b = (const float*)d_in[9];
    const float* A_log     = (const float*)d_in[10];
    const float* Dvec      = (const float*)d_in[11];
    const float* out_proj_w= (const float*)d_in[12];
    const float* out_w     = (const float*)d_in[13];
    float* ws  = (float*)d_ws;
    float* out = (float*)d_out;

    float* xn    = ws + OFF_XN;
    float* meanv = ws + OFF_MEAN;
    float* stdv  = ws + OFF_STD;
    float* wf    = ws + OFF_WF;
    float* pacc  = ws + OFF_PACC;
    float* x     = ws + OFF_X;
    float* xdbl  = ws + OFF_XDBL;
    float* gs    = ws + OFF_GS;
    __hip_bfloat16* xi = (__hip_bfloat16*)(ws + OFF_XI);
    __hip_bfloat16* u  = (__hip_bfloat16*)(ws + OFF_U);

    k_norm<<<dim3(ENC_IN, BATCH), 64, 0, stream>>>(x_enc, xn, meanv, stdv);
    k_fusew<<<dim3(DINNER / 256), 256, 0, stream>>>(out_proj_w, out_w, wf);
    k_build_x<<<dim3(DMODEL / 256, LSEQ, BATCH), 256, 0, stream>>>(xn, x_mark, conv_w, temp_w, x);
    k_gemm_inproj<<<dim3(2048 / G1_BN, MROWS / G1_BM), 256, 0, stream>>>(x, in_proj_w, xi, gs);
    k_dwconv_silu<<<dim3(DINNER / 256, LSEQ, BATCH), 256, 0, stream>>>(xi, conv1d_w, conv1d_b, u);
    k_gemm_xproj<<<dim3(MROWS / G2_BM), 256, 0, stream>>>(u, x_proj_w, xdbl);
    k_scan<<<dim3(DINNER / 64, BATCH), 64, 0, stream>>>(u, xdbl, A_log, dt_proj_w, dt_proj_b,
                                                        Dvec, wf, gs, pacc);
    k_final<<<dim3((BATCH * PREDLEN) / 256), 256, 0, stream>>>(pacc, meanv, stdv, out);
}

// Round 3
// 664.644 us; speedup vs baseline: 1.8472x; 1.8472x over previous
//
#include <hip/hip_runtime.h>
#include <hip/hip_bf16.h>
#include <math.h>

// ---------------- problem constants ----------------
#define BATCH   32
#define LSEQ    512
#define ENC_IN  8
#define MARKD   4
#define DMODEL  512
#define DSTATE  16
#define DINNER  1024
#define DTRANK  32
#define PREDLEN 96
#define MROWS   (BATCH * LSEQ)          // 16384
#define TSTART  (LSEQ - PREDLEN)        // 416

// ---------------- workspace layout (float units), total 101.5 MiB ----------------
#define OFF_XN    ((size_t)0)            // 131072
#define OFF_MEAN  ((size_t)131072)       // 256
#define OFF_STD   ((size_t)131328)       // 256
#define OFF_WF    ((size_t)131584)       // 1024
#define OFF_PACC  ((size_t)132608)       // 32*96*256 = 786432
#define OFF_XB    ((size_t)919040)       // 16384x512 bf16 = 4194304 f
#define OFF_WB    ((size_t)5113344)      // 2048x512 bf16 = 524288 f
#define OFF_XDBL  ((size_t)5637632)      // 16384x64 fp32 = 1048576 f
#define OFF_GS    ((size_t)6686208)      // 32x96x1024 fp32 = 3145728 f
#define OFF_XI    ((size_t)9831936)      // 16384x1024 bf16 = 8388608 f (dt overlays after conv)
#define OFF_U     ((size_t)18220544)     // 16384x1024 bf16 = 8388608 f
#define OFF_DT    OFF_XI                 // dt reuses xi space (xi dead after dwconv)
// end: 26609152 floats

typedef __bf16 bf16_8 __attribute__((ext_vector_type(8)));
typedef float  f32x4  __attribute__((ext_vector_type(4)));

static __device__ __forceinline__ float b2f(unsigned short h) {
    union { float f; unsigned u; } v; v.u = ((unsigned)h) << 16; return v.f;
}
static __device__ __forceinline__ unsigned short f2b(float f) {
    __hip_bfloat16 h = __float2bfloat16(f);   // RNE
    union { __hip_bfloat16 b; unsigned short s; } v; v.b = h; return v.s;
}

// ============ Kernel A: per-(b,c) mean/std + normalize ============
__global__ __launch_bounds__(64) void k_norm(const float* __restrict__ xe,
                                             float* __restrict__ xn,
                                             float* __restrict__ meanv,
                                             float* __restrict__ stdv) {
    int c = blockIdx.x;           // 0..7
    int b = blockIdx.y;           // 0..31
    int lane = threadIdx.x;       // 0..63
    const float* p = xe + ((size_t)b * LSEQ) * ENC_IN + c;
    float vals[8];
    float s = 0.f, s2 = 0.f;
#pragma unroll
    for (int i = 0; i < 8; ++i) {
        float v = p[(size_t)(lane + i * 64) * ENC_IN];
        vals[i] = v; s += v; s2 += v * v;
    }
#pragma unroll
    for (int off = 32; off; off >>= 1) {
        s  += __shfl_xor(s,  off);
        s2 += __shfl_xor(s2, off);
    }
    float mean = s * (1.f / LSEQ);
    float var  = s2 * (1.f / LSEQ) - mean * mean;
    float sd   = sqrtf(var + 1e-5f);
    float rstd = 1.f / sd;
    if (lane == 0) { meanv[b * ENC_IN + c] = mean; stdv[b * ENC_IN + c] = sd; }
#pragma unroll
    for (int i = 0; i < 8; ++i)
        xn[((size_t)b * LSEQ + lane + i * 64) * ENC_IN + c] = (vals[i] - mean) * rstd;
}

// ============ Kernel B: x = token_conv(xn) + temporal + pos_emb  (bf16 out) ============
__global__ __launch_bounds__(256) void k_build_x(const float* __restrict__ xn,
                                                 const float* __restrict__ xmark,
                                                 const float* __restrict__ convw,
                                                 const float* __restrict__ tempw,
                                                 unsigned short* __restrict__ xb) {
    int d = blockIdx.x * 256 + threadIdx.x;   // 0..511
    int l = blockIdx.y;
    int b = blockIdx.z;
    int lm = (l + LSEQ - 1) & (LSEQ - 1);     // circular pad per reference
    int lp = (l + 1) & (LSEQ - 1);
    const float* r0 = xn + ((size_t)b * LSEQ + lm) * ENC_IN;
    const float* r1 = xn + ((size_t)b * LSEQ + l ) * ENC_IN;
    const float* r2 = xn + ((size_t)b * LSEQ + lp) * ENC_IN;
    const float* w  = convw + (size_t)d * (ENC_IN * 3);   // (512,8,3)
    float acc = 0.f;
#pragma unroll
    for (int i = 0; i < ENC_IN; ++i)
        acc += r0[i] * w[i * 3 + 0] + r1[i] * w[i * 3 + 1] + r2[i] * w[i * 3 + 2];
    const float* tw = tempw + (size_t)d * MARKD;
    const float* xm = xmark + ((size_t)b * LSEQ + l) * MARKD;
    acc += xm[0] * tw[0] + xm[1] * tw[1] + xm[2] * tw[2] + xm[3] * tw[3];
    float freq = __expf(-(float)(d & ~1) * (9.210340371976184f / (float)DMODEL));
    float ang  = (float)l * freq;
    acc += (d & 1) ? cosf(ang) : sinf(ang);
    xb[((size_t)b * LSEQ + l) * DMODEL + d] = f2b(acc);
}

// ============ Kernel W2B: in_proj_w fp32 -> bf16 ============
__global__ __launch_bounds__(256) void k_w2b(const float* __restrict__ w,
                                             unsigned short* __restrict__ wb) {
    int i = (blockIdx.x * 256 + threadIdx.x) * 4;
    float4 v = *(const float4*)(w + i);
    ushort4 o;
    o.x = f2b(v.x); o.y = f2b(v.y); o.z = f2b(v.z); o.w = f2b(v.w);
    *(ushort4*)(wb + i) = o;
}

// ============ Kernel C: in_proj GEMM via bf16 MFMA ============
// xz[m,n] = sum_k x[m,k]*W[n,k].  M=16384, N=2048, K=512.
// 128x128 tile, BK=32, 4 waves each 64x64 (4x4 MFMA 16x16x32).
// LDS stored in fragment order: chunk[im][lane] = 8 bf16 at row im*16+(lane&15),
// cols (lane>>4)*8..+7  -> conflict-free b128 read AND write.
// n<1024 -> xi bf16.  n>=1024 -> z: only m-tiles with (m0&511)==384 kept; silu -> gs fp32.
__global__ __launch_bounds__(256) void k_gemm_inproj(const unsigned short* __restrict__ xb,
                                                     const unsigned short* __restrict__ wb,
                                                     unsigned short* __restrict__ xi,
                                                     float* __restrict__ gs) {
    int n0 = blockIdx.x * 128;
    int m0 = blockIdx.y * 128;
    if (n0 >= DINNER && (m0 & (LSEQ - 1)) != 384) return;   // z-tiles below TSTART window

    __shared__ uint4 As4[512];   // 8KB: [im(8)][lane(64)] 16B chunks
    __shared__ uint4 Bs4[512];
    int tid  = threadIdx.x;
    int lane = tid & 63;
    int w    = tid >> 6;          // wave 0..3
    int wm   = (w & 1) * 64;      // wave row offset
    int wn   = (w >> 1) * 64;     // wave col offset
    f32x4 acc[4][4] = {};

    for (int k0 = 0; k0 < DMODEL; k0 += 32) {
#pragma unroll
        for (int hh = 0; hh < 2; ++hh) {
            int c  = tid + hh * 256;
            int im = c >> 6;
            int lc = c & 63;
            int r  = im * 16 + (lc & 15);
            int kq = lc >> 4;
            As4[c] = *(const uint4*)(xb + (size_t)(m0 + r) * DMODEL + k0 + kq * 8);
            Bs4[c] = *(const uint4*)(wb + (size_t)(n0 + r) * DMODEL + k0 + kq * 8);
        }
        __syncthreads();
        bf16_8 af[4], bf[4];
#pragma unroll
        for (int i = 0; i < 4; ++i) {
            af[i] = ((const bf16_8*)As4)[((wm >> 4) + i) * 64 + lane];
            bf[i] = ((const bf16_8*)Bs4)[((wn >> 4) + i) * 64 + lane];
        }
#pragma unroll
        for (int i = 0; i < 4; ++i)
#pragma unroll
            for (int j = 0; j < 4; ++j)
                acc[i][j] = __builtin_amdgcn_mfma_f32_16x16x32_bf16(af[i], bf[j], acc[i][j], 0, 0, 0);
        __syncthreads();
    }

    // epilogue: C/D layout col=lane&15, row=(lane>>4)*4+reg
    int col  = lane & 15;
    int quad = lane >> 4;
    if (n0 < DINNER) {
#pragma unroll
        for (int i = 0; i < 4; ++i) {
#pragma unroll
            for (int j = 0; j < 4; ++j) {
                int m = m0 + wm + i * 16 + quad * 4;
                int n = n0 + wn + j * 16 + col;
#pragma unroll
                for (int r = 0; r < 4; ++r)
                    xi[(size_t)(m + r) * DINNER + n] = f2b(acc[i][j][r]);
            }
        }
    } else {
#pragma unroll
        for (int i = 0; i < 4; ++i) {
#pragma unroll
            for (int j = 0; j < 4; ++j) {
                int nz = n0 - DINNER + wn + j * 16 + col;
#pragma unroll
                for (int r = 0; r < 4; ++r) {
                    int m = m0 + wm + i * 16 + quad * 4 + r;
                    int t = m & (LSEQ - 1);
                    if (t < TSTART) continue;
                    int b = m >> 9;
                    float v = acc[i][j][r];
                    float g = v / (1.f + __expf(-v));
                    gs[((size_t)b * PREDLEN + (t - TSTART)) * DINNER + nz] = g;
                }
            }
        }
    }
}

// ============ Kernel D: causal depthwise conv (k=4) + bias + silu ============
__global__ __launch_bounds__(256) void k_dwconv_silu(const unsigned short* __restrict__ xi,
                                                     const float* __restrict__ cw,
                                                     const float* __restrict__ cb,
                                                     unsigned short* __restrict__ u) {
    int d = blockIdx.x * 256 + threadIdx.x;   // 0..1023
    int l = blockIdx.y;
    int b = blockIdx.z;
    const unsigned short* base = xi + ((size_t)b * LSEQ) * DINNER + d;
    const float* w = cw + (size_t)d * 4;
    float acc = cb[d];
#pragma unroll
    for (int k = 0; k < 4; ++k) {
        int src = l - 3 + k;
        if (src >= 0) acc += b2f(base[(size_t)src * DINNER]) * w[k];
    }
    float sig = 1.f / (1.f + __expf(-acc));
    u[((size_t)b * LSEQ + l) * DINNER + d] = f2b(acc * sig);
}

// ============ Kernel E: x_proj GEMM  xdbl[m,j] = sum_k u[m,k]*XP[j,k] ============
#define G2_BM 64
#define G2_BK 16
#define G2_PAD 4
__global__ __launch_bounds__(256) void k_gemm_xproj(const unsigned short* __restrict__ A,
                                                    const float* __restrict__ W,
                                                    float* __restrict__ C) {
    __shared__ float As[G2_BK][G2_BM + G2_PAD];
    __shared__ float Bs[G2_BK][G2_BM + G2_PAD];
    const int K = 1024;
    int tid = threadIdx.x;
    int m0 = blockIdx.x * G2_BM;
    int tm = tid & 15;
    int tn = tid >> 4;
    float acc[4][4] = {};
    for (int k0 = 0; k0 < K; k0 += G2_BK) {
        {
            int f   = tid;
            int row = f >> 2;
            int kq  = (f & 3) << 2;
            uint2 va = *(const uint2*)(A + (size_t)(m0 + row) * K + k0 + kq);
            As[kq + 0][row] = b2f((unsigned short)(va.x & 0xffff));
            As[kq + 1][row] = b2f((unsigned short)(va.x >> 16));
            As[kq + 2][row] = b2f((unsigned short)(va.y & 0xffff));
            As[kq + 3][row] = b2f((unsigned short)(va.y >> 16));
            float4 vb = *(const float4*)(W + (size_t)row * K + k0 + kq);
            Bs[kq + 0][row] = vb.x; Bs[kq + 1][row] = vb.y;
            Bs[kq + 2][row] = vb.z; Bs[kq + 3][row] = vb.w;
        }
        __syncthreads();
#pragma unroll
        for (int k = 0; k < G2_BK; ++k) {
            float a[4], bb[4];
            float4 a0 = *(const float4*)&As[k][tm * 4];
            a[0]=a0.x; a[1]=a0.y; a[2]=a0.z; a[3]=a0.w;
            float4 b0 = *(const float4*)&Bs[k][tn * 4];
            bb[0]=b0.x; bb[1]=b0.y; bb[2]=b0.z; bb[3]=b0.w;
#pragma unroll
            for (int i = 0; i < 4; ++i)
#pragma unroll
                for (int j = 0; j < 4; ++j)
                    acc[i][j] += a[i] * bb[j];
        }
        __syncthreads();
    }
#pragma unroll
    for (int i = 0; i < 4; ++i) {
        float* cp = C + (size_t)(m0 + tm * 4 + i) * 64 + tn * 4;
        *(float4*)cp = make_float4(acc[i][0], acc[i][1], acc[i][2], acc[i][3]);
    }
}

// ============ Kernel F: dt = softplus(dt_in @ dt_proj_w.T + b), bf16 out ============
__global__ __launch_bounds__(256) void k_dtproj(const float* __restrict__ xdbl,
                                                const float* __restrict__ dpw,
                                                const float* __restrict__ dpb,
                                                unsigned short* __restrict__ dtv) {
    __shared__ float xs[64][32];
    int n  = blockIdx.x * 256 + threadIdx.x;   // 0..1023
    int m0 = blockIdx.y * 64;
    for (int f = threadIdx.x; f < 512; f += 256) {
        int row = f >> 3;
        int c   = (f & 7) << 2;
        *(float4*)&xs[row][c] = *(const float4*)(xdbl + (size_t)(m0 + row) * 64 + c);
    }
    __syncthreads();
    float w[32];
#pragma unroll
    for (int r = 0; r < 32; r += 4) {
        float4 v = *(const float4*)(dpw + (size_t)n * 32 + r);
        w[r] = v.x; w[r + 1] = v.y; w[r + 2] = v.z; w[r + 3] = v.w;
    }
    float bias = dpb[n];
    for (int m = 0; m < 64; ++m) {
        float acc = bias;
#pragma unroll
        for (int r = 0; r < 32; ++r) acc += xs[m][r] * w[r];
        float sp = (acc > 20.f) ? acc : log1pf(__expf(acc));
        dtv[(size_t)(m0 + m) * DINNER + n] = f2b(sp);
    }
}

// ============ Kernel G: selective scan, state-parallel (16 lanes per (b,d)) ============
// block 256 = 4 waves; each wave: 4 d's x 16 states.  Full occupancy: 8192 waves.
__global__ __launch_bounds__(256) void k_scan2(const unsigned short* __restrict__ u,
                                               const unsigned short* __restrict__ dtv,
                                               const float* __restrict__ xdbl,
                                               const float* __restrict__ A_log,
                                               const float* __restrict__ Dvec,
                                               const float* __restrict__ wf,
                                               const float* __restrict__ gs,
                                               float* __restrict__ pacc) {
    int b    = blockIdx.y;
    int tid  = threadIdx.x;
    int s    = tid & 15;
    int dloc = tid >> 4;                 // 0..15
    int d    = blockIdx.x * 16 + dloc;
    float As  = -__expf(A_log[(size_t)d * DSTATE + s]);
    float Dd  = Dvec[d];
    float wfd = wf[d];
    float h = 0.f;
    const unsigned short* up  = u   + (size_t)b * LSEQ * DINNER + d;
    const unsigned short* dtp = dtv + (size_t)b * LSEQ * DINNER + d;
    const float* xr = xdbl + (size_t)b * LSEQ * 64;
    const float* gp = gs + (size_t)b * PREDLEN * DINNER + d;
    float* pout = pacc + ((size_t)b * PREDLEN) * 256 + blockIdx.x * 4 + (tid >> 6);
    for (int t = 0; t < LSEQ; ++t) {
        float u_  = b2f(up [(size_t)t * DINNER]);
        float dt_ = b2f(dtp[(size_t)t * DINNER]);
        float Bs  = xr[t * 64 + 32 + s];
        float Cs  = xr[t * 64 + 48 + s];
        h = __expf(dt_ * As) * h + (dt_ * u_) * Bs;
        if (t >= TSTART) {
            float y = h * Cs;
            y += __shfl_xor(y, 1); y += __shfl_xor(y, 2);
            y += __shfl_xor(y, 4); y += __shfl_xor(y, 8);
            float g = gp[(size_t)(t - TSTART) * DINNER];
            float c = (s == 0) ? (y + u_ * Dd) * g * wfd : 0.f;
            c += __shfl_xor(c, 16); c += __shfl_xor(c, 32);
            if ((tid & 63) == 0) pout[(size_t)(t - TSTART) * 256] = c;
        }
    }
}

// ============ Kernel W: w_fused[i] = sum_d out_proj_w[d,i]*out_w[d] ============
__global__ __launch_bounds__(256) void k_fusew(const float* __restrict__ opw,
                                               const float* __restrict__ ow,
                                               float* __restrict__ wfv) {
    int i = blockIdx.x * 256 + threadIdx.x;
    float acc = 0.f;
    for (int dd = 0; dd < DMODEL; ++dd)
        acc += opw[(size_t)dd * DINNER + i] * ow[dd];
    wfv[i] = acc;
}

// ============ Kernel H: reduce 256 partials + de-normalize ============
__global__ __launch_bounds__(64) void k_final(const float* __restrict__ pacc,
                                              const float* __restrict__ meanv,
                                              const float* __restrict__ stdv,
                                              float* __restrict__ out) {
    int idx  = blockIdx.x;               // 0..3071 = b*96+tl
    int lane = threadIdx.x;
    int b = idx / PREDLEN;
    float4 v = *(const float4*)(pacc + (size_t)idx * 256 + lane * 4);
    float tot = v.x + v.y + v.z + v.w;
#pragma unroll
    for (int off = 32; off; off >>= 1) tot += __shfl_xor(tot, off);
    if (lane == 0) out[idx] = tot * stdv[b * ENC_IN] + meanv[b * ENC_IN];
}

// ---------------- launch ----------------
extern "C" void kernel_launch(void* const* d_in, const int* in_sizes, int n_in,
                              void* d_out, int out_size, void* d_ws, size_t ws_size,
                              hipStream_t stream) {
    const float* x_enc     = (const float*)d_in[0];
    const float* x_mark    = (const float*)d_in[1];
    const float* conv_w    = (const float*)d_in[2];
    const float* temp_w    = (const float*)d_in[3];
    const float* in_proj_w = (const float*)d_in[4];
    const float* conv1d_w  = (const float*)d_in[5];
    const float* conv1d_b  = (const float*)d_in[6];
    const float* x_proj_w  = (const float*)d_in[7];
    const float* dt_proj_w = (const float*)d_in[8];
    const float* dt_proj_b = (const float*)d_in[9];
    const float* A_log     = (const float*)d_in[10];
    const float* Dvec      = (const float*)d_in[11];
    const float* out_proj_w= (const float*)d_in[12];
    const float* out_w     = (const float*)d_in[13];
    float* ws  = (float*)d_ws;
    float* out = (float*)d_out;

    float* xn    = ws + OFF_XN;
    float* meanv = ws + OFF_MEAN;
    float* stdv  = ws + OFF_STD;
    float* wfv   = ws + OFF_WF;
    float* pacc  = ws + OFF_PACC;
    float* xdbl  = ws + OFF_XDBL;
    float* gs    = ws + OFF_GS;
    unsigned short* xb  = (unsigned short*)(ws + OFF_XB);
    unsigned short* wb  = (unsigned short*)(ws + OFF_WB);
    unsigned short* xi  = (unsigned short*)(ws + OFF_XI);
    unsigned short* u   = (unsigned short*)(ws + OFF_U);
    unsigned short* dtv = (unsigned short*)(ws + OFF_DT);   // overlays xi

    k_norm<<<dim3(ENC_IN, BATCH), 64, 0, stream>>>(x_enc, xn, meanv, stdv);
    k_fusew<<<dim3(DINNER / 256), 256, 0, stream>>>(out_proj_w, out_w, wfv);
    k_build_x<<<dim3(DMODEL / 256, LSEQ, BATCH), 256, 0, stream>>>(xn, x_mark, conv_w, temp_w, xb);
    k_w2b<<<dim3((2 * DINNER * DMODEL) / 1024), 256, 0, stream>>>(in_proj_w, wb);
    k_gemm_inproj<<<dim3(16, 128), 256, 0, stream>>>(xb, wb, xi, gs);
    k_dwconv_silu<<<dim3(DINNER / 256, LSEQ, BATCH), 256, 0, stream>>>(xi, conv1d_w, conv1d_b, u);
    k_gemm_xproj<<<dim3(MROWS / G2_BM), 256, 0, stream>>>(u, x_proj_w, xdbl);
    k_dtproj<<<dim3(DINNER / 256, MROWS / 64), 256, 0, stream>>>(xdbl, dt_proj_w, dt_proj_b, dtv);
    k_scan2<<<dim3(DINNER / 16, BATCH), 256, 0, stream>>>(u, dtv, xdbl, A_log, Dvec, wfv, gs, pacc);
    k_final<<<dim3(BATCH * PREDLEN), 64, 0, stream>>>(pacc, meanv, stdv, out);
}

// Round 4
// 625.404 us; speedup vs baseline: 1.9631x; 1.0627x over previous
//
#include <hip/hip_runtime.h>
#include <hip/hip_bf16.h>
#include <math.h>

// ---------------- problem constants ----------------
#define BATCH   32
#define LSEQ    512
#define ENC_IN  8
#define MARKD   4
#define DMODEL  512
#define DSTATE  16
#define DINNER  1024
#define DTRANK  32
#define PREDLEN 96
#define MROWS   (BATCH * LSEQ)          // 16384
#define TSTART  (LSEQ - PREDLEN)        // 416

// ---------------- workspace layout (float units), total 101.5 MiB ----------------
#define OFF_XN    ((size_t)0)            // 131072
#define OFF_MEAN  ((size_t)131072)       // 256
#define OFF_STD   ((size_t)131328)       // 256
#define OFF_WF    ((size_t)131584)       // 1024
#define OFF_PACC  ((size_t)132608)       // 32*96*256 = 786432
#define OFF_XB    ((size_t)919040)       // 16384x512 bf16 = 4194304 f
#define OFF_WB    ((size_t)5113344)      // 2048x512 bf16 = 524288 f
#define OFF_DTIN  ((size_t)5637632)      // 16384x32 fp32 = 524288 f
#define OFF_BT    ((size_t)6161920)      // 32x16x512 fp32 = 262144 f
#define OFF_CT    ((size_t)6424064)      // 262144 f
#define OFF_GST   ((size_t)6686208)      // 32x1024x96 fp32 = 3145728 f
#define OFF_XIT   ((size_t)9831936)      // [b][d][t] bf16 = 8388608 f (dt_T overlays)
#define OFF_UT    ((size_t)18220544)     // [b][d][t] bf16 = 8388608 f
#define OFF_DTT   OFF_XIT                // dt_T reuses xi_T (dead after dwconv)
// end: 26609152 floats = 101.5 MiB

typedef __bf16 bf16_8 __attribute__((ext_vector_type(8)));
typedef float  f32x4  __attribute__((ext_vector_type(4)));

static __device__ __forceinline__ float b2f(unsigned short h) {
    union { float f; unsigned u; } v; v.u = ((unsigned)h) << 16; return v.f;
}
static __device__ __forceinline__ unsigned short f2b(float f) {
    __hip_bfloat16 h = __float2bfloat16(f);   // RNE
    union { __hip_bfloat16 b; unsigned short s; } v; v.b = h; return v.s;
}
static __device__ __forceinline__ float blo(unsigned v) {
    union { float f; unsigned u; } x; x.u = v << 16; return x.f;
}
static __device__ __forceinline__ float bhi(unsigned v) {
    union { float f; unsigned u; } x; x.u = v & 0xffff0000u; return x.f;
}

// ============ Kernel A: per-(b,c) mean/std + normalize ============
__global__ __launch_bounds__(64) void k_norm(const float* __restrict__ xe,
                                             float* __restrict__ xn,
                                             float* __restrict__ meanv,
                                             float* __restrict__ stdv) {
    int c = blockIdx.x;
    int b = blockIdx.y;
    int lane = threadIdx.x;
    const float* p = xe + ((size_t)b * LSEQ) * ENC_IN + c;
    float vals[8];
    float s = 0.f, s2 = 0.f;
#pragma unroll
    for (int i = 0; i < 8; ++i) {
        float v = p[(size_t)(lane + i * 64) * ENC_IN];
        vals[i] = v; s += v; s2 += v * v;
    }
#pragma unroll
    for (int off = 32; off; off >>= 1) {
        s  += __shfl_xor(s,  off);
        s2 += __shfl_xor(s2, off);
    }
    float mean = s * (1.f / LSEQ);
    float var  = s2 * (1.f / LSEQ) - mean * mean;
    float sd   = sqrtf(var + 1e-5f);
    float rstd = 1.f / sd;
    if (lane == 0) { meanv[b * ENC_IN + c] = mean; stdv[b * ENC_IN + c] = sd; }
#pragma unroll
    for (int i = 0; i < 8; ++i)
        xn[((size_t)b * LSEQ + lane + i * 64) * ENC_IN + c] = (vals[i] - mean) * rstd;
}

// ============ Kernel B: x = token_conv(xn) + temporal + pos_emb  (bf16 out) ============
__global__ __launch_bounds__(256) void k_build_x(const float* __restrict__ xn,
                                                 const float* __restrict__ xmark,
                                                 const float* __restrict__ convw,
                                                 const float* __restrict__ tempw,
                                                 unsigned short* __restrict__ xb) {
    int d = blockIdx.x * 256 + threadIdx.x;
    int l = blockIdx.y;
    int b = blockIdx.z;
    int lm = (l + LSEQ - 1) & (LSEQ - 1);     // circular pad per reference
    int lp = (l + 1) & (LSEQ - 1);
    const float* r0 = xn + ((size_t)b * LSEQ + lm) * ENC_IN;
    const float* r1 = xn + ((size_t)b * LSEQ + l ) * ENC_IN;
    const float* r2 = xn + ((size_t)b * LSEQ + lp) * ENC_IN;
    const float* w  = convw + (size_t)d * (ENC_IN * 3);
    float acc = 0.f;
#pragma unroll
    for (int i = 0; i < ENC_IN; ++i)
        acc += r0[i] * w[i * 3 + 0] + r1[i] * w[i * 3 + 1] + r2[i] * w[i * 3 + 2];
    const float* tw = tempw + (size_t)d * MARKD;
    const float* xm = xmark + ((size_t)b * LSEQ + l) * MARKD;
    acc += xm[0] * tw[0] + xm[1] * tw[1] + xm[2] * tw[2] + xm[3] * tw[3];
    float freq = __expf(-(float)(d & ~1) * (9.210340371976184f / (float)DMODEL));
    float ang  = (float)l * freq;
    acc += (d & 1) ? cosf(ang) : sinf(ang);
    xb[((size_t)b * LSEQ + l) * DMODEL + d] = f2b(acc);
}

// ============ Kernel W2B: in_proj_w fp32 -> bf16 ============
__global__ __launch_bounds__(256) void k_w2b(const float* __restrict__ w,
                                             unsigned short* __restrict__ wb) {
    int i = (blockIdx.x * 256 + threadIdx.x) * 4;
    float4 v = *(const float4*)(w + i);
    ushort4 o;
    o.x = f2b(v.x); o.y = f2b(v.y); o.z = f2b(v.z); o.w = f2b(v.w);
    *(ushort4*)(wb + i) = o;
}

// ============ Kernel C: in_proj GEMM via bf16 MFMA ============
// n<1024 -> xi_T[b][d][t] bf16 (ushort4-packed along t).
// n>=1024 -> z: m-tiles at (m0&511)==384; silu -> gs_T[b][d][tl] fp32 (float4 along tl).
__global__ __launch_bounds__(256) void k_gemm_inproj(const unsigned short* __restrict__ xb,
                                                     const unsigned short* __restrict__ wb,
                                                     unsigned short* __restrict__ xiT,
                                                     float* __restrict__ gsT) {
    int n0 = blockIdx.x * 128;
    int m0 = blockIdx.y * 128;
    if (n0 >= DINNER && (m0 & (LSEQ - 1)) != 384) return;

    __shared__ uint4 As4[512];   // 8KB fragment-order staging
    __shared__ uint4 Bs4[512];
    int tid  = threadIdx.x;
    int lane = tid & 63;
    int w    = tid >> 6;
    int wm   = (w & 1) * 64;
    int wn   = (w >> 1) * 64;
    f32x4 acc[4][4] = {};

    for (int k0 = 0; k0 < DMODEL; k0 += 32) {
#pragma unroll
        for (int hh = 0; hh < 2; ++hh) {
            int c  = tid + hh * 256;
            int im = c >> 6;
            int lc = c & 63;
            int r  = im * 16 + (lc & 15);
            int kq = lc >> 4;
            As4[c] = *(const uint4*)(xb + (size_t)(m0 + r) * DMODEL + k0 + kq * 8);
            Bs4[c] = *(const uint4*)(wb + (size_t)(n0 + r) * DMODEL + k0 + kq * 8);
        }
        __syncthreads();
        bf16_8 af[4], bf[4];
#pragma unroll
        for (int i = 0; i < 4; ++i) {
            af[i] = ((const bf16_8*)As4)[((wm >> 4) + i) * 64 + lane];
            bf[i] = ((const bf16_8*)Bs4)[((wn >> 4) + i) * 64 + lane];
        }
#pragma unroll
        for (int i = 0; i < 4; ++i)
#pragma unroll
            for (int j = 0; j < 4; ++j)
                acc[i][j] = __builtin_amdgcn_mfma_f32_16x16x32_bf16(af[i], bf[j], acc[i][j], 0, 0, 0);
        __syncthreads();
    }

    // C/D layout: col = lane&15, row = (lane>>4)*4 + reg  -> 4 consecutive m per reg block
    int col  = lane & 15;
    int quad = lane >> 4;
    if (n0 < DINNER) {
#pragma unroll
        for (int i = 0; i < 4; ++i) {
#pragma unroll
            for (int j = 0; j < 4; ++j) {
                int m = m0 + wm + i * 16 + quad * 4;
                int n = n0 + wn + j * 16 + col;
                int b = m >> 9, t = m & (LSEQ - 1);
                ushort4 o;
                o.x = f2b(acc[i][j][0]); o.y = f2b(acc[i][j][1]);
                o.z = f2b(acc[i][j][2]); o.w = f2b(acc[i][j][3]);
                *(ushort4*)(xiT + ((size_t)b * DINNER + n) * LSEQ + t) = o;
            }
        }
    } else {
#pragma unroll
        for (int i = 0; i < 4; ++i) {
#pragma unroll
            for (int j = 0; j < 4; ++j) {
                int m = m0 + wm + i * 16 + quad * 4;
                int t = m & (LSEQ - 1);
                if (t < TSTART) continue;          // 4-aligned boundary: whole quad in/out
                int b = m >> 9;
                int nz = n0 - DINNER + wn + j * 16 + col;
                float4 g;
                float v0 = acc[i][j][0], v1 = acc[i][j][1], v2 = acc[i][j][2], v3 = acc[i][j][3];
                g.x = v0 / (1.f + __expf(-v0));
                g.y = v1 / (1.f + __expf(-v1));
                g.z = v2 / (1.f + __expf(-v2));
                g.w = v3 / (1.f + __expf(-v3));
                *(float4*)(gsT + ((size_t)b * DINNER + nz) * PREDLEN + (t - TSTART)) = g;
            }
        }
    }
}

// ============ Kernel D: causal depthwise conv (k=4) + bias + silu ============
// reads xi_T[b][d][t], writes u_T[b][d][t]; thread = one d, 32-t chunk.
__global__ __launch_bounds__(256) void k_dwconv_silu(const unsigned short* __restrict__ xiT,
                                                     const float* __restrict__ cw,
                                                     const float* __restrict__ cb,
                                                     unsigned short* __restrict__ uT) {
    int d  = blockIdx.x * 256 + threadIdx.x;   // 0..1023
    int t0 = blockIdx.y * 32;
    int b  = blockIdx.z;
    const unsigned short* src = xiT + ((size_t)b * DINNER + d) * LSEQ;
    float4 w4 = *(const float4*)(cw + (size_t)d * 4);
    float bias = cb[d];
    uint4 raw[5];
    raw[0] = (t0 > 0) ? *(const uint4*)(src + t0 - 8) : make_uint4(0, 0, 0, 0);
#pragma unroll
    for (int k = 0; k < 4; ++k) raw[1 + k] = *(const uint4*)(src + t0 + 8 * k);
    float xv[40];
#pragma unroll
    for (int k = 0; k < 5; ++k) {
        const unsigned* pr = (const unsigned*)&raw[k];
#pragma unroll
        for (int q = 0; q < 4; ++q) {
            xv[k * 8 + q * 2 + 0] = blo(pr[q]);
            xv[k * 8 + q * 2 + 1] = bhi(pr[q]);
        }
    }
    unsigned ov[4];
    unsigned short* dst = uT + ((size_t)b * DINNER + d) * LSEQ + t0;
#pragma unroll
    for (int tt = 0; tt < 32; ++tt) {
        float a = bias + xv[tt + 5] * w4.x + xv[tt + 6] * w4.y
                       + xv[tt + 7] * w4.z + xv[tt + 8] * w4.w;
        float uv = a / (1.f + __expf(-a));
        unsigned short us = f2b(uv);
        if (tt & 1) ov[(tt >> 1) & 3] |= ((unsigned)us) << 16;
        else        ov[(tt >> 1) & 3]  = us;
        if ((tt & 7) == 7) *(uint4*)(dst + (tt - 7)) = *(uint4*)ov;
    }
}

// ============ Kernel E: x_proj GEMM from u_T ============
// xdbl[m,j] = sum_k u[m,k]*XP[j,k]; A staged from u_T via LDS transpose.
// cols 0..31 -> dt_in[m][32]; 32..47 -> Bt[b][s][t]; 48..63 -> Ct[b][s][t].
#define G2_BM 64
#define G2_BK 16
#define G2_PAD 4
__global__ __launch_bounds__(256) void k_gemm_xproj(const unsigned short* __restrict__ uT,
                                                    const float* __restrict__ W,
                                                    float* __restrict__ dt_in,
                                                    float* __restrict__ Bt,
                                                    float* __restrict__ Ct) {
    __shared__ float As[G2_BK][G2_BM + G2_PAD];
    __shared__ float Bs[G2_BK][G2_BM + G2_PAD];
    const int K = 1024;
    int tid = threadIdx.x;
    int m0 = blockIdx.x * G2_BM;
    int b  = m0 >> 9;
    int t0 = m0 & (LSEQ - 1);
    int tm = tid & 15;
    int tn = tid >> 4;
    float acc[4][4] = {};
    for (int k0 = 0; k0 < K; k0 += G2_BK) {
        {
            int k    = tid >> 4;          // 0..15
            int msub = (tid & 15) * 4;    // 0..60
            uint2 va = *(const uint2*)(uT + ((size_t)b * DINNER + k0 + k) * LSEQ + t0 + msub);
            float4 fv;
            fv.x = blo(va.x); fv.y = bhi(va.x); fv.z = blo(va.y); fv.w = bhi(va.y);
            *(float4*)&As[k][msub] = fv;
            int row = tid >> 2;           // 0..63
            int kq  = (tid & 3) << 2;
            float4 vb = *(const float4*)(W + (size_t)row * K + k0 + kq);
            Bs[kq + 0][row] = vb.x; Bs[kq + 1][row] = vb.y;
            Bs[kq + 2][row] = vb.z; Bs[kq + 3][row] = vb.w;
        }
        __syncthreads();
#pragma unroll
        for (int k = 0; k < G2_BK; ++k) {
            float a[4], bb[4];
            float4 a0 = *(const float4*)&As[k][tm * 4];
            a[0]=a0.x; a[1]=a0.y; a[2]=a0.z; a[3]=a0.w;
            float4 b0 = *(const float4*)&Bs[k][tn * 4];
            bb[0]=b0.x; bb[1]=b0.y; bb[2]=b0.z; bb[3]=b0.w;
#pragma unroll
            for (int i = 0; i < 4; ++i)
#pragma unroll
                for (int j = 0; j < 4; ++j)
                    acc[i][j] += a[i] * bb[j];
        }
        __syncthreads();
    }
    if (tn < 8) {
#pragma unroll
        for (int i = 0; i < 4; ++i) {
            float4 st = make_float4(acc[i][0], acc[i][1], acc[i][2], acc[i][3]);
            *(float4*)(dt_in + (size_t)(m0 + tm * 4 + i) * DTRANK + tn * 4) = st;
        }
    } else {
#pragma unroll
        for (int j = 0; j < 4; ++j) {
            int c = tn * 4 + j;           // 32..63
            float4 st = make_float4(acc[0][j], acc[1][j], acc[2][j], acc[3][j]);
            int t = t0 + tm * 4;
            if (c < 48) *(float4*)(Bt + ((size_t)b * DSTATE + (c - 32)) * LSEQ + t) = st;
            else        *(float4*)(Ct + ((size_t)b * DSTATE + (c - 48)) * LSEQ + t) = st;
        }
    }
}

// ============ Kernel F: dt = softplus(dt_in @ dt_proj_w.T + b) -> dt_T[b][d][t] bf16 ============
__global__ __launch_bounds__(256) void k_dtproj(const float* __restrict__ dt_in,
                                                const float* __restrict__ dpw,
                                                const float* __restrict__ dpb,
                                                unsigned short* __restrict__ dtT) {
    __shared__ float xs[64][32];
    int n  = blockIdx.x * 256 + threadIdx.x;   // d
    int m0 = blockIdx.y * 64;
    int b  = m0 >> 9;
    int t0 = m0 & (LSEQ - 1);
    for (int f = threadIdx.x; f < 512; f += 256) {
        int row = f >> 3;
        int c   = (f & 7) << 2;
        *(float4*)&xs[row][c] = *(const float4*)(dt_in + (size_t)(m0 + row) * DTRANK + c);
    }
    __syncthreads();
    float w[32];
#pragma unroll
    for (int r = 0; r < 32; r += 4) {
        float4 v = *(const float4*)(dpw + (size_t)n * DTRANK + r);
        w[r] = v.x; w[r + 1] = v.y; w[r + 2] = v.z; w[r + 3] = v.w;
    }
    float bias = dpb[n];
    unsigned short* dst = dtT + ((size_t)b * DINNER + n) * LSEQ + t0;
    unsigned ov[4];
#pragma unroll 4
    for (int m = 0; m < 64; m += 2) {
        float a0 = bias, a1 = bias;
#pragma unroll
        for (int r = 0; r < 32; ++r) {
            a0 += xs[m][r]     * w[r];
            a1 += xs[m + 1][r] * w[r];
        }
        float s0 = (a0 > 20.f) ? a0 : log1pf(__expf(a0));
        float s1 = (a1 > 20.f) ? a1 : log1pf(__expf(a1));
        ov[(m >> 1) & 3] = (unsigned)f2b(s0) | (((unsigned)f2b(s1)) << 16);
        if ((m & 7) == 6) *(uint4*)(dst + (m - 6)) = *(uint4*)ov;
    }
}

// ============ Kernel G: selective scan, t-vectorized ============
// block 256 = 16 d x 16 s; loads 8 t-steps per iteration from t-contiguous buffers.
__global__ __launch_bounds__(256) void k_scan3(const unsigned short* __restrict__ uT,
                                               const unsigned short* __restrict__ dtT,
                                               const float* __restrict__ Bt,
                                               const float* __restrict__ Ct,
                                               const float* __restrict__ A_log,
                                               const float* __restrict__ Dvec,
                                               const float* __restrict__ wf,
                                               const float* __restrict__ gsT,
                                               float* __restrict__ pacc) {
    int b    = blockIdx.y;
    int tid  = threadIdx.x;
    int s    = tid & 15;
    int dloc = tid >> 4;
    int d    = blockIdx.x * 16 + dloc;
    float As2 = -__expf(A_log[(size_t)d * DSTATE + s]) * 1.44269504088896f; // for exp2
    float Dd  = Dvec[d];
    float wfd = wf[d];
    const unsigned short* up = uT  + ((size_t)b * DINNER + d) * LSEQ;
    const unsigned short* dp = dtT + ((size_t)b * DINNER + d) * LSEQ;
    const float* Bp = Bt + ((size_t)b * DSTATE + s) * LSEQ;
    const float* Cp = Ct + ((size_t)b * DSTATE + s) * LSEQ;
    const float* gp = gsT + ((size_t)b * DINNER + d) * PREDLEN;
    float* pout = pacc + ((size_t)b * PREDLEN) * 256 + blockIdx.x * 4 + (tid >> 6);
    float h = 0.f;
    for (int t8 = 0; t8 < LSEQ; t8 += 8) {
        uint4 uq = *(const uint4*)(up + t8);
        uint4 dq = *(const uint4*)(dp + t8);
        float4 B0 = *(const float4*)(Bp + t8);
        float4 B1 = *(const float4*)(Bp + t8 + 4);
        float4 C0 = *(const float4*)(Cp + t8);
        float4 C1 = *(const float4*)(Cp + t8 + 4);
        float uu[8], dd[8];
        const unsigned* uqp = (const unsigned*)&uq;
        const unsigned* dqp = (const unsigned*)&dq;
#pragma unroll
        for (int q = 0; q < 4; ++q) {
            uu[q * 2] = blo(uqp[q]); uu[q * 2 + 1] = bhi(uqp[q]);
            dd[q * 2] = blo(dqp[q]); dd[q * 2 + 1] = bhi(dqp[q]);
        }
        float Bv[8] = {B0.x, B0.y, B0.z, B0.w, B1.x, B1.y, B1.z, B1.w};
        float Cv[8] = {C0.x, C0.y, C0.z, C0.w, C1.x, C1.y, C1.z, C1.w};
        if (t8 < TSTART) {
#pragma unroll
            for (int j = 0; j < 8; ++j)
                h = exp2f(dd[j] * As2) * h + (dd[j] * uu[j]) * Bv[j];
        } else {
            int tl0 = t8 - TSTART;
            float4 g0 = *(const float4*)(gp + tl0);
            float4 g1 = *(const float4*)(gp + tl0 + 4);
            float gv[8] = {g0.x, g0.y, g0.z, g0.w, g1.x, g1.y, g1.z, g1.w};
#pragma unroll
            for (int j = 0; j < 8; ++j) {
                h = exp2f(dd[j] * As2) * h + (dd[j] * uu[j]) * Bv[j];
                float y = h * Cv[j];
                y += __shfl_xor(y, 1); y += __shfl_xor(y, 2);
                y += __shfl_xor(y, 4); y += __shfl_xor(y, 8);
                float c = (s == 0) ? (y + uu[j] * Dd) * gv[j] * wfd : 0.f;
                c += __shfl_xor(c, 16); c += __shfl_xor(c, 32);
                if ((tid & 63) == 0) pout[(size_t)(tl0 + j) * 256] = c;
            }
        }
    }
}

// ============ Kernel W: w_fused[i] = sum_d out_proj_w[d,i]*out_w[d] ============
__global__ __launch_bounds__(256) void k_fusew(const float* __restrict__ opw,
                                               const float* __restrict__ ow,
                                               float* __restrict__ wfv) {
    int i = blockIdx.x * 256 + threadIdx.x;
    float acc = 0.f;
    for (int dd = 0; dd < DMODEL; ++dd)
        acc += opw[(size_t)dd * DINNER + i] * ow[dd];
    wfv[i] = acc;
}

// ============ Kernel H: reduce 256 partials + de-normalize ============
__global__ __launch_bounds__(64) void k_final(const float* __restrict__ pacc,
                                              const float* __restrict__ meanv,
                                              const float* __restrict__ stdv,
                                              float* __restrict__ out) {
    int idx  = blockIdx.x;               // b*96+tl
    int lane = threadIdx.x;
    int b = idx / PREDLEN;
    float4 v = *(const float4*)(pacc + (size_t)idx * 256 + lane * 4);
    float tot = v.x + v.y + v.z + v.w;
#pragma unroll
    for (int off = 32; off; off >>= 1) tot += __shfl_xor(tot, off);
    if (lane == 0) out[idx] = tot * stdv[b * ENC_IN] + meanv[b * ENC_IN];
}

// ---------------- launch ----------------
extern "C" void kernel_launch(void* const* d_in, const int* in_sizes, int n_in,
                              void* d_out, int out_size, void* d_ws, size_t ws_size,
                              hipStream_t stream) {
    const float* x_enc     = (const float*)d_in[0];
    const float* x_mark    = (const float*)d_in[1];
    const float* conv_w    = (const float*)d_in[2];
    const float* temp_w    = (const float*)d_in[3];
    const float* in_proj_w = (const float*)d_in[4];
    const float* conv1d_w  = (const float*)d_in[5];
    const float* conv1d_b  = (const float*)d_in[6];
    const float* x_proj_w  = (const float*)d_in[7];
    const float* dt_proj_w = (const float*)d_in[8];
    const float* dt_proj_b = (const float*)d_in[9];
    const float* A_log     = (const float*)d_in[10];
    const float* Dvec      = (const float*)d_in[11];
    const float* out_proj_w= (const float*)d_in[12];
    const float* out_w     = (const float*)d_in[13];
    float* ws  = (float*)d_ws;
    float* out = (float*)d_out;

    float* xn    = ws + OFF_XN;
    float* meanv = ws + OFF_MEAN;
    float* stdv  = ws + OFF_STD;
    float* wfv   = ws + OFF_WF;
    float* pacc  = ws + OFF_PACC;
    float* dt_in = ws + OFF_DTIN;
    float* Btv   = ws + OFF_BT;
    float* Ctv   = ws + OFF_CT;
    float* gsT   = ws + OFF_GST;
    unsigned short* xb  = (unsigned short*)(ws + OFF_XB);
    unsigned short* wb  = (unsigned short*)(ws + OFF_WB);
    unsigned short* xiT = (unsigned short*)(ws + OFF_XIT);
    unsigned short* uT  = (unsigned short*)(ws + OFF_UT);
    unsigned short* dtT = (unsigned short*)(ws + OFF_DTT);   // overlays xiT

    k_norm<<<dim3(ENC_IN, BATCH), 64, 0, stream>>>(x_enc, xn, meanv, stdv);
    k_fusew<<<dim3(DINNER / 256), 256, 0, stream>>>(out_proj_w, out_w, wfv);
    k_build_x<<<dim3(DMODEL / 256, LSEQ, BATCH), 256, 0, stream>>>(xn, x_mark, conv_w, temp_w, xb);
    k_w2b<<<dim3((2 * DINNER * DMODEL) / 1024), 256, 0, stream>>>(in_proj_w, wb);
    k_gemm_inproj<<<dim3(16, 128), 256, 0, stream>>>(xb, wb, xiT, gsT);
    k_dwconv_silu<<<dim3(DINNER / 256, LSEQ / 32, BATCH), 256, 0, stream>>>(xiT, conv1d_w, conv1d_b, uT);
    k_gemm_xproj<<<dim3(MROWS / G2_BM), 256, 0, stream>>>(uT, x_proj_w, dt_in, Btv, Ctv);
    k_dtproj<<<dim3(DINNER / 256, MROWS / 64), 256, 0, stream>>>(dt_in, dt_proj_w, dt_proj_b, dtT);
    k_scan3<<<dim3(DINNER / 16, BATCH), 256, 0, stream>>>(uT, dtT, Btv, Ctv, A_log, Dvec, wfv, gsT, pacc);
    k_final<<<dim3(BATCH * PREDLEN), 64, 0, stream>>>(pacc, meanv, stdv, out);
}

// Round 5
// 607.577 us; speedup vs baseline: 2.0207x; 1.0293x over previous
//
#include <hip/hip_runtime.h>
#include <hip/hip_bf16.h>
#include <math.h>

// ---------------- problem constants ----------------
#define BATCH   32
#define LSEQ    512
#define ENC_IN  8
#define MARKD   4
#define DMODEL  512
#define DSTATE  16
#define DINNER  1024
#define DTRANK  32
#define PREDLEN 96
#define MROWS   (BATCH * LSEQ)          // 16384
#define TSTART  (LSEQ - PREDLEN)        // 416
#define NCHUNK  3                       // parallel-scan chunks of 128 over t<384

// ---------------- workspace layout (float units), total 101.5 MiB ----------------
#define OFF_XN    ((size_t)0)            // 131072
#define OFF_MEAN  ((size_t)131072)       // 256
#define OFF_STD   ((size_t)131328)       // 256
#define OFF_WF    ((size_t)131584)       // 1024
#define OFF_PACC  ((size_t)132608)       // 32*96*256 = 786432
#define OFF_XB    ((size_t)919040)       // 16384x512 bf16 = 4194304 f  (alpha/beta overlays)
#define OFF_WB    ((size_t)5113344)      // 2048x512 bf16 = 524288 f
#define OFF_DTIN  ((size_t)5637632)      // 16384x32 fp32 = 524288 f
#define OFF_BT    ((size_t)6161920)      // 32x16x512 fp32 = 262144 f
#define OFF_CT    ((size_t)6424064)      // 262144 f
#define OFF_GST   ((size_t)6686208)      // 32x1024x96 fp32 = 3145728 f
#define OFF_XIT   ((size_t)9831936)      // [b][d][t] bf16 = 8388608 f (dt_T overlays)
#define OFF_UT    ((size_t)18220544)     // [b][d][t] bf16 = 8388608 f
#define OFF_DTT   OFF_XIT                // dt_T reuses xi_T (dead after dwconv)
#define OFF_AB    OFF_XB                 // alpha/beta: 32*1024*3*16*2 = 3145728 f <= 4194304
// end: 26609152 floats = 101.5 MiB

typedef __bf16 bf16_8 __attribute__((ext_vector_type(8)));
typedef float  f32x4  __attribute__((ext_vector_type(4)));

static __device__ __forceinline__ float b2f(unsigned short h) {
    union { float f; unsigned u; } v; v.u = ((unsigned)h) << 16; return v.f;
}
static __device__ __forceinline__ unsigned short f2b(float f) {
    __hip_bfloat16 h = __float2bfloat16(f);   // RNE
    union { __hip_bfloat16 b; unsigned short s; } v; v.b = h; return v.s;
}
static __device__ __forceinline__ float blo(unsigned v) {
    union { float f; unsigned u; } x; x.u = v << 16; return x.f;
}
static __device__ __forceinline__ float bhi(unsigned v) {
    union { float f; unsigned u; } x; x.u = v & 0xffff0000u; return x.f;
}

// ============ Kernel A: per-(b,c) mean/std + normalize ============
__global__ __launch_bounds__(64) void k_norm(const float* __restrict__ xe,
                                             float* __restrict__ xn,
                                             float* __restrict__ meanv,
                                             float* __restrict__ stdv) {
    int c = blockIdx.x;
    int b = blockIdx.y;
    int lane = threadIdx.x;
    const float* p = xe + ((size_t)b * LSEQ) * ENC_IN + c;
    float vals[8];
    float s = 0.f, s2 = 0.f;
#pragma unroll
    for (int i = 0; i < 8; ++i) {
        float v = p[(size_t)(lane + i * 64) * ENC_IN];
        vals[i] = v; s += v; s2 += v * v;
    }
#pragma unroll
    for (int off = 32; off; off >>= 1) {
        s  += __shfl_xor(s,  off);
        s2 += __shfl_xor(s2, off);
    }
    float mean = s * (1.f / LSEQ);
    float var  = s2 * (1.f / LSEQ) - mean * mean;
    float sd   = sqrtf(var + 1e-5f);
    float rstd = 1.f / sd;
    if (lane == 0) { meanv[b * ENC_IN + c] = mean; stdv[b * ENC_IN + c] = sd; }
#pragma unroll
    for (int i = 0; i < 8; ++i)
        xn[((size_t)b * LSEQ + lane + i * 64) * ENC_IN + c] = (vals[i] - mean) * rstd;
}

// ============ Kernel B: x = token_conv(xn) + temporal + pos_emb  (bf16 out) ============
__global__ __launch_bounds__(256) void k_build_x(const float* __restrict__ xn,
                                                 const float* __restrict__ xmark,
                                                 const float* __restrict__ convw,
                                                 const float* __restrict__ tempw,
                                                 unsigned short* __restrict__ xb) {
    int d = blockIdx.x * 256 + threadIdx.x;
    int l = blockIdx.y;
    int b = blockIdx.z;
    int lm = (l + LSEQ - 1) & (LSEQ - 1);     // circular pad per reference
    int lp = (l + 1) & (LSEQ - 1);
    const float* r0 = xn + ((size_t)b * LSEQ + lm) * ENC_IN;
    const float* r1 = xn + ((size_t)b * LSEQ + l ) * ENC_IN;
    const float* r2 = xn + ((size_t)b * LSEQ + lp) * ENC_IN;
    const float* w  = convw + (size_t)d * (ENC_IN * 3);
    float acc = 0.f;
#pragma unroll
    for (int i = 0; i < ENC_IN; ++i)
        acc += r0[i] * w[i * 3 + 0] + r1[i] * w[i * 3 + 1] + r2[i] * w[i * 3 + 2];
    const float* tw = tempw + (size_t)d * MARKD;
    const float* xm = xmark + ((size_t)b * LSEQ + l) * MARKD;
    acc += xm[0] * tw[0] + xm[1] * tw[1] + xm[2] * tw[2] + xm[3] * tw[3];
    float freq = __expf(-(float)(d & ~1) * (9.210340371976184f / (float)DMODEL));
    float ang  = (float)l * freq;
    acc += (d & 1) ? cosf(ang) : sinf(ang);
    xb[((size_t)b * LSEQ + l) * DMODEL + d] = f2b(acc);
}

// ============ Kernel W2B: in_proj_w fp32 -> bf16 ============
__global__ __launch_bounds__(256) void k_w2b(const float* __restrict__ w,
                                             unsigned short* __restrict__ wb) {
    int i = (blockIdx.x * 256 + threadIdx.x) * 4;
    float4 v = *(const float4*)(w + i);
    ushort4 o;
    o.x = f2b(v.x); o.y = f2b(v.y); o.z = f2b(v.z); o.w = f2b(v.w);
    *(ushort4*)(wb + i) = o;
}

// ============ Kernel C: in_proj GEMM via bf16 MFMA ============
__global__ __launch_bounds__(256) void k_gemm_inproj(const unsigned short* __restrict__ xb,
                                                     const unsigned short* __restrict__ wb,
                                                     unsigned short* __restrict__ xiT,
                                                     float* __restrict__ gsT) {
    int n0 = blockIdx.x * 128;
    int m0 = blockIdx.y * 128;
    if (n0 >= DINNER && (m0 & (LSEQ - 1)) != 384) return;

    __shared__ uint4 As4[512];   // 8KB fragment-order staging
    __shared__ uint4 Bs4[512];
    int tid  = threadIdx.x;
    int lane = tid & 63;
    int w    = tid >> 6;
    int wm   = (w & 1) * 64;
    int wn   = (w >> 1) * 64;
    f32x4 acc[4][4] = {};

    for (int k0 = 0; k0 < DMODEL; k0 += 32) {
#pragma unroll
        for (int hh = 0; hh < 2; ++hh) {
            int c  = tid + hh * 256;
            int im = c >> 6;
            int lc = c & 63;
            int r  = im * 16 + (lc & 15);
            int kq = lc >> 4;
            As4[c] = *(const uint4*)(xb + (size_t)(m0 + r) * DMODEL + k0 + kq * 8);
            Bs4[c] = *(const uint4*)(wb + (size_t)(n0 + r) * DMODEL + k0 + kq * 8);
        }
        __syncthreads();
        bf16_8 af[4], bf[4];
#pragma unroll
        for (int i = 0; i < 4; ++i) {
            af[i] = ((const bf16_8*)As4)[((wm >> 4) + i) * 64 + lane];
            bf[i] = ((const bf16_8*)Bs4)[((wn >> 4) + i) * 64 + lane];
        }
#pragma unroll
        for (int i = 0; i < 4; ++i)
#pragma unroll
            for (int j = 0; j < 4; ++j)
                acc[i][j] = __builtin_amdgcn_mfma_f32_16x16x32_bf16(af[i], bf[j], acc[i][j], 0, 0, 0);
        __syncthreads();
    }

    int col  = lane & 15;
    int quad = lane >> 4;
    if (n0 < DINNER) {
#pragma unroll
        for (int i = 0; i < 4; ++i) {
#pragma unroll
            for (int j = 0; j < 4; ++j) {
                int m = m0 + wm + i * 16 + quad * 4;
                int n = n0 + wn + j * 16 + col;
                int b = m >> 9, t = m & (LSEQ - 1);
                ushort4 o;
                o.x = f2b(acc[i][j][0]); o.y = f2b(acc[i][j][1]);
                o.z = f2b(acc[i][j][2]); o.w = f2b(acc[i][j][3]);
                *(ushort4*)(xiT + ((size_t)b * DINNER + n) * LSEQ + t) = o;
            }
        }
    } else {
#pragma unroll
        for (int i = 0; i < 4; ++i) {
#pragma unroll
            for (int j = 0; j < 4; ++j) {
                int m = m0 + wm + i * 16 + quad * 4;
                int t = m & (LSEQ - 1);
                if (t < TSTART) continue;
                int b = m >> 9;
                int nz = n0 - DINNER + wn + j * 16 + col;
                float4 g;
                float v0 = acc[i][j][0], v1 = acc[i][j][1], v2 = acc[i][j][2], v3 = acc[i][j][3];
                g.x = v0 / (1.f + __expf(-v0));
                g.y = v1 / (1.f + __expf(-v1));
                g.z = v2 / (1.f + __expf(-v2));
                g.w = v3 / (1.f + __expf(-v3));
                *(float4*)(gsT + ((size_t)b * DINNER + nz) * PREDLEN + (t - TSTART)) = g;
            }
        }
    }
}

// ============ Kernel D: causal depthwise conv (k=4) + bias + silu ============
__global__ __launch_bounds__(256) void k_dwconv_silu(const unsigned short* __restrict__ xiT,
                                                     const float* __restrict__ cw,
                                                     const float* __restrict__ cb,
                                                     unsigned short* __restrict__ uT) {
    int d  = blockIdx.x * 256 + threadIdx.x;
    int t0 = blockIdx.y * 32;
    int b  = blockIdx.z;
    const unsigned short* src = xiT + ((size_t)b * DINNER + d) * LSEQ;
    float4 w4 = *(const float4*)(cw + (size_t)d * 4);
    float bias = cb[d];
    uint4 raw[5];
    raw[0] = (t0 > 0) ? *(const uint4*)(src + t0 - 8) : make_uint4(0, 0, 0, 0);
#pragma unroll
    for (int k = 0; k < 4; ++k) raw[1 + k] = *(const uint4*)(src + t0 + 8 * k);
    float xv[40];
#pragma unroll
    for (int k = 0; k < 5; ++k) {
        const unsigned* pr = (const unsigned*)&raw[k];
#pragma unroll
        for (int q = 0; q < 4; ++q) {
            xv[k * 8 + q * 2 + 0] = blo(pr[q]);
            xv[k * 8 + q * 2 + 1] = bhi(pr[q]);
        }
    }
    unsigned ov[4];
    unsigned short* dst = uT + ((size_t)b * DINNER + d) * LSEQ + t0;
#pragma unroll
    for (int tt = 0; tt < 32; ++tt) {
        float a = bias + xv[tt + 5] * w4.x + xv[tt + 6] * w4.y
                       + xv[tt + 7] * w4.z + xv[tt + 8] * w4.w;
        float uv = a / (1.f + __expf(-a));
        unsigned short us = f2b(uv);
        if (tt & 1) ov[(tt >> 1) & 3] |= ((unsigned)us) << 16;
        else        ov[(tt >> 1) & 3]  = us;
        if ((tt & 7) == 7) *(uint4*)(dst + (tt - 7)) = *(uint4*)ov;
    }
}

// ============ Kernel E: x_proj GEMM from u_T ============
#define G2_BM 64
#define G2_BK 16
#define G2_PAD 4
__global__ __launch_bounds__(256) void k_gemm_xproj(const unsigned short* __restrict__ uT,
                                                    const float* __restrict__ W,
                                                    float* __restrict__ dt_in,
                                                    float* __restrict__ Bt,
                                                    float* __restrict__ Ct) {
    __shared__ float As[G2_BK][G2_BM + G2_PAD];
    __shared__ float Bs[G2_BK][G2_BM + G2_PAD];
    const int K = 1024;
    int tid = threadIdx.x;
    int m0 = blockIdx.x * G2_BM;
    int b  = m0 >> 9;
    int t0 = m0 & (LSEQ - 1);
    int tm = tid & 15;
    int tn = tid >> 4;
    float acc[4][4] = {};
    for (int k0 = 0; k0 < K; k0 += G2_BK) {
        {
            int k    = tid >> 4;
            int msub = (tid & 15) * 4;
            uint2 va = *(const uint2*)(uT + ((size_t)b * DINNER + k0 + k) * LSEQ + t0 + msub);
            float4 fv;
            fv.x = blo(va.x); fv.y = bhi(va.x); fv.z = blo(va.y); fv.w = bhi(va.y);
            *(float4*)&As[k][msub] = fv;
            int row = tid >> 2;
            int kq  = (tid & 3) << 2;
            float4 vb = *(const float4*)(W + (size_t)row * K + k0 + kq);
            Bs[kq + 0][row] = vb.x; Bs[kq + 1][row] = vb.y;
            Bs[kq + 2][row] = vb.z; Bs[kq + 3][row] = vb.w;
        }
        __syncthreads();
#pragma unroll
        for (int k = 0; k < G2_BK; ++k) {
            float a[4], bb[4];
            float4 a0 = *(const float4*)&As[k][tm * 4];
            a[0]=a0.x; a[1]=a0.y; a[2]=a0.z; a[3]=a0.w;
            float4 b0 = *(const float4*)&Bs[k][tn * 4];
            bb[0]=b0.x; bb[1]=b0.y; bb[2]=b0.z; bb[3]=b0.w;
#pragma unroll
            for (int i = 0; i < 4; ++i)
#pragma unroll
                for (int j = 0; j < 4; ++j)
                    acc[i][j] += a[i] * bb[j];
        }
        __syncthreads();
    }
    if (tn < 8) {
#pragma unroll
        for (int i = 0; i < 4; ++i) {
            float4 st = make_float4(acc[i][0], acc[i][1], acc[i][2], acc[i][3]);
            *(float4*)(dt_in + (size_t)(m0 + tm * 4 + i) * DTRANK + tn * 4) = st;
        }
    } else {
#pragma unroll
        for (int j = 0; j < 4; ++j) {
            int c = tn * 4 + j;
            float4 st = make_float4(acc[0][j], acc[1][j], acc[2][j], acc[3][j]);
            int t = t0 + tm * 4;
            if (c < 48) *(float4*)(Bt + ((size_t)b * DSTATE + (c - 32)) * LSEQ + t) = st;
            else        *(float4*)(Ct + ((size_t)b * DSTATE + (c - 48)) * LSEQ + t) = st;
        }
    }
}

// ============ Kernel F: dt = softplus(dt_in @ dt_proj_w.T + b) -> dt_T[b][d][t] bf16 ============
__global__ __launch_bounds__(256) void k_dtproj(const float* __restrict__ dt_in,
                                                const float* __restrict__ dpw,
                                                const float* __restrict__ dpb,
                                                unsigned short* __restrict__ dtT) {
    __shared__ float xs[64][32];
    int n  = blockIdx.x * 256 + threadIdx.x;
    int m0 = blockIdx.y * 64;
    int b  = m0 >> 9;
    int t0 = m0 & (LSEQ - 1);
    for (int f = threadIdx.x; f < 512; f += 256) {
        int row = f >> 3;
        int c   = (f & 7) << 2;
        *(float4*)&xs[row][c] = *(const float4*)(dt_in + (size_t)(m0 + row) * DTRANK + c);
    }
    __syncthreads();
    float w[32];
#pragma unroll
    for (int r = 0; r < 32; r += 4) {
        float4 v = *(const float4*)(dpw + (size_t)n * DTRANK + r);
        w[r] = v.x; w[r + 1] = v.y; w[r + 2] = v.z; w[r + 3] = v.w;
    }
    float bias = dpb[n];
    unsigned short* dst = dtT + ((size_t)b * DINNER + n) * LSEQ + t0;
    unsigned ov[4];
#pragma unroll 4
    for (int m = 0; m < 64; m += 2) {
        float a0 = bias, a1 = bias;
#pragma unroll
        for (int r = 0; r < 32; ++r) {
            a0 += xs[m][r]     * w[r];
            a1 += xs[m + 1][r] * w[r];
        }
        float s0 = (a0 > 20.f) ? a0 : log1pf(__expf(a0));
        float s1 = (a1 > 20.f) ? a1 : log1pf(__expf(a1));
        ov[(m >> 1) & 3] = (unsigned)f2b(s0) | (((unsigned)f2b(s1)) << 16);
        if ((m & 7) == 6) *(uint4*)(dst + (m - 6)) = *(uint4*)ov;
    }
}

// ============ Kernel G1: scan phase 1 — per-chunk (alpha, beta) over t<384 ============
// block 256 = 16 d x 16 s; chunk = blockIdx.z (128 t-steps).
// alpha = exp2(As2 * sum(dt)); beta = chunk-local scan from h=0.
__global__ __launch_bounds__(256) void k_scan_p1(const unsigned short* __restrict__ uT,
                                                 const unsigned short* __restrict__ dtT,
                                                 const float* __restrict__ Bt,
                                                 const float* __restrict__ A_log,
                                                 float2* __restrict__ ab) {
    int b    = blockIdx.y;
    int c    = blockIdx.z;
    int tid  = threadIdx.x;
    int s    = tid & 15;
    int dloc = tid >> 4;
    int d    = blockIdx.x * 16 + dloc;
    float As2 = -__expf(A_log[(size_t)d * DSTATE + s]) * 1.44269504088896f;
    const unsigned short* up = uT  + ((size_t)b * DINNER + d) * LSEQ;
    const unsigned short* dp = dtT + ((size_t)b * DINNER + d) * LSEQ;
    const float* Bp = Bt + ((size_t)b * DSTATE + s) * LSEQ;
    float beta = 0.f, asum = 0.f;
    int tbeg = c * 128;
    for (int t8 = tbeg; t8 < tbeg + 128; t8 += 8) {
        uint4 uq = *(const uint4*)(up + t8);
        uint4 dq = *(const uint4*)(dp + t8);
        float4 B0 = *(const float4*)(Bp + t8);
        float4 B1 = *(const float4*)(Bp + t8 + 4);
        float uu[8], dd[8];
        const unsigned* uqp = (const unsigned*)&uq;
        const unsigned* dqp = (const unsigned*)&dq;
#pragma unroll
        for (int q = 0; q < 4; ++q) {
            uu[q * 2] = blo(uqp[q]); uu[q * 2 + 1] = bhi(uqp[q]);
            dd[q * 2] = blo(dqp[q]); dd[q * 2 + 1] = bhi(dqp[q]);
        }
        float Bv[8] = {B0.x, B0.y, B0.z, B0.w, B1.x, B1.y, B1.z, B1.w};
#pragma unroll
        for (int j = 0; j < 8; ++j) {
            float e = exp2f(dd[j] * As2);
            beta = e * beta + (dd[j] * uu[j]) * Bv[j];
            asum += dd[j];
        }
    }
    float alpha = exp2f(asum * As2);
    ab[((size_t)(b * DINNER + d) * NCHUNK + c) * DSTATE + s] = make_float2(alpha, beta);
}

// ============ Kernel G2: scan phase 2+3 — stitch h(384), run t in [384,512), emit outputs ============
__global__ __launch_bounds__(256) void k_scan_p3(const unsigned short* __restrict__ uT,
                                                 const unsigned short* __restrict__ dtT,
                                                 const float* __restrict__ Bt,
                                                 const float* __restrict__ Ct,
                                                 const float* __restrict__ A_log,
                                                 const float* __restrict__ Dvec,
                                                 const float* __restrict__ wf,
                                                 const float* __restrict__ gsT,
                                                 const float2* __restrict__ ab,
                                                 float* __restrict__ pacc) {
    int b    = blockIdx.y;
    int tid  = threadIdx.x;
    int s    = tid & 15;
    int dloc = tid >> 4;
    int d    = blockIdx.x * 16 + dloc;
    float As2 = -__expf(A_log[(size_t)d * DSTATE + s]) * 1.44269504088896f;
    float Dd  = Dvec[d];
    float wfd = wf[d];
    // stitch: h(384) = beta2 + alpha2*(beta1 + alpha1*beta0)
    const float2* abp = ab + (size_t)(b * DINNER + d) * NCHUNK * DSTATE + s;
    float h = 0.f;
#pragma unroll
    for (int c = 0; c < NCHUNK; ++c) {
        float2 v = abp[c * DSTATE];
        h = v.y + v.x * h;
    }
    const unsigned short* up = uT  + ((size_t)b * DINNER + d) * LSEQ;
    const unsigned short* dp = dtT + ((size_t)b * DINNER + d) * LSEQ;
    const float* Bp = Bt + ((size_t)b * DSTATE + s) * LSEQ;
    const float* Cp = Ct + ((size_t)b * DSTATE + s) * LSEQ;
    const float* gp = gsT + ((size_t)b * DINNER + d) * PREDLEN;
    float* pout = pacc + ((size_t)b * PREDLEN) * 256 + blockIdx.x * 4 + (tid >> 6);
    for (int t8 = NCHUNK * 128; t8 < LSEQ; t8 += 8) {
        uint4 uq = *(const uint4*)(up + t8);
        uint4 dq = *(const uint4*)(dp + t8);
        float4 B0 = *(const float4*)(Bp + t8);
        float4 B1 = *(const float4*)(Bp + t8 + 4);
        float4 C0 = *(const float4*)(Cp + t8);
        float4 C1 = *(const float4*)(Cp + t8 + 4);
        float uu[8], dd[8];
        const unsigned* uqp = (const unsigned*)&uq;
        const unsigned* dqp = (const unsigned*)&dq;
#pragma unroll
        for (int q = 0; q < 4; ++q) {
            uu[q * 2] = blo(uqp[q]); uu[q * 2 + 1] = bhi(uqp[q]);
            dd[q * 2] = blo(dqp[q]); dd[q * 2 + 1] = bhi(dqp[q]);
        }
        float Bv[8] = {B0.x, B0.y, B0.z, B0.w, B1.x, B1.y, B1.z, B1.w};
        float Cv[8] = {C0.x, C0.y, C0.z, C0.w, C1.x, C1.y, C1.z, C1.w};
        if (t8 < TSTART) {
#pragma unroll
            for (int j = 0; j < 8; ++j)
                h = exp2f(dd[j] * As2) * h + (dd[j] * uu[j]) * Bv[j];
        } else {
            int tl0 = t8 - TSTART;
            float4 g0 = *(const float4*)(gp + tl0);
            float4 g1 = *(const float4*)(gp + tl0 + 4);
            float gv[8] = {g0.x, g0.y, g0.z, g0.w, g1.x, g1.y, g1.z, g1.w};
#pragma unroll
            for (int j = 0; j < 8; ++j) {
                h = exp2f(dd[j] * As2) * h + (dd[j] * uu[j]) * Bv[j];
                float y = h * Cv[j];
                y += __shfl_xor(y, 1); y += __shfl_xor(y, 2);
                y += __shfl_xor(y, 4); y += __shfl_xor(y, 8);
                float cc = (s == 0) ? (y + uu[j] * Dd) * gv[j] * wfd : 0.f;
                cc += __shfl_xor(cc, 16); cc += __shfl_xor(cc, 32);
                if ((tid & 63) == 0) pout[(size_t)(tl0 + j) * 256] = cc;
            }
        }
    }
}

// ============ Kernel W: w_fused[i] = sum_d out_proj_w[d,i]*out_w[d] ============
__global__ __launch_bounds__(256) void k_fusew(const float* __restrict__ opw,
                                               const float* __restrict__ ow,
                                               float* __restrict__ wfv) {
    int i = blockIdx.x * 256 + threadIdx.x;
    float acc = 0.f;
    for (int dd = 0; dd < DMODEL; ++dd)
        acc += opw[(size_t)dd * DINNER + i] * ow[dd];
    wfv[i] = acc;
}

// ============ Kernel H: reduce 256 partials + de-normalize ============
__global__ __launch_bounds__(64) void k_final(const float* __restrict__ pacc,
                                              const float* __restrict__ meanv,
                                              const float* __restrict__ stdv,
                                              float* __restrict__ out) {
    int idx  = blockIdx.x;
    int lane = threadIdx.x;
    int b = idx / PREDLEN;
    float4 v = *(const float4*)(pacc + (size_t)idx * 256 + lane * 4);
    float tot = v.x + v.y + v.z + v.w;
#pragma unroll
    for (int off = 32; off; off >>= 1) tot += __shfl_xor(tot, off);
    if (lane == 0) out[idx] = tot * stdv[b * ENC_IN] + meanv[b * ENC_IN];
}

// ---------------- launch ----------------
extern "C" void kernel_launch(void* const* d_in, const int* in_sizes, int n_in,
                              void* d_out, int out_size, void* d_ws, size_t ws_size,
                              hipStream_t stream) {
    const float* x_enc     = (const float*)d_in[0];
    const float* x_mark    = (const float*)d_in[1];
    const float* conv_w    = (const float*)d_in[2];
    const float* temp_w    = (const float*)d_in[3];
    const float* in_proj_w = (const float*)d_in[4];
    const float* conv1d_w  = (const float*)d_in[5];
    const float* conv1d_b  = (const float*)d_in[6];
    const float* x_proj_w  = (const float*)d_in[7];
    const float* dt_proj_w = (const float*)d_in[8];
    const float* dt_proj_b = (const float*)d_in[9];
    const float* A_log     = (const float*)d_in[10];
    const float* Dvec      = (const float*)d_in[11];
    const float* out_proj_w= (const float*)d_in[12];
    const float* out_w     = (const float*)d_in[13];
    float* ws  = (float*)d_ws;
    float* out = (float*)d_out;

    float* xn    = ws + OFF_XN;
    float* meanv = ws + OFF_MEAN;
    float* stdv  = ws + OFF_STD;
    float* wfv   = ws + OFF_WF;
    float* pacc  = ws + OFF_PACC;
    float* dt_in = ws + OFF_DTIN;
    float* Btv   = ws + OFF_BT;
    float* Ctv   = ws + OFF_CT;
    float* gsT   = ws + OFF_GST;
    unsigned short* xb  = (unsigned short*)(ws + OFF_XB);
    unsigned short* wb  = (unsigned short*)(ws + OFF_WB);
    unsigned short* xiT = (unsigned short*)(ws + OFF_XIT);
    unsigned short* uT  = (unsigned short*)(ws + OFF_UT);
    unsigned short* dtT = (unsigned short*)(ws + OFF_DTT);   // overlays xiT
    float2* ab = (float2*)(ws + OFF_AB);                     // overlays xb (dead by then)

    k_norm<<<dim3(ENC_IN, BATCH), 64, 0, stream>>>(x_enc, xn, meanv, stdv);
    k_fusew<<<dim3(DINNER / 256), 256, 0, stream>>>(out_proj_w, out_w, wfv);
    k_build_x<<<dim3(DMODEL / 256, LSEQ, BATCH), 256, 0, stream>>>(xn, x_mark, conv_w, temp_w, xb);
    k_w2b<<<dim3((2 * DINNER * DMODEL) / 1024), 256, 0, stream>>>(in_proj_w, wb);
    k_gemm_inproj<<<dim3(16, 128), 256, 0, stream>>>(xb, wb, xiT, gsT);
    k_dwconv_silu<<<dim3(DINNER / 256, LSEQ / 32, BATCH), 256, 0, stream>>>(xiT, conv1d_w, conv1d_b, uT);
    k_gemm_xproj<<<dim3(MROWS / G2_BM), 256, 0, stream>>>(uT, x_proj_w, dt_in, Btv, Ctv);
    k_dtproj<<<dim3(DINNER / 256, MROWS / 64), 256, 0, stream>>>(dt_in, dt_proj_w, dt_proj_b, dtT);
    k_scan_p1<<<dim3(DINNER / 16, BATCH, NCHUNK), 256, 0, stream>>>(uT, dtT, Btv, A_log, ab);
    k_scan_p3<<<dim3(DINNER / 16, BATCH), 256, 0, stream>>>(uT, dtT, Btv, Ctv, A_log, Dvec, wfv,
                                                            gsT, ab, pacc);
    k_final<<<dim3(BATCH * PREDLEN), 64, 0, stream>>>(pacc, meanv, stdv, out);
}

// Round 6
// 540.467 us; speedup vs baseline: 2.2716x; 1.1242x over previous
//
#include <hip/hip_runtime.h>
#include <hip/hip_bf16.h>
#include <math.h>

// ---------------- problem constants ----------------
#define BATCH   32
#define LSEQ    512
#define ENC_IN  8
#define MARKD   4
#define DMODEL  512
#define DSTATE  16
#define DINNER  1024
#define DTRANK  32
#define PREDLEN 96
#define MROWS   (BATCH * LSEQ)          // 16384
#define TSTART  (LSEQ - PREDLEN)        // 416
#define NCHUNK  3                       // parallel-scan chunks of 128 over t<384

// ---------------- workspace layout (float units), total 101.5 MiB ----------------
#define OFF_XN    ((size_t)0)            // 131072 (wbx bf16 overlays after build_x)
#define OFF_MEAN  ((size_t)131072)       // 256
#define OFF_STD   ((size_t)131328)       // 256
#define OFF_WF    ((size_t)131584)       // 1024
#define OFF_PACC  ((size_t)132608)       // 32*96*256 = 786432
#define OFF_XB    ((size_t)919040)       // 16384x512 bf16 = 4194304 f  (alpha/beta overlays)
#define OFF_WB    ((size_t)5113344)      // 2048x512 bf16 = 524288 f
#define OFF_DTIN  ((size_t)5637632)      // 16384x32 fp32 = 524288 f
#define OFF_BT    ((size_t)6161920)      // 32x16x512 fp32 = 262144 f
#define OFF_CT    ((size_t)6424064)      // 262144 f
#define OFF_GST   ((size_t)6686208)      // 32x1024x96 fp32 = 3145728 f
#define OFF_XIT   ((size_t)9831936)      // [b][d][t] bf16 = 8388608 f (dt_T overlays)
#define OFF_UT    ((size_t)18220544)     // [b][d][t] bf16 = 8388608 f
#define OFF_DTT   OFF_XIT                // dt_T reuses xi_T (dead after dwconv)
#define OFF_AB    OFF_XB                 // alpha/beta: 3145728 f <= 4194304
#define OFF_WBX   OFF_XN                 // x_proj_w bf16: 65536 shorts = 32768 f <= 131072
// end: 26609152 floats = 101.5 MiB

typedef __bf16 bf16_8 __attribute__((ext_vector_type(8)));
typedef float  f32x4  __attribute__((ext_vector_type(4)));

static __device__ __forceinline__ float b2f(unsigned short h) {
    union { float f; unsigned u; } v; v.u = ((unsigned)h) << 16; return v.f;
}
static __device__ __forceinline__ unsigned short f2b(float f) {
    __hip_bfloat16 h = __float2bfloat16(f);   // RNE
    union { __hip_bfloat16 b; unsigned short s; } v; v.b = h; return v.s;
}
static __device__ __forceinline__ float blo(unsigned v) {
    union { float f; unsigned u; } x; x.u = v << 16; return x.f;
}
static __device__ __forceinline__ float bhi(unsigned v) {
    union { float f; unsigned u; } x; x.u = v & 0xffff0000u; return x.f;
}

// ============ Kernel A: per-(b,c) mean/std + normalize ============
__global__ __launch_bounds__(64) void k_norm(const float* __restrict__ xe,
                                             float* __restrict__ xn,
                                             float* __restrict__ meanv,
                                             float* __restrict__ stdv) {
    int c = blockIdx.x;
    int b = blockIdx.y;
    int lane = threadIdx.x;
    const float* p = xe + ((size_t)b * LSEQ) * ENC_IN + c;
    float vals[8];
    float s = 0.f, s2 = 0.f;
#pragma unroll
    for (int i = 0; i < 8; ++i) {
        float v = p[(size_t)(lane + i * 64) * ENC_IN];
        vals[i] = v; s += v; s2 += v * v;
    }
#pragma unroll
    for (int off = 32; off; off >>= 1) {
        s  += __shfl_xor(s,  off);
        s2 += __shfl_xor(s2, off);
    }
    float mean = s * (1.f / LSEQ);
    float var  = s2 * (1.f / LSEQ) - mean * mean;
    float sd   = sqrtf(var + 1e-5f);
    float rstd = 1.f / sd;
    if (lane == 0) { meanv[b * ENC_IN + c] = mean; stdv[b * ENC_IN + c] = sd; }
#pragma unroll
    for (int i = 0; i < 8; ++i)
        xn[((size_t)b * LSEQ + lane + i * 64) * ENC_IN + c] = (vals[i] - mean) * rstd;
}

// ============ Kernel B: x = token_conv(xn) + temporal + pos_emb  (bf16 out) ============
__global__ __launch_bounds__(256) void k_build_x(const float* __restrict__ xn,
                                                 const float* __restrict__ xmark,
                                                 const float* __restrict__ convw,
                                                 const float* __restrict__ tempw,
                                                 unsigned short* __restrict__ xb) {
    int d = blockIdx.x * 256 + threadIdx.x;
    int l = blockIdx.y;
    int b = blockIdx.z;
    int lm = (l + LSEQ - 1) & (LSEQ - 1);     // circular pad per reference
    int lp = (l + 1) & (LSEQ - 1);
    const float* r0 = xn + ((size_t)b * LSEQ + lm) * ENC_IN;
    const float* r1 = xn + ((size_t)b * LSEQ + l ) * ENC_IN;
    const float* r2 = xn + ((size_t)b * LSEQ + lp) * ENC_IN;
    const float* w  = convw + (size_t)d * (ENC_IN * 3);
    float acc = 0.f;
#pragma unroll
    for (int i = 0; i < ENC_IN; ++i)
        acc += r0[i] * w[i * 3 + 0] + r1[i] * w[i * 3 + 1] + r2[i] * w[i * 3 + 2];
    const float* tw = tempw + (size_t)d * MARKD;
    const float* xm = xmark + ((size_t)b * LSEQ + l) * MARKD;
    acc += xm[0] * tw[0] + xm[1] * tw[1] + xm[2] * tw[2] + xm[3] * tw[3];
    float freq = __expf(-(float)(d & ~1) * (9.210340371976184f / (float)DMODEL));
    float ang  = (float)l * freq;
    acc += (d & 1) ? cosf(ang) : sinf(ang);
    xb[((size_t)b * LSEQ + l) * DMODEL + d] = f2b(acc);
}

// ============ Kernel W2B: fp32 -> bf16 cast (generic) ============
__global__ __launch_bounds__(256) void k_w2b(const float* __restrict__ w,
                                             unsigned short* __restrict__ wb) {
    int i = (blockIdx.x * 256 + threadIdx.x) * 4;
    float4 v = *(const float4*)(w + i);
    ushort4 o;
    o.x = f2b(v.x); o.y = f2b(v.y); o.z = f2b(v.z); o.w = f2b(v.w);
    *(ushort4*)(wb + i) = o;
}

// ============ Kernel C: in_proj GEMM via bf16 MFMA ============
// n<1024 -> xi_T[b][d][t] bf16, written COALESCED via LDS transpose.
// n>=1024 -> z: m-tiles at (m0&511)==384; silu -> gs_T[b][d][tl] fp32.
#define TP_STRIDE 136   // shorts; 272B rows -> 16B-aligned b128 reads
__global__ __launch_bounds__(256) void k_gemm_inproj(const unsigned short* __restrict__ xb,
                                                     const unsigned short* __restrict__ wb,
                                                     unsigned short* __restrict__ xiT,
                                                     float* __restrict__ gsT) {
    int n0 = blockIdx.x * 128;
    int m0 = blockIdx.y * 128;
    if (n0 >= DINNER && (m0 & (LSEQ - 1)) != 384) return;

    __shared__ unsigned char smem[128 * TP_STRIDE * 2];   // 34816 B
    uint4* As4 = (uint4*)smem;          // 8 KB
    uint4* Bs4 = As4 + 512;             // 8 KB
    unsigned short* T = (unsigned short*)smem;  // transpose buffer (epilogue only)

    int tid  = threadIdx.x;
    int lane = tid & 63;
    int w    = tid >> 6;
    int wm   = (w & 1) * 64;
    int wn   = (w >> 1) * 64;
    f32x4 acc[4][4] = {};

    for (int k0 = 0; k0 < DMODEL; k0 += 32) {
#pragma unroll
        for (int hh = 0; hh < 2; ++hh) {
            int c  = tid + hh * 256;
            int im = c >> 6;
            int lc = c & 63;
            int r  = im * 16 + (lc & 15);
            int kq = lc >> 4;
            As4[c] = *(const uint4*)(xb + (size_t)(m0 + r) * DMODEL + k0 + kq * 8);
            Bs4[c] = *(const uint4*)(wb + (size_t)(n0 + r) * DMODEL + k0 + kq * 8);
        }
        __syncthreads();
        bf16_8 af[4], bf[4];
#pragma unroll
        for (int i = 0; i < 4; ++i) {
            af[i] = ((const bf16_8*)As4)[((wm >> 4) + i) * 64 + lane];
            bf[i] = ((const bf16_8*)Bs4)[((wn >> 4) + i) * 64 + lane];
        }
#pragma unroll
        for (int i = 0; i < 4; ++i)
#pragma unroll
            for (int j = 0; j < 4; ++j)
                acc[i][j] = __builtin_amdgcn_mfma_f32_16x16x32_bf16(af[i], bf[j], acc[i][j], 0, 0, 0);
        __syncthreads();
    }

    // C/D layout: col = lane&15 (n), row = (lane>>4)*4 + reg (m)
    int col  = lane & 15;
    int quad = lane >> 4;
    if (n0 < DINNER) {
        // dump frags into LDS as T[n][m] bf16, then write coalesced along t(=m)
#pragma unroll
        for (int i = 0; i < 4; ++i) {
#pragma unroll
            for (int j = 0; j < 4; ++j) {
                int nn = wn + j * 16 + col;
                int mm = wm + i * 16 + quad * 4;
                ushort4 o;
                o.x = f2b(acc[i][j][0]); o.y = f2b(acc[i][j][1]);
                o.z = f2b(acc[i][j][2]); o.w = f2b(acc[i][j][3]);
                *(ushort4*)&T[nn * TP_STRIDE + mm] = o;
            }
        }
        __syncthreads();
        int bI = m0 >> 9;
        int tglob = m0 & (LSEQ - 1);
#pragma unroll
        for (int it = 0; it < 8; ++it) {
            int c  = tid + it * 256;      // 0..2047
            int nn = c >> 4;              // 0..127
            int tc = c & 15;              // 0..15 (8-t chunks)
            uint4 v = *(const uint4*)&T[nn * TP_STRIDE + tc * 8];
            *(uint4*)(xiT + ((size_t)bI * DINNER + n0 + nn) * LSEQ + tglob + tc * 8) = v;
        }
    } else {
#pragma unroll
        for (int i = 0; i < 4; ++i) {
#pragma unroll
            for (int j = 0; j < 4; ++j) {
                int m = m0 + wm + i * 16 + quad * 4;
                int t = m & (LSEQ - 1);
                if (t < TSTART) continue;
                int b = m >> 9;
                int nz = n0 - DINNER + wn + j * 16 + col;
                float4 g;
                float v0 = acc[i][j][0], v1 = acc[i][j][1], v2 = acc[i][j][2], v3 = acc[i][j][3];
                g.x = v0 / (1.f + __expf(-v0));
                g.y = v1 / (1.f + __expf(-v1));
                g.z = v2 / (1.f + __expf(-v2));
                g.w = v3 / (1.f + __expf(-v3));
                *(float4*)(gsT + ((size_t)b * DINNER + nz) * PREDLEN + (t - TSTART)) = g;
            }
        }
    }
}

// ============ Kernel D: causal depthwise conv (k=4) + bias + silu ============
// wave = one d-row (512 t); lane = 8-t chunk; halo via shfl; fully coalesced.
__global__ __launch_bounds__(256) void k_dwconv_silu(const unsigned short* __restrict__ xiT,
                                                     const float* __restrict__ cw,
                                                     const float* __restrict__ cb,
                                                     unsigned short* __restrict__ uT) {
    int lane = threadIdx.x & 63;
    int w    = threadIdx.x >> 6;
    int d = blockIdx.x * 4 + w;
    int b = blockIdx.y;
    const unsigned short* src = xiT + ((size_t)b * DINNER + d) * LSEQ;
    uint4 cur = *(const uint4*)(src + lane * 8);
    unsigned pw = (unsigned)__shfl_up((int)cur.w, 1);   // t0-2 (lo), t0-1 (hi)
    unsigned pz = (unsigned)__shfl_up((int)cur.z, 1);   // t0-4 (lo), t0-3 (hi)
    if (lane == 0) { pw = 0u; pz = 0u; }                // causal zero pad
    float4 w4 = *(const float4*)(cw + (size_t)d * 4);
    float bias = cb[d];
    float win[11];
    win[0] = bhi(pz); win[1] = blo(pw); win[2] = bhi(pw);
    const unsigned* cp = (const unsigned*)&cur;
#pragma unroll
    for (int q = 0; q < 4; ++q) {
        win[3 + 2 * q] = blo(cp[q]);
        win[4 + 2 * q] = bhi(cp[q]);
    }
    unsigned ov[4];
#pragma unroll
    for (int tt = 0; tt < 8; ++tt) {
        float a = bias + win[tt] * w4.x + win[tt + 1] * w4.y
                       + win[tt + 2] * w4.z + win[tt + 3] * w4.w;
        float uv = a / (1.f + __expf(-a));
        unsigned short us = f2b(uv);
        if (tt & 1) ov[tt >> 1] |= ((unsigned)us) << 16;
        else        ov[tt >> 1]  = us;
    }
    *(uint4*)(uT + ((size_t)b * DINNER + d) * LSEQ + lane * 8) = *(uint4*)ov;
}

// ============ Kernel E: x_proj GEMM via bf16 MFMA (A transposed through LDS) ============
// out[m, 0..31] -> dt_in ; out[m, 32..47] -> Bt[b][s][t] ; out[m, 48..63] -> Ct.
#define XP_STRIDE 132   // shorts; 264B rows: b64 staging writes, ~2-way u16 frag reads
__global__ __launch_bounds__(256) void k_gemm_xproj2(const unsigned short* __restrict__ uT,
                                                     const unsigned short* __restrict__ wbx,
                                                     float* __restrict__ dt_in,
                                                     float* __restrict__ Bt,
                                                     float* __restrict__ Ct) {
    __shared__ unsigned short Asl[32 * XP_STRIDE];   // [k][m] 32x128 + pad
    int tid  = threadIdx.x;
    int lane = tid & 63;
    int w    = tid >> 6;
    int quad = lane >> 4;
    int col  = lane & 15;
    int m0 = blockIdx.x * 128;
    int b  = m0 >> 9;
    int t0 = m0 & (LSEQ - 1);
    f32x4 acc[2][4] = {};
    for (int k0 = 0; k0 < DINNER; k0 += 32) {
#pragma unroll
        for (int h = 0; h < 2; ++h) {
            int c  = tid + h * 256;       // 0..511
            int k  = c >> 4;              // 0..31
            int mc = (c & 15) * 8;        // 0..120
            uint4 v = *(const uint4*)(uT + ((size_t)b * DINNER + k0 + k) * LSEQ + t0 + mc);
            *(uint2*)&Asl[k * XP_STRIDE + mc]     = make_uint2(v.x, v.y);
            *(uint2*)&Asl[k * XP_STRIDE + mc + 4] = make_uint2(v.z, v.w);
        }
        __syncthreads();
        bf16_8 bf[4];
#pragma unroll
        for (int j = 0; j < 4; ++j)
            bf[j] = *((const bf16_8*)(wbx + (size_t)(j * 16 + col) * DINNER + k0 + quad * 8));
#pragma unroll
        for (int i = 0; i < 2; ++i) {
            union { bf16_8 v; unsigned short u[8]; } af;
            int m = w * 32 + i * 16 + col;
#pragma unroll
            for (int j8 = 0; j8 < 8; ++j8)
                af.u[j8] = Asl[(quad * 8 + j8) * XP_STRIDE + m];
#pragma unroll
            for (int j = 0; j < 4; ++j)
                acc[i][j] = __builtin_amdgcn_mfma_f32_16x16x32_bf16(af.v, bf[j], acc[i][j], 0, 0, 0);
        }
        __syncthreads();
    }
#pragma unroll
    for (int i = 0; i < 2; ++i) {
        int mrow = w * 32 + i * 16 + quad * 4;
#pragma unroll
        for (int j = 0; j < 4; ++j) {
            int n = j * 16 + col;
            if (j < 2) {
#pragma unroll
                for (int r = 0; r < 4; ++r)
                    dt_in[(size_t)(m0 + mrow + r) * DTRANK + n] = acc[i][j][r];
            } else {
                float4 st = make_float4(acc[i][j][0], acc[i][j][1], acc[i][j][2], acc[i][j][3]);
                int t = t0 + mrow;
                if (j == 2) *(float4*)(Bt + ((size_t)b * DSTATE + (n - 32)) * LSEQ + t) = st;
                else        *(float4*)(Ct + ((size_t)b * DSTATE + (n - 48)) * LSEQ + t) = st;
            }
        }
    }
}

// ============ Kernel F: dt = softplus(dt_in @ dt_proj_w.T + b) -> dt_T[b][d][t] bf16 ============
// thread = (d, 8-t chunk): coalesced uint4 writes; xs padded [64][33] (conflict-free).
__global__ __launch_bounds__(256) void k_dtproj(const float* __restrict__ dt_in,
                                                const float* __restrict__ dpw,
                                                const float* __restrict__ dpb,
                                                unsigned short* __restrict__ dtT) {
    __shared__ float xs[64][33];
    int tid  = threadIdx.x;
    int dloc = tid >> 3;                 // 0..31
    int tc   = tid & 7;                  // 0..7
    int d  = blockIdx.x * 32 + dloc;
    int m0 = blockIdx.y * 64;
    int b  = m0 >> 9;
    int t0 = m0 & (LSEQ - 1);
    for (int f = tid; f < 512; f += 256) {
        int row = f >> 3;
        int c   = (f & 7) << 2;
        float4 v = *(const float4*)(dt_in + (size_t)(m0 + row) * DTRANK + c);
        xs[row][c] = v.x; xs[row][c + 1] = v.y; xs[row][c + 2] = v.z; xs[row][c + 3] = v.w;
    }
    __syncthreads();
    float wv[32];
#pragma unroll
    for (int r = 0; r < 32; r += 4) {
        float4 v = *(const float4*)(dpw + (size_t)d * DTRANK + r);
        wv[r] = v.x; wv[r + 1] = v.y; wv[r + 2] = v.z; wv[r + 3] = v.w;
    }
    float bias = dpb[d];
    unsigned ov[4];
#pragma unroll
    for (int j = 0; j < 8; ++j) {
        int m = tc * 8 + j;
        float a = bias;
#pragma unroll
        for (int r = 0; r < 32; ++r) a += xs[m][r] * wv[r];
        float sp = (a > 20.f) ? a : log1pf(__expf(a));
        unsigned short us = f2b(sp);
        if (j & 1) ov[j >> 1] |= ((unsigned)us) << 16;
        else       ov[j >> 1]  = us;
    }
    *(uint4*)(dtT + ((size_t)b * DINNER + d) * LSEQ + t0 + tc * 8) = *(uint4*)ov;
}

// ============ Kernel G1: scan phase 1 — per-chunk (alpha, beta) over t<384 ============
__global__ __launch_bounds__(256) void k_scan_p1(const unsigned short* __restrict__ uT,
                                                 const unsigned short* __restrict__ dtT,
                                                 const float* __restrict__ Bt,
                                                 const float* __restrict__ A_log,
                                                 float2* __restrict__ ab) {
    int b    = blockIdx.y;
    int c    = blockIdx.z;
    int tid  = threadIdx.x;
    int s    = tid & 15;
    int dloc = tid >> 4;
    int d    = blockIdx.x * 16 + dloc;
    float As2 = -__expf(A_log[(size_t)d * DSTATE + s]) * 1.44269504088896f;
    const unsigned short* up = uT  + ((size_t)b * DINNER + d) * LSEQ;
    const unsigned short* dp = dtT + ((size_t)b * DINNER + d) * LSEQ;
    const float* Bp = Bt + ((size_t)b * DSTATE + s) * LSEQ;
    float beta = 0.f, asum = 0.f;
    int tbeg = c * 128;
    for (int t8 = tbeg; t8 < tbeg + 128; t8 += 8) {
        uint4 uq = *(const uint4*)(up + t8);
        uint4 dq = *(const uint4*)(dp + t8);
        float4 B0 = *(const float4*)(Bp + t8);
        float4 B1 = *(const float4*)(Bp + t8 + 4);
        float uu[8], dd[8];
        const unsigned* uqp = (const unsigned*)&uq;
        const unsigned* dqp = (const unsigned*)&dq;
#pragma unroll
        for (int q = 0; q < 4; ++q) {
            uu[q * 2] = blo(uqp[q]); uu[q * 2 + 1] = bhi(uqp[q]);
            dd[q * 2] = blo(dqp[q]); dd[q * 2 + 1] = bhi(dqp[q]);
        }
        float Bv[8] = {B0.x, B0.y, B0.z, B0.w, B1.x, B1.y, B1.z, B1.w};
#pragma unroll
        for (int j = 0; j < 8; ++j) {
            float e = exp2f(dd[j] * As2);
            beta = e * beta + (dd[j] * uu[j]) * Bv[j];
            asum += dd[j];
        }
    }
    float alpha = exp2f(asum * As2);
    ab[((size_t)(b * DINNER + d) * NCHUNK + c) * DSTATE + s] = make_float2(alpha, beta);
}

// ============ Kernel G2: scan phase 2+3 — stitch h(384), run [384,512), emit outputs ============
__global__ __launch_bounds__(256) void k_scan_p3(const unsigned short* __restrict__ uT,
                                                 const unsigned short* __restrict__ dtT,
                                                 const float* __restrict__ Bt,
                                                 const float* __restrict__ Ct,
                                                 const float* __restrict__ A_log,
                                                 const float* __restrict__ Dvec,
                                                 const float* __restrict__ wf,
                                                 const float* __restrict__ gsT,
                                                 const float2* __restrict__ ab,
                                                 float* __restrict__ pacc) {
    int b    = blockIdx.y;
    int tid  = threadIdx.x;
    int s    = tid & 15;
    int dloc = tid >> 4;
    int d    = blockIdx.x * 16 + dloc;
    float As2 = -__expf(A_log[(size_t)d * DSTATE + s]) * 1.44269504088896f;
    float Dd  = Dvec[d];
    float wfd = wf[d];
    const float2* abp = ab + (size_t)(b * DINNER + d) * NCHUNK * DSTATE + s;
    float h = 0.f;
#pragma unroll
    for (int c = 0; c < NCHUNK; ++c) {
        float2 v = abp[c * DSTATE];
        h = v.y + v.x * h;
    }
    const unsigned short* up = uT  + ((size_t)b * DINNER + d) * LSEQ;
    const unsigned short* dp = dtT + ((size_t)b * DINNER + d) * LSEQ;
    const float* Bp = Bt + ((size_t)b * DSTATE + s) * LSEQ;
    const float* Cp = Ct + ((size_t)b * DSTATE + s) * LSEQ;
    const float* gp = gsT + ((size_t)b * DINNER + d) * PREDLEN;
    float* pout = pacc + ((size_t)b * PREDLEN) * 256 + blockIdx.x * 4 + (tid >> 6);
    for (int t8 = NCHUNK * 128; t8 < LSEQ; t8 += 8) {
        uint4 uq = *(const uint4*)(up + t8);
        uint4 dq = *(const uint4*)(dp + t8);
        float4 B0 = *(const float4*)(Bp + t8);
        float4 B1 = *(const float4*)(Bp + t8 + 4);
        float4 C0 = *(const float4*)(Cp + t8);
        float4 C1 = *(const float4*)(Cp + t8 + 4);
        float uu[8], dd[8];
        const unsigned* uqp = (const unsigned*)&uq;
        const unsigned* dqp = (const unsigned*)&dq;
#pragma unroll
        for (int q = 0; q < 4; ++q) {
            uu[q * 2] = blo(uqp[q]); uu[q * 2 + 1] = bhi(uqp[q]);
            dd[q * 2] = blo(dqp[q]); dd[q * 2 + 1] = bhi(dqp[q]);
        }
        float Bv[8] = {B0.x, B0.y, B0.z, B0.w, B1.x, B1.y, B1.z, B1.w};
        float Cv[8] = {C0.x, C0.y, C0.z, C0.w, C1.x, C1.y, C1.z, C1.w};
        if (t8 < TSTART) {
#pragma unroll
            for (int j = 0; j < 8; ++j)
                h = exp2f(dd[j] * As2) * h + (dd[j] * uu[j]) * Bv[j];
        } else {
            int tl0 = t8 - TSTART;
            float4 g0 = *(const float4*)(gp + tl0);
            float4 g1 = *(const float4*)(gp + tl0 + 4);
            float gv[8] = {g0.x, g0.y, g0.z, g0.w, g1.x, g1.y, g1.z, g1.w};
#pragma unroll
            for (int j = 0; j < 8; ++j) {
                h = exp2f(dd[j] * As2) * h + (dd[j] * uu[j]) * Bv[j];
                float y = h * Cv[j];
                y += __shfl_xor(y, 1); y += __shfl_xor(y, 2);
                y += __shfl_xor(y, 4); y += __shfl_xor(y, 8);
                float cc = (s == 0) ? (y + uu[j] * Dd) * gv[j] * wfd : 0.f;
                cc += __shfl_xor(cc, 16); cc += __shfl_xor(cc, 32);
                if ((tid & 63) == 0) pout[(size_t)(tl0 + j) * 256] = cc;
            }
        }
    }
}

// ============ Kernel W: w_fused[i] = sum_d out_proj_w[d,i]*out_w[d] ============
__global__ __launch_bounds__(256) void k_fusew(const float* __restrict__ opw,
                                               const float* __restrict__ ow,
                                               float* __restrict__ wfv) {
    int i = blockIdx.x * 256 + threadIdx.x;
    float acc = 0.f;
    for (int dd = 0; dd < DMODEL; ++dd)
        acc += opw[(size_t)dd * DINNER + i] * ow[dd];
    wfv[i] = acc;
}

// ============ Kernel H: reduce 256 partials + de-normalize ============
__global__ __launch_bounds__(64) void k_final(const float* __restrict__ pacc,
                                              const float* __restrict__ meanv,
                                              const float* __restrict__ stdv,
                                              float* __restrict__ out) {
    int idx  = blockIdx.x;
    int lane = threadIdx.x;
    int b = idx / PREDLEN;
    float4 v = *(const float4*)(pacc + (size_t)idx * 256 + lane * 4);
    float tot = v.x + v.y + v.z + v.w;
#pragma unroll
    for (int off = 32; off; off >>= 1) tot += __shfl_xor(tot, off);
    if (lane == 0) out[idx] = tot * stdv[b * ENC_IN] + meanv[b * ENC_IN];
}

// ---------------- launch ----------------
extern "C" void kernel_launch(void* const* d_in, const int* in_sizes, int n_in,
                              void* d_out, int out_size, void* d_ws, size_t ws_size,
                              hipStream_t stream) {
    const float* x_enc     = (const float*)d_in[0];
    const float* x_mark    = (const float*)d_in[1];
    const float* conv_w    = (const float*)d_in[2];
    const float* temp_w    = (const float*)d_in[3];
    const float* in_proj_w = (const float*)d_in[4];
    const float* conv1d_w  = (const float*)d_in[5];
    const float* conv1d_b  = (const float*)d_in[6];
    const float* x_proj_w  = (const float*)d_in[7];
    const float* dt_proj_w = (const float*)d_in[8];
    const float* dt_proj_b = (const float*)d_in[9];
    const float* A_log     = (const float*)d_in[10];
    const float* Dvec      = (const float*)d_in[11];
    const float* out_proj_w= (const float*)d_in[12];
    const float* out_w     = (const float*)d_in[13];
    float* ws  = (float*)d_ws;
    float* out = (float*)d_out;

    float* xn    = ws + OFF_XN;
    float* meanv = ws + OFF_MEAN;
    float* stdv  = ws + OFF_STD;
    float* wfv   = ws + OFF_WF;
    float* pacc  = ws + OFF_PACC;
    float* dt_in = ws + OFF_DTIN;
    float* Btv   = ws + OFF_BT;
    float* Ctv   = ws + OFF_CT;
    float* gsT   = ws + OFF_GST;
    unsigned short* xb  = (unsigned short*)(ws + OFF_XB);
    unsigned short* wb  = (unsigned short*)(ws + OFF_WB);
    unsigned short* wbx = (unsigned short*)(ws + OFF_WBX);  // overlays xn (dead after build_x)
    unsigned short* xiT = (unsigned short*)(ws + OFF_XIT);
    unsigned short* uT  = (unsigned short*)(ws + OFF_UT);
    unsigned short* dtT = (unsigned short*)(ws + OFF_DTT);  // overlays xiT
    float2* ab = (float2*)(ws + OFF_AB);                    // overlays xb

    k_norm<<<dim3(ENC_IN, BATCH), 64, 0, stream>>>(x_enc, xn, meanv, stdv);
    k_fusew<<<dim3(DINNER / 256), 256, 0, stream>>>(out_proj_w, out_w, wfv);
    k_build_x<<<dim3(DMODEL / 256, LSEQ, BATCH), 256, 0, stream>>>(xn, x_mark, conv_w, temp_w, xb);
    k_w2b<<<dim3((2 * DINNER * DMODEL) / 1024), 256, 0, stream>>>(in_proj_w, wb);
    k_w2b<<<dim3((64 * DINNER) / 1024), 256, 0, stream>>>(x_proj_w, wbx);   // after build_x (overlays xn)
    k_gemm_inproj<<<dim3(16, 128), 256, 0, stream>>>(xb, wb, xiT, gsT);
    k_dwconv_silu<<<dim3(DINNER / 4, BATCH), 256, 0, stream>>>(xiT, conv1d_w, conv1d_b, uT);
    k_gemm_xproj2<<<dim3(MROWS / 128), 256, 0, stream>>>(uT, wbx, dt_in, Btv, Ctv);
    k_dtproj<<<dim3(DINNER / 32, MROWS / 64), 256, 0, stream>>>(dt_in, dt_proj_w, dt_proj_b, dtT);
    k_scan_p1<<<dim3(DINNER / 16, BATCH, NCHUNK), 256, 0, stream>>>(uT, dtT, Btv, A_log, ab);
    k_scan_p3<<<dim3(DINNER / 16, BATCH), 256, 0, stream>>>(uT, dtT, Btv, Ctv, A_log, Dvec, wfv,
                                                            gsT, ab, pacc);
    k_final<<<dim3(BATCH * PREDLEN), 64, 0, stream>>>(pacc, meanv, stdv, out);
}

// Round 7
// 516.893 us; speedup vs baseline: 2.3752x; 1.0456x over previous
//
#include <hip/hip_runtime.h>
#include <hip/hip_bf16.h>
#include <math.h>

// ---------------- problem constants ----------------
#define BATCH   32
#define LSEQ    512
#define ENC_IN  8
#define MARKD   4
#define DMODEL  512
#define DSTATE  16
#define DINNER  1024
#define DTRANK  32
#define PREDLEN 96
#define MROWS   (BATCH * LSEQ)          // 16384
#define TSTART  (LSEQ - PREDLEN)        // 416
#define NCHUNK  3                       // parallel-scan chunks of 128 over t<384

// ---------------- workspace layout (float units), total 107.5 MiB ----------------
#define OFF_XN    ((size_t)0)            // 131072 (wbx bf16 overlays after build_x)
#define OFF_MEAN  ((size_t)131072)       // 256
#define OFF_STD   ((size_t)131328)       // 256
#define OFF_WF    ((size_t)131584)       // 1024
#define OFF_PACC  ((size_t)132608)       // 32*96*256 = 786432
#define OFF_XB    ((size_t)919040)       // 16384x512 bf16 = 4194304 f  (alpha/beta overlays)
#define OFF_WB    ((size_t)5113344)      // 2048x512 bf16 = 524288 f
#define OFF_DTIN  ((size_t)5637632)      // 16384x32 fp32 = 524288 f (wfp partials overlay early)
#define OFF_BT    ((size_t)6161920)      // 32x16x512 fp32 = 262144 f
#define OFF_CT    ((size_t)6424064)      // 262144 f
#define OFF_GST   ((size_t)6686208)      // 32x1024x96 fp32 = 3145728 f (g, then gw in place)
#define OFF_XIT   ((size_t)9831936)      // [b][d][t] bf16 = 8388608 f (dt_T overlays)
#define OFF_UT    ((size_t)18220544)     // [b][d][t] bf16 = 8388608 f
#define OFF_C0    ((size_t)26609152)     // 32x1024x96 bf16 = 1572864 f
#define OFF_DTT   OFF_XIT                // dt_T reuses xi_T (dead after dwconv)
#define OFF_AB    OFF_XB                 // alpha/beta: 3145728 f <= 4194304
#define OFF_WBX   OFF_XN                 // x_proj_w bf16: 32768 f <= 131072
#define OFF_WFP   OFF_DTIN               // fusew partials: 4096 f (dt_in written later)
// end: 28182016 floats = 107.5 MiB (<= 112.7 known-good)

typedef __bf16 bf16_8 __attribute__((ext_vector_type(8)));
typedef float  f32x4  __attribute__((ext_vector_type(4)));

static __device__ __forceinline__ float b2f(unsigned short h) {
    union { float f; unsigned u; } v; v.u = ((unsigned)h) << 16; return v.f;
}
static __device__ __forceinline__ unsigned short f2b(float f) {
    __hip_bfloat16 h = __float2bfloat16(f);   // RNE
    union { __hip_bfloat16 b; unsigned short s; } v; v.b = h; return v.s;
}
static __device__ __forceinline__ float blo(unsigned v) {
    union { float f; unsigned u; } x; x.u = v << 16; return x.f;
}
static __device__ __forceinline__ float bhi(unsigned v) {
    union { float f; unsigned u; } x; x.u = v & 0xffff0000u; return x.f;
}

// ============ Kernel A: per-(b,c) mean/std + normalize ============
__global__ __launch_bounds__(64) void k_norm(const float* __restrict__ xe,
                                             float* __restrict__ xn,
                                             float* __restrict__ meanv,
                                             float* __restrict__ stdv) {
    int c = blockIdx.x;
    int b = blockIdx.y;
    int lane = threadIdx.x;
    const float* p = xe + ((size_t)b * LSEQ) * ENC_IN + c;
    float vals[8];
    float s = 0.f, s2 = 0.f;
#pragma unroll
    for (int i = 0; i < 8; ++i) {
        float v = p[(size_t)(lane + i * 64) * ENC_IN];
        vals[i] = v; s += v; s2 += v * v;
    }
#pragma unroll
    for (int off = 32; off; off >>= 1) {
        s  += __shfl_xor(s,  off);
        s2 += __shfl_xor(s2, off);
    }
    float mean = s * (1.f / LSEQ);
    float var  = s2 * (1.f / LSEQ) - mean * mean;
    float sd   = sqrtf(var + 1e-5f);
    float rstd = 1.f / sd;
    if (lane == 0) { meanv[b * ENC_IN + c] = mean; stdv[b * ENC_IN + c] = sd; }
#pragma unroll
    for (int i = 0; i < 8; ++i)
        xn[((size_t)b * LSEQ + lane + i * 64) * ENC_IN + c] = (vals[i] - mean) * rstd;
}

// ============ Kernel B: x = token_conv(xn) + temporal + pos_emb  (bf16 out) ============
__global__ __launch_bounds__(256) void k_build_x(const float* __restrict__ xn,
                                                 const float* __restrict__ xmark,
                                                 const float* __restrict__ convw,
                                                 const float* __restrict__ tempw,
                                                 unsigned short* __restrict__ xb) {
    int d = blockIdx.x * 256 + threadIdx.x;
    int l = blockIdx.y;
    int b = blockIdx.z;
    int lm = (l + LSEQ - 1) & (LSEQ - 1);     // circular pad per reference
    int lp = (l + 1) & (LSEQ - 1);
    const float* r0 = xn + ((size_t)b * LSEQ + lm) * ENC_IN;
    const float* r1 = xn + ((size_t)b * LSEQ + l ) * ENC_IN;
    const float* r2 = xn + ((size_t)b * LSEQ + lp) * ENC_IN;
    const float* w  = convw + (size_t)d * (ENC_IN * 3);
    float acc = 0.f;
#pragma unroll
    for (int i = 0; i < ENC_IN; ++i)
        acc += r0[i] * w[i * 3 + 0] + r1[i] * w[i * 3 + 1] + r2[i] * w[i * 3 + 2];
    const float* tw = tempw + (size_t)d * MARKD;
    const float* xm = xmark + ((size_t)b * LSEQ + l) * MARKD;
    acc += xm[0] * tw[0] + xm[1] * tw[1] + xm[2] * tw[2] + xm[3] * tw[3];
    float freq = __expf(-(float)(d & ~1) * (9.210340371976184f / (float)DMODEL));
    float ang  = (float)l * freq;
    acc += (d & 1) ? cosf(ang) : sinf(ang);
    xb[((size_t)b * LSEQ + l) * DMODEL + d] = f2b(acc);
}

// ============ Kernel W2B: fp32 -> bf16 cast (generic) ============
__global__ __launch_bounds__(256) void k_w2b(const float* __restrict__ w,
                                             unsigned short* __restrict__ wb) {
    int i = (blockIdx.x * 256 + threadIdx.x) * 4;
    float4 v = *(const float4*)(w + i);
    ushort4 o;
    o.x = f2b(v.x); o.y = f2b(v.y); o.z = f2b(v.z); o.w = f2b(v.w);
    *(ushort4*)(wb + i) = o;
}

// ============ Kernel C: in_proj GEMM via bf16 MFMA ============
#define TP_STRIDE 136
__global__ __launch_bounds__(256) void k_gemm_inproj(const unsigned short* __restrict__ xb,
                                                     const unsigned short* __restrict__ wb,
                                                     unsigned short* __restrict__ xiT,
                                                     float* __restrict__ gsT) {
    int n0 = blockIdx.x * 128;
    int m0 = blockIdx.y * 128;
    if (n0 >= DINNER && (m0 & (LSEQ - 1)) != 384) return;

    __shared__ unsigned char smem[128 * TP_STRIDE * 2];
    uint4* As4 = (uint4*)smem;
    uint4* Bs4 = As4 + 512;
    unsigned short* T = (unsigned short*)smem;

    int tid  = threadIdx.x;
    int lane = tid & 63;
    int w    = tid >> 6;
    int wm   = (w & 1) * 64;
    int wn   = (w >> 1) * 64;
    f32x4 acc[4][4] = {};

    for (int k0 = 0; k0 < DMODEL; k0 += 32) {
#pragma unroll
        for (int hh = 0; hh < 2; ++hh) {
            int c  = tid + hh * 256;
            int im = c >> 6;
            int lc = c & 63;
            int r  = im * 16 + (lc & 15);
            int kq = lc >> 4;
            As4[c] = *(const uint4*)(xb + (size_t)(m0 + r) * DMODEL + k0 + kq * 8);
            Bs4[c] = *(const uint4*)(wb + (size_t)(n0 + r) * DMODEL + k0 + kq * 8);
        }
        __syncthreads();
        bf16_8 af[4], bf[4];
#pragma unroll
        for (int i = 0; i < 4; ++i) {
            af[i] = ((const bf16_8*)As4)[((wm >> 4) + i) * 64 + lane];
            bf[i] = ((const bf16_8*)Bs4)[((wn >> 4) + i) * 64 + lane];
        }
#pragma unroll
        for (int i = 0; i < 4; ++i)
#pragma unroll
            for (int j = 0; j < 4; ++j)
                acc[i][j] = __builtin_amdgcn_mfma_f32_16x16x32_bf16(af[i], bf[j], acc[i][j], 0, 0, 0);
        __syncthreads();
    }

    int col  = lane & 15;
    int quad = lane >> 4;
    if (n0 < DINNER) {
#pragma unroll
        for (int i = 0; i < 4; ++i) {
#pragma unroll
            for (int j = 0; j < 4; ++j) {
                int nn = wn + j * 16 + col;
                int mm = wm + i * 16 + quad * 4;
                ushort4 o;
                o.x = f2b(acc[i][j][0]); o.y = f2b(acc[i][j][1]);
                o.z = f2b(acc[i][j][2]); o.w = f2b(acc[i][j][3]);
                *(ushort4*)&T[nn * TP_STRIDE + mm] = o;
            }
        }
        __syncthreads();
        int bI = m0 >> 9;
        int tglob = m0 & (LSEQ - 1);
#pragma unroll
        for (int it = 0; it < 8; ++it) {
            int c  = tid + it * 256;
            int nn = c >> 4;
            int tc = c & 15;
            uint4 v = *(const uint4*)&T[nn * TP_STRIDE + tc * 8];
            *(uint4*)(xiT + ((size_t)bI * DINNER + n0 + nn) * LSEQ + tglob + tc * 8) = v;
        }
    } else {
#pragma unroll
        for (int i = 0; i < 4; ++i) {
#pragma unroll
            for (int j = 0; j < 4; ++j) {
                int m = m0 + wm + i * 16 + quad * 4;
                int t = m & (LSEQ - 1);
                if (t < TSTART) continue;
                int b = m >> 9;
                int nz = n0 - DINNER + wn + j * 16 + col;
                float4 g;
                float v0 = acc[i][j][0], v1 = acc[i][j][1], v2 = acc[i][j][2], v3 = acc[i][j][3];
                g.x = v0 / (1.f + __expf(-v0));
                g.y = v1 / (1.f + __expf(-v1));
                g.z = v2 / (1.f + __expf(-v2));
                g.w = v3 / (1.f + __expf(-v3));
                *(float4*)(gsT + ((size_t)b * DINNER + nz) * PREDLEN + (t - TSTART)) = g;
            }
        }
    }
}

// ============ Kernel D: depthwise conv + silu; also gw=g*wf (in place) and c0=u*D*g*wf ============
__global__ __launch_bounds__(256) void k_dwconv_silu(const unsigned short* __restrict__ xiT,
                                                     const float* __restrict__ cw,
                                                     const float* __restrict__ cb,
                                                     const float* __restrict__ wfv,
                                                     const float* __restrict__ Dvec,
                                                     float* __restrict__ gsT,
                                                     unsigned short* __restrict__ c0,
                                                     unsigned short* __restrict__ uT) {
    int lane = threadIdx.x & 63;
    int w    = threadIdx.x >> 6;
    int d = blockIdx.x * 4 + w;
    int b = blockIdx.y;
    const unsigned short* src = xiT + ((size_t)b * DINNER + d) * LSEQ;
    uint4 cur = *(const uint4*)(src + lane * 8);
    unsigned pw = (unsigned)__shfl_up((int)cur.w, 1);
    unsigned pz = (unsigned)__shfl_up((int)cur.z, 1);
    if (lane == 0) { pw = 0u; pz = 0u; }
    float4 w4 = *(const float4*)(cw + (size_t)d * 4);
    float bias = cb[d];
    float win[11];
    win[0] = bhi(pz); win[1] = blo(pw); win[2] = bhi(pw);
    const unsigned* cp = (const unsigned*)&cur;
#pragma unroll
    for (int q = 0; q < 4; ++q) {
        win[3 + 2 * q] = blo(cp[q]);
        win[4 + 2 * q] = bhi(cp[q]);
    }
    float uvf[8];
    unsigned ov[4];
#pragma unroll
    for (int tt = 0; tt < 8; ++tt) {
        float a = bias + win[tt] * w4.x + win[tt + 1] * w4.y
                       + win[tt + 2] * w4.z + win[tt + 3] * w4.w;
        float uv = a / (1.f + __expf(-a));
        uvf[tt] = uv;
        unsigned short us = f2b(uv);
        if (tt & 1) ov[tt >> 1] |= ((unsigned)us) << 16;
        else        ov[tt >> 1]  = us;
    }
    *(uint4*)(uT + ((size_t)b * DINNER + d) * LSEQ + lane * 8) = *(uint4*)ov;
    if (lane >= 52) {               // t in [416,512): tail precompute
        int tl0 = lane * 8 - TSTART;
        float wfd = wfv[d];
        float Dd  = Dvec[d];
        float* gp = gsT + ((size_t)b * DINNER + d) * PREDLEN + tl0;
        float4 g0 = *(const float4*)gp;
        float4 g1 = *(const float4*)(gp + 4);
        float gg[8] = {g0.x, g0.y, g0.z, g0.w, g1.x, g1.y, g1.z, g1.w};
        unsigned cv[4];
#pragma unroll
        for (int j = 0; j < 8; ++j) {
            float gw = gg[j] * wfd;
            gg[j] = gw;
            unsigned short us = f2b(uvf[j] * Dd * gw);
            if (j & 1) cv[j >> 1] |= ((unsigned)us) << 16;
            else       cv[j >> 1]  = us;
        }
        *(float4*)gp       = make_float4(gg[0], gg[1], gg[2], gg[3]);
        *(float4*)(gp + 4) = make_float4(gg[4], gg[5], gg[6], gg[7]);
        *(uint4*)(c0 + ((size_t)b * DINNER + d) * PREDLEN + tl0) = *(uint4*)cv;
    }
}

// ============ Kernel E: x_proj GEMM via bf16 MFMA, M/64 tiling (256 blocks) ============
#define XPS 66   // shorts; dword-granular stores, conflict-free u16 frag gathers
__global__ __launch_bounds__(256) void k_gemm_xproj2(const unsigned short* __restrict__ uT,
                                                     const unsigned short* __restrict__ wbx,
                                                     float* __restrict__ dt_in,
                                                     float* __restrict__ Bt,
                                                     float* __restrict__ Ct) {
    __shared__ unsigned short Asl[32 * XPS];
    int tid  = threadIdx.x;
    int lane = tid & 63;
    int w    = tid >> 6;
    int quad = lane >> 4;
    int col  = lane & 15;
    int m0 = blockIdx.x * 64;
    int b  = m0 >> 9;
    int t0 = m0 & (LSEQ - 1);
    int sk  = tid >> 3;          // 0..31
    int smc = (tid & 7) * 8;     // 0..56
    f32x4 acc[4] = {};
    for (int k0 = 0; k0 < DINNER; k0 += 32) {
        uint4 v = *(const uint4*)(uT + ((size_t)b * DINNER + k0 + sk) * LSEQ + t0 + smc);
        unsigned* dst = (unsigned*)&Asl[sk * XPS + smc];
        dst[0] = v.x; dst[1] = v.y; dst[2] = v.z; dst[3] = v.w;
        __syncthreads();
        bf16_8 bf[4];
#pragma unroll
        for (int j = 0; j < 4; ++j)
            bf[j] = *((const bf16_8*)(wbx + (size_t)(j * 16 + col) * DINNER + k0 + quad * 8));
        union { bf16_8 v; unsigned short u[8]; } af;
#pragma unroll
        for (int j8 = 0; j8 < 8; ++j8)
            af.u[j8] = Asl[(quad * 8 + j8) * XPS + w * 16 + col];
#pragma unroll
        for (int j = 0; j < 4; ++j)
            acc[j] = __builtin_amdgcn_mfma_f32_16x16x32_bf16(af.v, bf[j], acc[j], 0, 0, 0);
        __syncthreads();
    }
    int mrow = m0 + w * 16 + quad * 4;
#pragma unroll
    for (int j = 0; j < 2; ++j)
#pragma unroll
        for (int r = 0; r < 4; ++r)
            dt_in[(size_t)(mrow + r) * DTRANK + j * 16 + col] = acc[j][r];
    int t = t0 + w * 16 + quad * 4;
    *(float4*)(Bt + ((size_t)b * DSTATE + col) * LSEQ + t) =
        make_float4(acc[2][0], acc[2][1], acc[2][2], acc[2][3]);
    *(float4*)(Ct + ((size_t)b * DSTATE + col) * LSEQ + t) =
        make_float4(acc[3][0], acc[3][1], acc[3][2], acc[3][3]);
}

// ============ Kernel F: dt = softplus(dt_in @ dpw.T + b) -> dt_T bf16 ============
__global__ __launch_bounds__(256) void k_dtproj(const float* __restrict__ dt_in,
                                                const float* __restrict__ dpw,
                                                const float* __restrict__ dpb,
                                                unsigned short* __restrict__ dtT) {
    __shared__ float xs[64][33];
    int tid  = threadIdx.x;
    int dloc = tid >> 3;
    int tc   = tid & 7;
    int d  = blockIdx.x * 32 + dloc;
    int m0 = blockIdx.y * 64;
    int b  = m0 >> 9;
    int t0 = m0 & (LSEQ - 1);
    for (int f = tid; f < 512; f += 256) {
        int row = f >> 3;
        int c   = (f & 7) << 2;
        float4 v = *(const float4*)(dt_in + (size_t)(m0 + row) * DTRANK + c);
        xs[row][c] = v.x; xs[row][c + 1] = v.y; xs[row][c + 2] = v.z; xs[row][c + 3] = v.w;
    }
    __syncthreads();
    float wv[32];
#pragma unroll
    for (int r = 0; r < 32; r += 4) {
        float4 v = *(const float4*)(dpw + (size_t)d * DTRANK + r);
        wv[r] = v.x; wv[r + 1] = v.y; wv[r + 2] = v.z; wv[r + 3] = v.w;
    }
    float bias = dpb[d];
    unsigned ov[4];
#pragma unroll
    for (int j = 0; j < 8; ++j) {
        int m = tc * 8 + j;
        float a = bias;
#pragma unroll
        for (int r = 0; r < 32; ++r) a += xs[m][r] * wv[r];
        float sp = (a > 20.f) ? a : log1pf(__expf(a));
        unsigned short us = f2b(sp);
        if (j & 1) ov[j >> 1] |= ((unsigned)us) << 16;
        else       ov[j >> 1]  = us;
    }
    *(uint4*)(dtT + ((size_t)b * DINNER + d) * LSEQ + t0 + tc * 8) = *(uint4*)ov;
}

// ============ Kernel G1: scan phase 1 — 4 states per lane ============
// wave = 16 d x 4 lanes; lane q handles states s = q*4..q*4+3.
__global__ __launch_bounds__(256) void k_scan_p1(const unsigned short* __restrict__ uT,
                                                 const unsigned short* __restrict__ dtT,
                                                 const float* __restrict__ Bt,
                                                 const float* __restrict__ A_log,
                                                 float2* __restrict__ ab) {
    int b = blockIdx.y;
    int c = blockIdx.z;
    int tid  = threadIdx.x;
    int lane = tid & 63;
    int w    = tid >> 6;
    int q    = lane & 3;
    int dloc = lane >> 2;
    int d    = blockIdx.x * 64 + w * 16 + dloc;
    float4 al = *(const float4*)(A_log + (size_t)d * DSTATE + q * 4);
    float As2[4];
    As2[0] = -__expf(al.x) * 1.44269504088896f;
    As2[1] = -__expf(al.y) * 1.44269504088896f;
    As2[2] = -__expf(al.z) * 1.44269504088896f;
    As2[3] = -__expf(al.w) * 1.44269504088896f;
    float beta[4] = {0.f, 0.f, 0.f, 0.f};
    float asum = 0.f;
    const unsigned short* up = uT  + ((size_t)b * DINNER + d) * LSEQ;
    const unsigned short* dp = dtT + ((size_t)b * DINNER + d) * LSEQ;
    const float* Bp = Bt + ((size_t)b * DSTATE + q * 4) * LSEQ;
    int tbeg = c * 128;
    for (int t8 = tbeg; t8 < tbeg + 128; t8 += 8) {
        uint4 uq = *(const uint4*)(up + t8);
        uint4 dq = *(const uint4*)(dp + t8);
        float uu[8], dd[8];
        const unsigned* uqp = (const unsigned*)&uq;
        const unsigned* dqp = (const unsigned*)&dq;
#pragma unroll
        for (int p = 0; p < 4; ++p) {
            uu[p * 2] = blo(uqp[p]); uu[p * 2 + 1] = bhi(uqp[p]);
            dd[p * 2] = blo(dqp[p]); dd[p * 2 + 1] = bhi(dqp[p]);
        }
#pragma unroll
        for (int hh = 0; hh < 2; ++hh) {
            float4 B0 = *(const float4*)(Bp + 0 * LSEQ + t8 + hh * 4);
            float4 B1 = *(const float4*)(Bp + 1 * LSEQ + t8 + hh * 4);
            float4 B2 = *(const float4*)(Bp + 2 * LSEQ + t8 + hh * 4);
            float4 B3 = *(const float4*)(Bp + 3 * LSEQ + t8 + hh * 4);
            float Bv0[4] = {B0.x, B0.y, B0.z, B0.w};
            float Bv1[4] = {B1.x, B1.y, B1.z, B1.w};
            float Bv2[4] = {B2.x, B2.y, B2.z, B2.w};
            float Bv3[4] = {B3.x, B3.y, B3.z, B3.w};
#pragma unroll
            for (int j = 0; j < 4; ++j) {
                int jj = hh * 4 + j;
                float du = dd[jj] * uu[jj];
                asum += dd[jj];
                beta[0] = exp2f(dd[jj] * As2[0]) * beta[0] + du * Bv0[j];
                beta[1] = exp2f(dd[jj] * As2[1]) * beta[1] + du * Bv1[j];
                beta[2] = exp2f(dd[jj] * As2[2]) * beta[2] + du * Bv2[j];
                beta[3] = exp2f(dd[jj] * As2[3]) * beta[3] + du * Bv3[j];
            }
        }
    }
    float2* abp = ab + ((size_t)(b * DINNER + d) * NCHUNK + c) * DSTATE + q * 4;
#pragma unroll
    for (int si = 0; si < 4; ++si)
        abp[si] = make_float2(exp2f(asum * As2[si]), beta[si]);
}

// ============ Kernel G2: scan phase 2+3 — stitch h(384), run [384,512), emit outputs ============
__global__ __launch_bounds__(256) void k_scan_p3(const unsigned short* __restrict__ uT,
                                                 const unsigned short* __restrict__ dtT,
                                                 const float* __restrict__ Bt,
                                                 const float* __restrict__ Ct,
                                                 const float* __restrict__ A_log,
                                                 const float* __restrict__ gsT,   // gw
                                                 const unsigned short* __restrict__ c0,
                                                 const float2* __restrict__ ab,
                                                 float* __restrict__ pacc) {
    int b    = blockIdx.y;
    int tid  = threadIdx.x;
    int s    = tid & 15;
    int dloc = tid >> 4;
    int d    = blockIdx.x * 16 + dloc;
    float As2 = -__expf(A_log[(size_t)d * DSTATE + s]) * 1.44269504088896f;
    const float2* abp = ab + (size_t)(b * DINNER + d) * NCHUNK * DSTATE + s;
    float h = 0.f;
#pragma unroll
    for (int c = 0; c < NCHUNK; ++c) {
        float2 v = abp[c * DSTATE];
        h = v.y + v.x * h;
    }
    const unsigned short* up = uT  + ((size_t)b * DINNER + d) * LSEQ;
    const unsigned short* dp = dtT + ((size_t)b * DINNER + d) * LSEQ;
    const float* Bp = Bt + ((size_t)b * DSTATE + s) * LSEQ;
    const float* Cp = Ct + ((size_t)b * DSTATE + s) * LSEQ;
    const float* gp = gsT + ((size_t)b * DINNER + d) * PREDLEN;
    const unsigned short* cp0 = c0 + ((size_t)b * DINNER + d) * PREDLEN;
    float* pout = pacc + ((size_t)b * PREDLEN) * 256 + blockIdx.x * 4 + (tid >> 6);
    for (int t8 = NCHUNK * 128; t8 < LSEQ; t8 += 8) {
        uint4 uq = *(const uint4*)(up + t8);
        uint4 dq = *(const uint4*)(dp + t8);
        float4 B0 = *(const float4*)(Bp + t8);
        float4 B1 = *(const float4*)(Bp + t8 + 4);
        float4 C0 = *(const float4*)(Cp + t8);
        float4 C1 = *(const float4*)(Cp + t8 + 4);
        float uu[8], dd[8];
        const unsigned* uqp = (const unsigned*)&uq;
        const unsigned* dqp = (const unsigned*)&dq;
#pragma unroll
        for (int p = 0; p < 4; ++p) {
            uu[p * 2] = blo(uqp[p]); uu[p * 2 + 1] = bhi(uqp[p]);
            dd[p * 2] = blo(dqp[p]); dd[p * 2 + 1] = bhi(dqp[p]);
        }
        float Bv[8] = {B0.x, B0.y, B0.z, B0.w, B1.x, B1.y, B1.z, B1.w};
        float Cv[8] = {C0.x, C0.y, C0.z, C0.w, C1.x, C1.y, C1.z, C1.w};
        if (t8 < TSTART) {
#pragma unroll
            for (int j = 0; j < 8; ++j)
                h = exp2f(dd[j] * As2) * h + (dd[j] * uu[j]) * Bv[j];
        } else {
            int tl0 = t8 - TSTART;
            float4 g0 = *(const float4*)(gp + tl0);
            float4 g1 = *(const float4*)(gp + tl0 + 4);
            float gv[8] = {g0.x, g0.y, g0.z, g0.w, g1.x, g1.y, g1.z, g1.w};
            uint4 cq = *(const uint4*)(cp0 + tl0);
            float cf[8];
            const unsigned* cqp = (const unsigned*)&cq;
#pragma unroll
            for (int p = 0; p < 4; ++p) {
                cf[p * 2] = blo(cqp[p]); cf[p * 2 + 1] = bhi(cqp[p]);
            }
#pragma unroll
            for (int j = 0; j < 8; ++j) {
                h = exp2f(dd[j] * As2) * h + (dd[j] * uu[j]) * Bv[j];
                float y = h * Cv[j];
                y += __shfl_xor(y, 1); y += __shfl_xor(y, 2);
                y += __shfl_xor(y, 4); y += __shfl_xor(y, 8);
                float cc = (s == 0) ? (y * gv[j] + cf[j]) : 0.f;
                cc += __shfl_xor(cc, 16); cc += __shfl_xor(cc, 32);
                if ((tid & 63) == 0) pout[(size_t)(tl0 + j) * 256] = cc;
            }
        }
    }
}

// ============ Kernel W: fusew partials + reduce ============
__global__ __launch_bounds__(256) void k_fusew(const float* __restrict__ opw,
                                               const float* __restrict__ ow,
                                               float* __restrict__ wfp) {
    int i = blockIdx.x * 256 + threadIdx.x;
    int q = blockIdx.y;
    float acc = 0.f;
    for (int dd = q * 128; dd < q * 128 + 128; ++dd)
        acc += opw[(size_t)dd * DINNER + i] * ow[dd];
    wfp[(size_t)q * DINNER + i] = acc;
}
__global__ __launch_bounds__(256) void k_fusew2(const float* __restrict__ wfp,
                                                float* __restrict__ wfv) {
    int i = blockIdx.x * 256 + threadIdx.x;
    wfv[i] = wfp[i] + wfp[DINNER + i] + wfp[2 * DINNER + i] + wfp[3 * DINNER + i];
}

// ============ Kernel H: reduce 256 partials + de-normalize ============
__global__ __launch_bounds__(64) void k_final(const float* __restrict__ pacc,
                                              const float* __restrict__ meanv,
                                              const float* __restrict__ stdv,
                                              float* __restrict__ out) {
    int idx  = blockIdx.x;
    int lane = threadIdx.x;
    int b = idx / PREDLEN;
    float4 v = *(const float4*)(pacc + (size_t)idx * 256 + lane * 4);
    float tot = v.x + v.y + v.z + v.w;
#pragma unroll
    for (int off = 32; off; off >>= 1) tot += __shfl_xor(tot, off);
    if (lane == 0) out[idx] = tot * stdv[b * ENC_IN] + meanv[b * ENC_IN];
}

// ---------------- launch ----------------
extern "C" void kernel_launch(void* const* d_in, const int* in_sizes, int n_in,
                              void* d_out, int out_size, void* d_ws, size_t ws_size,
                              hipStream_t stream) {
    const float* x_enc     = (const float*)d_in[0];
    const float* x_mark    = (const float*)d_in[1];
    const float* conv_w    = (const float*)d_in[2];
    const float* temp_w    = (const float*)d_in[3];
    const float* in_proj_w = (const float*)d_in[4];
    const float* conv1d_w  = (const float*)d_in[5];
    const float* conv1d_b  = (const float*)d_in[6];
    const float* x_proj_w  = (const float*)d_in[7];
    const float* dt_proj_w = (const float*)d_in[8];
    const float* dt_proj_b = (const float*)d_in[9];
    const float* A_log     = (const float*)d_in[10];
    const float* Dvec      = (const float*)d_in[11];
    const float* out_proj_w= (const float*)d_in[12];
    const float* out_w     = (const float*)d_in[13];
    float* ws  = (float*)d_ws;
    float* out = (float*)d_out;

    float* xn    = ws + OFF_XN;
    float* meanv = ws + OFF_MEAN;
    float* stdv  = ws + OFF_STD;
    float* wfv   = ws + OFF_WF;
    float* wfp   = ws + OFF_WFP;
    float* pacc  = ws + OFF_PACC;
    float* dt_in = ws + OFF_DTIN;
    float* Btv   = ws + OFF_BT;
    float* Ctv   = ws + OFF_CT;
    float* gsT   = ws + OFF_GST;
    unsigned short* xb  = (unsigned short*)(ws + OFF_XB);
    unsigned short* wb  = (unsigned short*)(ws + OFF_WB);
    unsigned short* wbx = (unsigned short*)(ws + OFF_WBX);
    unsigned short* xiT = (unsigned short*)(ws + OFF_XIT);
    unsigned short* uT  = (unsigned short*)(ws + OFF_UT);
    unsigned short* dtT = (unsigned short*)(ws + OFF_DTT);
    unsigned short* c0  = (unsigned short*)(ws + OFF_C0);
    float2* ab = (float2*)(ws + OFF_AB);

    k_norm<<<dim3(ENC_IN, BATCH), 64, 0, stream>>>(x_enc, xn, meanv, stdv);
    k_fusew<<<dim3(DINNER / 256, 4), 256, 0, stream>>>(out_proj_w, out_w, wfp);
    k_fusew2<<<dim3(DINNER / 256), 256, 0, stream>>>(wfp, wfv);
    k_build_x<<<dim3(DMODEL / 256, LSEQ, BATCH), 256, 0, stream>>>(xn, x_mark, conv_w, temp_w, xb);
    k_w2b<<<dim3((2 * DINNER * DMODEL) / 1024), 256, 0, stream>>>(in_proj_w, wb);
    k_w2b<<<dim3((64 * DINNER) / 1024), 256, 0, stream>>>(x_proj_w, wbx);
    k_gemm_inproj<<<dim3(16, 128), 256, 0, stream>>>(xb, wb, xiT, gsT);
    k_dwconv_silu<<<dim3(DINNER / 4, BATCH), 256, 0, stream>>>(xiT, conv1d_w, conv1d_b,
                                                               wfv, Dvec, gsT, c0, uT);
    k_gemm_xproj2<<<dim3(MROWS / 64), 256, 0, stream>>>(uT, wbx, dt_in, Btv, Ctv);
    k_dtproj<<<dim3(DINNER / 32, MROWS / 64), 256, 0, stream>>>(dt_in, dt_proj_w, dt_proj_b, dtT);
    k_scan_p1<<<dim3(DINNER / 64, BATCH, NCHUNK), 256, 0, stream>>>(uT, dtT, Btv, A_log, ab);
    k_scan_p3<<<dim3(DINNER / 16, BATCH), 256, 0, stream>>>(uT, dtT, Btv, Ctv, A_log,
                                                            gsT, c0, ab, pacc);
    k_final<<<dim3(BATCH * PREDLEN), 64, 0, stream>>>(pacc, meanv, stdv, out);
}

// Round 8
// 512.073 us; speedup vs baseline: 2.3976x; 1.0094x over previous
//
#include <hip/hip_runtime.h>
#include <hip/hip_bf16.h>
#include <math.h>

// ---------------- problem constants ----------------
#define BATCH   32
#define LSEQ    512
#define ENC_IN  8
#define MARKD   4
#define DMODEL  512
#define DSTATE  16
#define DINNER  1024
#define DTRANK  32
#define PREDLEN 96
#define MROWS   (BATCH * LSEQ)          // 16384
#define TSTART  (LSEQ - PREDLEN)        // 416
#define NCHUNK  4                       // chunks: [0,128),[128,256),[256,384),[384,416)

// ---------------- workspace layout (float units), total 107.5 MiB ----------------
#define OFF_XN    ((size_t)0)            // 131072 (wbx bf16 overlays after build_x)
#define OFF_MEAN  ((size_t)131072)       // 256
#define OFF_STD   ((size_t)131328)       // 256
#define OFF_WF    ((size_t)131584)       // 1024
#define OFF_PACC  ((size_t)132608)       // (unused now)
#define OFF_XB    ((size_t)919040)       // 16384x512 bf16 = 4194304 f  (alpha/beta overlays)
#define OFF_WB    ((size_t)5113344)      // 2048x512 bf16 = 524288 f
#define OFF_DTIN  ((size_t)5637632)      // 16384x32 fp32 = 524288 f (wfp partials overlay early)
#define OFF_BT    ((size_t)6161920)      // 32x16x512 fp32 = 262144 f
#define OFF_CT    ((size_t)6424064)      // 262144 f
#define OFF_GST   ((size_t)6686208)      // 32x1024x96 fp32 (g -> gw -> per-d outputs in place)
#define OFF_XIT   ((size_t)9831936)      // [b][d][t] bf16 = 8388608 f (dt_T overlays)
#define OFF_UT    ((size_t)18220544)     // [b][d][t] bf16 = 8388608 f
#define OFF_C0    ((size_t)26609152)     // 32x1024x96 bf16 = 1572864 f
#define OFF_DTT   OFF_XIT                // dt_T reuses xi_T (dead after dwconv)
#define OFF_AB    OFF_XB                 // alpha/beta: 32*1024*4*16*2 = 4194304 f (exact fit)
#define OFF_WBX   OFF_XN                 // x_proj_w bf16: 32768 f <= 131072
#define OFF_WFP   OFF_DTIN               // fusew partials: 4096 f (dt_in written later)
// end: 28182016 floats = 107.5 MiB

typedef __bf16 bf16_8 __attribute__((ext_vector_type(8)));
typedef float  f32x4  __attribute__((ext_vector_type(4)));

static __device__ __forceinline__ float b2f(unsigned short h) {
    union { float f; unsigned u; } v; v.u = ((unsigned)h) << 16; return v.f;
}
static __device__ __forceinline__ unsigned short f2b(float f) {
    __hip_bfloat16 h = __float2bfloat16(f);   // RNE
    union { __hip_bfloat16 b; unsigned short s; } v; v.b = h; return v.s;
}
static __device__ __forceinline__ float blo(unsigned v) {
    union { float f; unsigned u; } x; x.u = v << 16; return x.f;
}
static __device__ __forceinline__ float bhi(unsigned v) {
    union { float f; unsigned u; } x; x.u = v & 0xffff0000u; return x.f;
}

// ============ Kernel A: per-(b,c) mean/std + normalize ============
__global__ __launch_bounds__(64) void k_norm(const float* __restrict__ xe,
                                             float* __restrict__ xn,
                                             float* __restrict__ meanv,
                                             float* __restrict__ stdv) {
    int c = blockIdx.x;
    int b = blockIdx.y;
    int lane = threadIdx.x;
    const float* p = xe + ((size_t)b * LSEQ) * ENC_IN + c;
    float vals[8];
    float s = 0.f, s2 = 0.f;
#pragma unroll
    for (int i = 0; i < 8; ++i) {
        float v = p[(size_t)(lane + i * 64) * ENC_IN];
        vals[i] = v; s += v; s2 += v * v;
    }
#pragma unroll
    for (int off = 32; off; off >>= 1) {
        s  += __shfl_xor(s,  off);
        s2 += __shfl_xor(s2, off);
    }
    float mean = s * (1.f / LSEQ);
    float var  = s2 * (1.f / LSEQ) - mean * mean;
    float sd   = sqrtf(var + 1e-5f);
    float rstd = 1.f / sd;
    if (lane == 0) { meanv[b * ENC_IN + c] = mean; stdv[b * ENC_IN + c] = sd; }
#pragma unroll
    for (int i = 0; i < 8; ++i)
        xn[((size_t)b * LSEQ + lane + i * 64) * ENC_IN + c] = (vals[i] - mean) * rstd;
}

// ============ Kernel B: x = token_conv(xn) + temporal + pos_emb  (bf16 out) ============
__global__ __launch_bounds__(256) void k_build_x(const float* __restrict__ xn,
                                                 const float* __restrict__ xmark,
                                                 const float* __restrict__ convw,
                                                 const float* __restrict__ tempw,
                                                 unsigned short* __restrict__ xb) {
    int d = blockIdx.x * 256 + threadIdx.x;
    int l = blockIdx.y;
    int b = blockIdx.z;
    int lm = (l + LSEQ - 1) & (LSEQ - 1);     // circular pad per reference
    int lp = (l + 1) & (LSEQ - 1);
    const float* r0 = xn + ((size_t)b * LSEQ + lm) * ENC_IN;
    const float* r1 = xn + ((size_t)b * LSEQ + l ) * ENC_IN;
    const float* r2 = xn + ((size_t)b * LSEQ + lp) * ENC_IN;
    const float* w  = convw + (size_t)d * (ENC_IN * 3);
    float acc = 0.f;
#pragma unroll
    for (int i = 0; i < ENC_IN; ++i)
        acc += r0[i] * w[i * 3 + 0] + r1[i] * w[i * 3 + 1] + r2[i] * w[i * 3 + 2];
    const float* tw = tempw + (size_t)d * MARKD;
    const float* xm = xmark + ((size_t)b * LSEQ + l) * MARKD;
    acc += xm[0] * tw[0] + xm[1] * tw[1] + xm[2] * tw[2] + xm[3] * tw[3];
    float freq = __expf(-(float)(d & ~1) * (9.210340371976184f / (float)DMODEL));
    float ang  = (float)l * freq;
    acc += (d & 1) ? cosf(ang) : sinf(ang);
    xb[((size_t)b * LSEQ + l) * DMODEL + d] = f2b(acc);
}

// ============ Kernel W2B: fp32 -> bf16 cast (generic) ============
__global__ __launch_bounds__(256) void k_w2b(const float* __restrict__ w,
                                             unsigned short* __restrict__ wb) {
    int i = (blockIdx.x * 256 + threadIdx.x) * 4;
    float4 v = *(const float4*)(w + i);
    ushort4 o;
    o.x = f2b(v.x); o.y = f2b(v.y); o.z = f2b(v.z); o.w = f2b(v.w);
    *(ushort4*)(wb + i) = o;
}

// ============ Kernel C: in_proj GEMM via bf16 MFMA ============
#define TP_STRIDE 136
__global__ __launch_bounds__(256) void k_gemm_inproj(const unsigned short* __restrict__ xb,
                                                     const unsigned short* __restrict__ wb,
                                                     unsigned short* __restrict__ xiT,
                                                     float* __restrict__ gsT) {
    int n0 = blockIdx.x * 128;
    int m0 = blockIdx.y * 128;
    if (n0 >= DINNER && (m0 & (LSEQ - 1)) != 384) return;

    __shared__ unsigned char smem[128 * TP_STRIDE * 2];
    uint4* As4 = (uint4*)smem;
    uint4* Bs4 = As4 + 512;
    unsigned short* T = (unsigned short*)smem;

    int tid  = threadIdx.x;
    int lane = tid & 63;
    int w    = tid >> 6;
    int wm   = (w & 1) * 64;
    int wn   = (w >> 1) * 64;
    f32x4 acc[4][4] = {};

    for (int k0 = 0; k0 < DMODEL; k0 += 32) {
#pragma unroll
        for (int hh = 0; hh < 2; ++hh) {
            int c  = tid + hh * 256;
            int im = c >> 6;
            int lc = c & 63;
            int r  = im * 16 + (lc & 15);
            int kq = lc >> 4;
            As4[c] = *(const uint4*)(xb + (size_t)(m0 + r) * DMODEL + k0 + kq * 8);
            Bs4[c] = *(const uint4*)(wb + (size_t)(n0 + r) * DMODEL + k0 + kq * 8);
        }
        __syncthreads();
        bf16_8 af[4], bf[4];
#pragma unroll
        for (int i = 0; i < 4; ++i) {
            af[i] = ((const bf16_8*)As4)[((wm >> 4) + i) * 64 + lane];
            bf[i] = ((const bf16_8*)Bs4)[((wn >> 4) + i) * 64 + lane];
        }
#pragma unroll
        for (int i = 0; i < 4; ++i)
#pragma unroll
            for (int j = 0; j < 4; ++j)
                acc[i][j] = __builtin_amdgcn_mfma_f32_16x16x32_bf16(af[i], bf[j], acc[i][j], 0, 0, 0);
        __syncthreads();
    }

    int col  = lane & 15;
    int quad = lane >> 4;
    if (n0 < DINNER) {
#pragma unroll
        for (int i = 0; i < 4; ++i) {
#pragma unroll
            for (int j = 0; j < 4; ++j) {
                int nn = wn + j * 16 + col;
                int mm = wm + i * 16 + quad * 4;
                ushort4 o;
                o.x = f2b(acc[i][j][0]); o.y = f2b(acc[i][j][1]);
                o.z = f2b(acc[i][j][2]); o.w = f2b(acc[i][j][3]);
                *(ushort4*)&T[nn * TP_STRIDE + mm] = o;
            }
        }
        __syncthreads();
        int bI = m0 >> 9;
        int tglob = m0 & (LSEQ - 1);
#pragma unroll
        for (int it = 0; it < 8; ++it) {
            int c  = tid + it * 256;
            int nn = c >> 4;
            int tc = c & 15;
            uint4 v = *(const uint4*)&T[nn * TP_STRIDE + tc * 8];
            *(uint4*)(xiT + ((size_t)bI * DINNER + n0 + nn) * LSEQ + tglob + tc * 8) = v;
        }
    } else {
#pragma unroll
        for (int i = 0; i < 4; ++i) {
#pragma unroll
            for (int j = 0; j < 4; ++j) {
                int m = m0 + wm + i * 16 + quad * 4;
                int t = m & (LSEQ - 1);
                if (t < TSTART) continue;
                int b = m >> 9;
                int nz = n0 - DINNER + wn + j * 16 + col;
                float4 g;
                float v0 = acc[i][j][0], v1 = acc[i][j][1], v2 = acc[i][j][2], v3 = acc[i][j][3];
                g.x = v0 / (1.f + __expf(-v0));
                g.y = v1 / (1.f + __expf(-v1));
                g.z = v2 / (1.f + __expf(-v2));
                g.w = v3 / (1.f + __expf(-v3));
                *(float4*)(gsT + ((size_t)b * DINNER + nz) * PREDLEN + (t - TSTART)) = g;
            }
        }
    }
}

// ============ Kernel D: depthwise conv + silu; also gw=g*wf (in place) and c0=u*D*g*wf ============
__global__ __launch_bounds__(256) void k_dwconv_silu(const unsigned short* __restrict__ xiT,
                                                     const float* __restrict__ cw,
                                                     const float* __restrict__ cb,
                                                     const float* __restrict__ wfv,
                                                     const float* __restrict__ Dvec,
                                                     float* __restrict__ gsT,
                                                     unsigned short* __restrict__ c0,
                                                     unsigned short* __restrict__ uT) {
    int lane = threadIdx.x & 63;
    int w    = threadIdx.x >> 6;
    int d = blockIdx.x * 4 + w;
    int b = blockIdx.y;
    const unsigned short* src = xiT + ((size_t)b * DINNER + d) * LSEQ;
    uint4 cur = *(const uint4*)(src + lane * 8);
    unsigned pw = (unsigned)__shfl_up((int)cur.w, 1);
    unsigned pz = (unsigned)__shfl_up((int)cur.z, 1);
    if (lane == 0) { pw = 0u; pz = 0u; }
    float4 w4 = *(const float4*)(cw + (size_t)d * 4);
    float bias = cb[d];
    float win[11];
    win[0] = bhi(pz); win[1] = blo(pw); win[2] = bhi(pw);
    const unsigned* cp = (const unsigned*)&cur;
#pragma unroll
    for (int q = 0; q < 4; ++q) {
        win[3 + 2 * q] = blo(cp[q]);
        win[4 + 2 * q] = bhi(cp[q]);
    }
    float uvf[8];
    unsigned ov[4];
#pragma unroll
    for (int tt = 0; tt < 8; ++tt) {
        float a = bias + win[tt] * w4.x + win[tt + 1] * w4.y
                       + win[tt + 2] * w4.z + win[tt + 3] * w4.w;
        float uv = a / (1.f + __expf(-a));
        uvf[tt] = uv;
        unsigned short us = f2b(uv);
        if (tt & 1) ov[tt >> 1] |= ((unsigned)us) << 16;
        else        ov[tt >> 1]  = us;
    }
    *(uint4*)(uT + ((size_t)b * DINNER + d) * LSEQ + lane * 8) = *(uint4*)ov;
    if (lane >= 52) {               // t in [416,512): tail precompute
        int tl0 = lane * 8 - TSTART;
        float wfd = wfv[d];
        float Dd  = Dvec[d];
        float* gp = gsT + ((size_t)b * DINNER + d) * PREDLEN + tl0;
        float4 g0 = *(const float4*)gp;
        float4 g1 = *(const float4*)(gp + 4);
        float gg[8] = {g0.x, g0.y, g0.z, g0.w, g1.x, g1.y, g1.z, g1.w};
        unsigned cv[4];
#pragma unroll
        for (int j = 0; j < 8; ++j) {
            float gw = gg[j] * wfd;
            gg[j] = gw;
            unsigned short us = f2b(uvf[j] * Dd * gw);
            if (j & 1) cv[j >> 1] |= ((unsigned)us) << 16;
            else       cv[j >> 1]  = us;
        }
        *(float4*)gp       = make_float4(gg[0], gg[1], gg[2], gg[3]);
        *(float4*)(gp + 4) = make_float4(gg[4], gg[5], gg[6], gg[7]);
        *(uint4*)(c0 + ((size_t)b * DINNER + d) * PREDLEN + tl0) = *(uint4*)cv;
    }
}

// ============ Kernel E: x_proj GEMM via bf16 MFMA, M/64 tiling (256 blocks) ============
#define XPS 66
__global__ __launch_bounds__(256) void k_gemm_xproj2(const unsigned short* __restrict__ uT,
                                                     const unsigned short* __restrict__ wbx,
                                                     float* __restrict__ dt_in,
                                                     float* __restrict__ Bt,
                                                     float* __restrict__ Ct) {
    __shared__ unsigned short Asl[32 * XPS];
    int tid  = threadIdx.x;
    int lane = tid & 63;
    int w    = tid >> 6;
    int quad = lane >> 4;
    int col  = lane & 15;
    int m0 = blockIdx.x * 64;
    int b  = m0 >> 9;
    int t0 = m0 & (LSEQ - 1);
    int sk  = tid >> 3;
    int smc = (tid & 7) * 8;
    f32x4 acc[4] = {};
    for (int k0 = 0; k0 < DINNER; k0 += 32) {
        uint4 v = *(const uint4*)(uT + ((size_t)b * DINNER + k0 + sk) * LSEQ + t0 + smc);
        unsigned* dst = (unsigned*)&Asl[sk * XPS + smc];
        dst[0] = v.x; dst[1] = v.y; dst[2] = v.z; dst[3] = v.w;
        __syncthreads();
        bf16_8 bf[4];
#pragma unroll
        for (int j = 0; j < 4; ++j)
            bf[j] = *((const bf16_8*)(wbx + (size_t)(j * 16 + col) * DINNER + k0 + quad * 8));
        union { bf16_8 v; unsigned short u[8]; } af;
#pragma unroll
        for (int j8 = 0; j8 < 8; ++j8)
            af.u[j8] = Asl[(quad * 8 + j8) * XPS + w * 16 + col];
#pragma unroll
        for (int j = 0; j < 4; ++j)
            acc[j] = __builtin_amdgcn_mfma_f32_16x16x32_bf16(af.v, bf[j], acc[j], 0, 0, 0);
        __syncthreads();
    }
    int mrow = m0 + w * 16 + quad * 4;
#pragma unroll
    for (int j = 0; j < 2; ++j)
#pragma unroll
        for (int r = 0; r < 4; ++r)
            dt_in[(size_t)(mrow + r) * DTRANK + j * 16 + col] = acc[j][r];
    int t = t0 + w * 16 + quad * 4;
    *(float4*)(Bt + ((size_t)b * DSTATE + col) * LSEQ + t) =
        make_float4(acc[2][0], acc[2][1], acc[2][2], acc[2][3]);
    *(float4*)(Ct + ((size_t)b * DSTATE + col) * LSEQ + t) =
        make_float4(acc[3][0], acc[3][1], acc[3][2], acc[3][3]);
}

// ============ Kernel F: dt = softplus(dt_in @ dpw.T + b) -> dt_T bf16 ============
__global__ __launch_bounds__(256) void k_dtproj(const float* __restrict__ dt_in,
                                                const float* __restrict__ dpw,
                                                const float* __restrict__ dpb,
                                                unsigned short* __restrict__ dtT) {
    __shared__ float xs[64][33];
    int tid  = threadIdx.x;
    int dloc = tid >> 3;
    int tc   = tid & 7;
    int d  = blockIdx.x * 32 + dloc;
    int m0 = blockIdx.y * 64;
    int b  = m0 >> 9;
    int t0 = m0 & (LSEQ - 1);
    for (int f = tid; f < 512; f += 256) {
        int row = f >> 3;
        int c   = (f & 7) << 2;
        float4 v = *(const float4*)(dt_in + (size_t)(m0 + row) * DTRANK + c);
        xs[row][c] = v.x; xs[row][c + 1] = v.y; xs[row][c + 2] = v.z; xs[row][c + 3] = v.w;
    }
    __syncthreads();
    float wv[32];
#pragma unroll
    for (int r = 0; r < 32; r += 4) {
        float4 v = *(const float4*)(dpw + (size_t)d * DTRANK + r);
        wv[r] = v.x; wv[r + 1] = v.y; wv[r + 2] = v.z; wv[r + 3] = v.w;
    }
    float bias = dpb[d];
    unsigned ov[4];
#pragma unroll
    for (int j = 0; j < 8; ++j) {
        int m = tc * 8 + j;
        float a = bias;
#pragma unroll
        for (int r = 0; r < 32; ++r) a += xs[m][r] * wv[r];
        float sp = (a > 20.f) ? a : log1pf(__expf(a));
        unsigned short us = f2b(sp);
        if (j & 1) ov[j >> 1] |= ((unsigned)us) << 16;
        else       ov[j >> 1]  = us;
    }
    *(uint4*)(dtT + ((size_t)b * DINNER + d) * LSEQ + t0 + tc * 8) = *(uint4*)ov;
}

// ============ Kernel G1: scan phase 1 — 4 states per lane, 4 chunks ============
__global__ __launch_bounds__(256) void k_scan_p1(const unsigned short* __restrict__ uT,
                                                 const unsigned short* __restrict__ dtT,
                                                 const float* __restrict__ Bt,
                                                 const float* __restrict__ A_log,
                                                 float2* __restrict__ ab) {
    int b = blockIdx.y;
    int c = blockIdx.z;
    int tid  = threadIdx.x;
    int lane = tid & 63;
    int w    = tid >> 6;
    int q    = lane & 3;
    int dloc = lane >> 2;
    int d    = blockIdx.x * 64 + w * 16 + dloc;
    float4 al = *(const float4*)(A_log + (size_t)d * DSTATE + q * 4);
    float As2[4];
    As2[0] = -__expf(al.x) * 1.44269504088896f;
    As2[1] = -__expf(al.y) * 1.44269504088896f;
    As2[2] = -__expf(al.z) * 1.44269504088896f;
    As2[3] = -__expf(al.w) * 1.44269504088896f;
    float beta[4] = {0.f, 0.f, 0.f, 0.f};
    float asum = 0.f;
    const unsigned short* up = uT  + ((size_t)b * DINNER + d) * LSEQ;
    const unsigned short* dp = dtT + ((size_t)b * DINNER + d) * LSEQ;
    const float* Bp = Bt + ((size_t)b * DSTATE + q * 4) * LSEQ;
    int tbeg = c * 128;
    int tend = (c == 3) ? TSTART : (tbeg + 128);   // chunk 3 = [384,416)
    for (int t8 = tbeg; t8 < tend; t8 += 8) {
        uint4 uq = *(const uint4*)(up + t8);
        uint4 dq = *(const uint4*)(dp + t8);
        float uu[8], dd[8];
        const unsigned* uqp = (const unsigned*)&uq;
        const unsigned* dqp = (const unsigned*)&dq;
#pragma unroll
        for (int p = 0; p < 4; ++p) {
            uu[p * 2] = blo(uqp[p]); uu[p * 2 + 1] = bhi(uqp[p]);
            dd[p * 2] = blo(dqp[p]); dd[p * 2 + 1] = bhi(dqp[p]);
        }
#pragma unroll
        for (int hh = 0; hh < 2; ++hh) {
            float4 B0 = *(const float4*)(Bp + 0 * LSEQ + t8 + hh * 4);
            float4 B1 = *(const float4*)(Bp + 1 * LSEQ + t8 + hh * 4);
            float4 B2 = *(const float4*)(Bp + 2 * LSEQ + t8 + hh * 4);
            float4 B3 = *(const float4*)(Bp + 3 * LSEQ + t8 + hh * 4);
            float Bv0[4] = {B0.x, B0.y, B0.z, B0.w};
            float Bv1[4] = {B1.x, B1.y, B1.z, B1.w};
            float Bv2[4] = {B2.x, B2.y, B2.z, B2.w};
            float Bv3[4] = {B3.x, B3.y, B3.z, B3.w};
#pragma unroll
            for (int j = 0; j < 4; ++j) {
                int jj = hh * 4 + j;
                float du = dd[jj] * uu[jj];
                asum += dd[jj];
                beta[0] = exp2f(dd[jj] * As2[0]) * beta[0] + du * Bv0[j];
                beta[1] = exp2f(dd[jj] * As2[1]) * beta[1] + du * Bv1[j];
                beta[2] = exp2f(dd[jj] * As2[2]) * beta[2] + du * Bv2[j];
                beta[3] = exp2f(dd[jj] * As2[3]) * beta[3] + du * Bv3[j];
            }
        }
    }
    float2* abp = ab + ((size_t)(b * DINNER + d) * NCHUNK + c) * DSTATE + q * 4;
#pragma unroll
    for (int si = 0; si < 4; ++si)
        abp[si] = make_float2(exp2f(asum * As2[si]), beta[si]);
}

// ============ Kernel G2: stitch h(416), run [416,512) with batched reduce ============
// y[8] accumulated per iter; butterfly AFTER the serial loop (8 independent chains);
// lanes s=0..7 each write one finished output in place into gsT[b][d][tl].
__global__ __launch_bounds__(256) void k_scan_p3(const unsigned short* __restrict__ uT,
                                                 const unsigned short* __restrict__ dtT,
                                                 const float* __restrict__ Bt,
                                                 const float* __restrict__ Ct,
                                                 const float* __restrict__ A_log,
                                                 float* __restrict__ gsT,   // gw in, outputs out
                                                 const unsigned short* __restrict__ c0,
                                                 const float2* __restrict__ ab) {
    int b    = blockIdx.y;
    int tid  = threadIdx.x;
    int s    = tid & 15;
    int dloc = tid >> 4;
    int d    = blockIdx.x * 16 + dloc;
    float As2 = -__expf(A_log[(size_t)d * DSTATE + s]) * 1.44269504088896f;
    const float2* abp = ab + (size_t)(b * DINNER + d) * NCHUNK * DSTATE + s;
    float h = 0.f;
#pragma unroll
    for (int c = 0; c < NCHUNK; ++c) {
        float2 v = abp[c * DSTATE];
        h = v.y + v.x * h;
    }
    const unsigned short* up = uT  + ((size_t)b * DINNER + d) * LSEQ;
    const unsigned short* dp = dtT + ((size_t)b * DINNER + d) * LSEQ;
    const float* Bp = Bt + ((size_t)b * DSTATE + s) * LSEQ;
    const float* Cp = Ct + ((size_t)b * DSTATE + s) * LSEQ;
    float* gp = gsT + ((size_t)b * DINNER + d) * PREDLEN;
    const unsigned short* cp0 = c0 + ((size_t)b * DINNER + d) * PREDLEN;
    for (int t8 = TSTART; t8 < LSEQ; t8 += 8) {
        int tl0 = t8 - TSTART;
        uint4 uq = *(const uint4*)(up + t8);
        uint4 dq = *(const uint4*)(dp + t8);
        float4 B0 = *(const float4*)(Bp + t8);
        float4 B1 = *(const float4*)(Bp + t8 + 4);
        float4 C0 = *(const float4*)(Cp + t8);
        float4 C1 = *(const float4*)(Cp + t8 + 4);
        float4 g0 = *(const float4*)(gp + tl0);
        float4 g1 = *(const float4*)(gp + tl0 + 4);
        uint4 cq = *(const uint4*)(cp0 + tl0);
        float uu[8], dd[8];
        const unsigned* uqp = (const unsigned*)&uq;
        const unsigned* dqp = (const unsigned*)&dq;
#pragma unroll
        for (int p = 0; p < 4; ++p) {
            uu[p * 2] = blo(uqp[p]); uu[p * 2 + 1] = bhi(uqp[p]);
            dd[p * 2] = blo(dqp[p]); dd[p * 2 + 1] = bhi(dqp[p]);
        }
        float Bv[8] = {B0.x, B0.y, B0.z, B0.w, B1.x, B1.y, B1.z, B1.w};
        float Cv[8] = {C0.x, C0.y, C0.z, C0.w, C1.x, C1.y, C1.z, C1.w};
        float y[8];
#pragma unroll
        for (int j = 0; j < 8; ++j) {
            h = exp2f(dd[j] * As2) * h + (dd[j] * uu[j]) * Bv[j];
            y[j] = h * Cv[j];
        }
        // batched butterfly over the 16 state lanes: 8 independent chains
#pragma unroll
        for (int j = 0; j < 8; ++j) y[j] += __shfl_xor(y[j], 1);
#pragma unroll
        for (int j = 0; j < 8; ++j) y[j] += __shfl_xor(y[j], 2);
#pragma unroll
        for (int j = 0; j < 8; ++j) y[j] += __shfl_xor(y[j], 4);
#pragma unroll
        for (int j = 0; j < 8; ++j) y[j] += __shfl_xor(y[j], 8);
        if (s < 8) {
            float gv[8] = {g0.x, g0.y, g0.z, g0.w, g1.x, g1.y, g1.z, g1.w};
            const unsigned* cqp = (const unsigned*)&cq;
            float cf = (s & 1) ? bhi(cqp[s >> 1]) : blo(cqp[s >> 1]);
            gp[tl0 + s] = y[s] * gv[s] + cf;
        }
    }
}

// ============ Kernel W: fusew partials + reduce ============
__global__ __launch_bounds__(256) void k_fusew(const float* __restrict__ opw,
                                               const float* __restrict__ ow,
                                               float* __restrict__ wfp) {
    int i = blockIdx.x * 256 + threadIdx.x;
    int q = blockIdx.y;
    float acc = 0.f;
    for (int dd = q * 128; dd < q * 128 + 128; ++dd)
        acc += opw[(size_t)dd * DINNER + i] * ow[dd];
    wfp[(size_t)q * DINNER + i] = acc;
}
__global__ __launch_bounds__(256) void k_fusew2(const float* __restrict__ wfp,
                                                float* __restrict__ wfv) {
    int i = blockIdx.x * 256 + threadIdx.x;
    wfv[i] = wfp[i] + wfp[DINNER + i] + wfp[2 * DINNER + i] + wfp[3 * DINNER + i];
}

// ============ Kernel H: reduce 1024 per-d outputs + de-normalize ============
__global__ __launch_bounds__(256) void k_final2(const float* __restrict__ gsT,
                                                const float* __restrict__ meanv,
                                                const float* __restrict__ stdv,
                                                float* __restrict__ out) {
    int tl = blockIdx.x;
    int b  = blockIdx.y;
    int tid = threadIdx.x;
    const float* gp = gsT + (size_t)b * DINNER * PREDLEN + tl;
    float acc = 0.f;
#pragma unroll
    for (int k = 0; k < 4; ++k)
        acc += gp[(size_t)(tid + k * 256) * PREDLEN];
#pragma unroll
    for (int off = 32; off; off >>= 1) acc += __shfl_xor(acc, off);
    __shared__ float red[4];
    if ((tid & 63) == 0) red[tid >> 6] = acc;
    __syncthreads();
    if (tid == 0) {
        float tot = red[0] + red[1] + red[2] + red[3];
        out[b * PREDLEN + tl] = tot * stdv[b * ENC_IN] + meanv[b * ENC_IN];
    }
}

// ---------------- launch ----------------
extern "C" void kernel_launch(void* const* d_in, const int* in_sizes, int n_in,
                              void* d_out, int out_size, void* d_ws, size_t ws_size,
                              hipStream_t stream) {
    const float* x_enc     = (const float*)d_in[0];
    const float* x_mark    = (const float*)d_in[1];
    const float* conv_w    = (const float*)d_in[2];
    const float* temp_w    = (const float*)d_in[3];
    const float* in_proj_w = (const float*)d_in[4];
    const float* conv1d_w  = (const float*)d_in[5];
    const float* conv1d_b  = (const float*)d_in[6];
    const float* x_proj_w  = (const float*)d_in[7];
    const float* dt_proj_w = (const float*)d_in[8];
    const float* dt_proj_b = (const float*)d_in[9];
    const float* A_log     = (const float*)d_in[10];
    const float* Dvec      = (const float*)d_in[11];
    const float* out_proj_w= (const float*)d_in[12];
    const float* out_w     = (const float*)d_in[13];
    float* ws  = (float*)d_ws;
    float* out = (float*)d_out;

    float* xn    = ws + OFF_XN;
    float* meanv = ws + OFF_MEAN;
    float* stdv  = ws + OFF_STD;
    float* wfv   = ws + OFF_WF;
    float* wfp   = ws + OFF_WFP;
    float* dt_in = ws + OFF_DTIN;
    float* Btv   = ws + OFF_BT;
    float* Ctv   = ws + OFF_CT;
    float* gsT   = ws + OFF_GST;
    unsigned short* xb  = (unsigned short*)(ws + OFF_XB);
    unsigned short* wb  = (unsigned short*)(ws + OFF_WB);
    unsigned short* wbx = (unsigned short*)(ws + OFF_WBX);
    unsigned short* xiT = (unsigned short*)(ws + OFF_XIT);
    unsigned short* uT  = (unsigned short*)(ws + OFF_UT);
    unsigned short* dtT = (unsigned short*)(ws + OFF_DTT);
    unsigned short* c0  = (unsigned short*)(ws + OFF_C0);
    float2* ab = (float2*)(ws + OFF_AB);

    k_norm<<<dim3(ENC_IN, BATCH), 64, 0, stream>>>(x_enc, xn, meanv, stdv);
    k_fusew<<<dim3(DINNER / 256, 4), 256, 0, stream>>>(out_proj_w, out_w, wfp);
    k_fusew2<<<dim3(DINNER / 256), 256, 0, stream>>>(wfp, wfv);
    k_build_x<<<dim3(DMODEL / 256, LSEQ, BATCH), 256, 0, stream>>>(xn, x_mark, conv_w, temp_w, xb);
    k_w2b<<<dim3((2 * DINNER * DMODEL) / 1024), 256, 0, stream>>>(in_proj_w, wb);
    k_w2b<<<dim3((64 * DINNER) / 1024), 256, 0, stream>>>(x_proj_w, wbx);
    k_gemm_inproj<<<dim3(16, 128), 256, 0, stream>>>(xb, wb, xiT, gsT);
    k_dwconv_silu<<<dim3(DINNER / 4, BATCH), 256, 0, stream>>>(xiT, conv1d_w, conv1d_b,
                                                               wfv, Dvec, gsT, c0, uT);
    k_gemm_xproj2<<<dim3(MROWS / 64), 256, 0, stream>>>(uT, wbx, dt_in, Btv, Ctv);
    k_dtproj<<<dim3(DINNER / 32, MROWS / 64), 256, 0, stream>>>(dt_in, dt_proj_w, dt_proj_b, dtT);
    k_scan_p1<<<dim3(DINNER / 64, BATCH, NCHUNK), 256, 0, stream>>>(uT, dtT, Btv, A_log, ab);
    k_scan_p3<<<dim3(DINNER / 16, BATCH), 256, 0, stream>>>(uT, dtT, Btv, Ctv, A_log,
                                                            gsT, c0, ab);
    k_final2<<<dim3(PREDLEN, BATCH), 256, 0, stream>>>(gsT, meanv, stdv, out);
}

// Round 9
// 463.975 us; speedup vs baseline: 2.6461x; 1.1037x over previous
//
#include <hip/hip_runtime.h>
#include <hip/hip_bf16.h>
#include <math.h>

// ---------------- problem constants ----------------
#define BATCH   32
#define LSEQ    512
#define ENC_IN  8
#define MARKD   4
#define DMODEL  512
#define DSTATE  16
#define DINNER  1024
#define DTRANK  32
#define PREDLEN 96
#define MROWS   (BATCH * LSEQ)          // 16384
#define TSTART  (LSEQ - PREDLEN)        // 416
#define NCHUNK  4                       // chunks: [0,128)x3 + [384,416)

// ---------------- workspace layout (float units), total 107.5 MiB ----------------
#define OFF_XN    ((size_t)0)            // 131072
#define OFF_MEAN  ((size_t)131072)       // 256
#define OFF_STD   ((size_t)131328)       // 256
#define OFF_WF    ((size_t)131584)       // 1024
#define OFF_WBX   ((size_t)132608)       // x_proj_w bf16: 32768 f (ex-pacc slot)
#define OFF_DPWB  ((size_t)165376)       // dt_proj_w bf16: 16384 f
#define OFF_XB    ((size_t)919040)       // 16384x512 bf16 = 4194304 f (ab overlays)
#define OFF_WB    ((size_t)5113344)      // 2048x512 bf16 = 524288 f
#define OFF_DTIN  ((size_t)5637632)      // dt_in bf16 16384x32 = 262144 f (wfp overlays early)
#define OFF_BT    ((size_t)6161920)      // 32x16x512 fp32 = 262144 f
#define OFF_CT    ((size_t)6424064)      // 262144 f
#define OFF_GST   ((size_t)6686208)      // 32x1024x96 fp32 (g -> gw -> outputs in place)
#define OFF_XIT   ((size_t)9831936)      // [b][d][t] bf16 = 8388608 f (dtT overlays)
#define OFF_UT    ((size_t)18220544)     // [b][d][t] bf16 = 8388608 f
#define OFF_C0    ((size_t)26609152)     // 32x1024x96 bf16 = 1572864 f
#define OFF_DTT   OFF_XIT
#define OFF_AB    OFF_XB                 // 32*1024*4*16*2 = 4194304 f exact fit
#define OFF_WFP   OFF_DTIN               // fusew partials 4096 f (dt_in written later)
// end: 28182016 floats = 107.5 MiB

typedef __bf16 bf16_8 __attribute__((ext_vector_type(8)));
typedef float  f32x4  __attribute__((ext_vector_type(4)));

#define EXP2F(x) __builtin_amdgcn_exp2f(x)
#define LOG2F(x) __builtin_amdgcn_logf(x)

static __device__ __forceinline__ float b2f(unsigned short h) {
    union { float f; unsigned u; } v; v.u = ((unsigned)h) << 16; return v.f;
}
static __device__ __forceinline__ unsigned short f2b(float f) {
    __hip_bfloat16 h = __float2bfloat16(f);   // RNE
    union { __hip_bfloat16 b; unsigned short s; } v; v.b = h; return v.s;
}
static __device__ __forceinline__ float blo(unsigned v) {
    union { float f; unsigned u; } x; x.u = v << 16; return x.f;
}
static __device__ __forceinline__ float bhi(unsigned v) {
    union { float f; unsigned u; } x; x.u = v & 0xffff0000u; return x.f;
}

// ============ k_front: fusew-partials | w2b(in_proj) | w2b(x_proj) | w2b(dt_proj) | norm ============
// block ranges: [0,16) fusew, [16,1040) w2b inproj, [1040,1104) w2b xproj,
//               [1104,1136) w2b dpw, [1136,1200) norm (wave-granular).
__global__ __launch_bounds__(256) void k_front(const float* __restrict__ opw,
                                               const float* __restrict__ ow,
                                               const float* __restrict__ in_proj_w,
                                               const float* __restrict__ x_proj_w,
                                               const float* __restrict__ dpw,
                                               const float* __restrict__ xe,
                                               float* __restrict__ wfp,
                                               unsigned short* __restrict__ wb,
                                               unsigned short* __restrict__ wbx,
                                               unsigned short* __restrict__ dpwb,
                                               float* __restrict__ xn,
                                               float* __restrict__ meanv,
                                               float* __restrict__ stdv) {
    int bid = blockIdx.x;
    int tid = threadIdx.x;
    if (bid < 16) {                       // fusew partials
        int q = bid >> 2;
        int i = (bid & 3) * 256 + tid;
        float acc = 0.f;
        for (int dd = q * 128; dd < q * 128 + 128; ++dd)
            acc += opw[(size_t)dd * DINNER + i] * ow[dd];
        wfp[(size_t)q * DINNER + i] = acc;
    } else if (bid < 1040) {              // in_proj_w -> bf16
        int i = ((bid - 16) * 256 + tid) * 4;
        float4 v = *(const float4*)(in_proj_w + i);
        ushort4 o; o.x = f2b(v.x); o.y = f2b(v.y); o.z = f2b(v.z); o.w = f2b(v.w);
        *(ushort4*)(wb + i) = o;
    } else if (bid < 1104) {              // x_proj_w -> bf16
        int i = ((bid - 1040) * 256 + tid) * 4;
        float4 v = *(const float4*)(x_proj_w + i);
        ushort4 o; o.x = f2b(v.x); o.y = f2b(v.y); o.z = f2b(v.z); o.w = f2b(v.w);
        *(ushort4*)(wbx + i) = o;
    } else if (bid < 1136) {              // dt_proj_w -> bf16
        int i = ((bid - 1104) * 256 + tid) * 4;
        float4 v = *(const float4*)(dpw + i);
        ushort4 o; o.x = f2b(v.x); o.y = f2b(v.y); o.z = f2b(v.z); o.w = f2b(v.w);
        *(ushort4*)(dpwb + i) = o;
    } else {                              // norm: wave-granular, 4 (b,c) per block
        int wv   = tid >> 6;
        int lane = tid & 63;
        int idx  = (bid - 1136) * 4 + wv;   // 0..255
        int c = idx & 7, b = idx >> 3;
        const float* p = xe + ((size_t)b * LSEQ) * ENC_IN + c;
        float vals[8];
        float s = 0.f, s2 = 0.f;
#pragma unroll
        for (int i = 0; i < 8; ++i) {
            float v = p[(size_t)(lane + i * 64) * ENC_IN];
            vals[i] = v; s += v; s2 += v * v;
        }
#pragma unroll
        for (int off = 32; off; off >>= 1) {
            s  += __shfl_xor(s,  off);
            s2 += __shfl_xor(s2, off);
        }
        float mean = s * (1.f / LSEQ);
        float var  = s2 * (1.f / LSEQ) - mean * mean;
        float sd   = sqrtf(var + 1e-5f);
        float rstd = 1.f / sd;
        if (lane == 0) { meanv[b * ENC_IN + c] = mean; stdv[b * ENC_IN + c] = sd; }
#pragma unroll
        for (int i = 0; i < 8; ++i)
            xn[((size_t)b * LSEQ + lane + i * 64) * ENC_IN + c] = (vals[i] - mean) * rstd;
    }
}

// ============ k_front2: build_x (32768 blocks) + fusew2 (4 blocks) ============
__global__ __launch_bounds__(256) void k_front2(const float* __restrict__ xn,
                                                const float* __restrict__ xmark,
                                                const float* __restrict__ convw,
                                                const float* __restrict__ tempw,
                                                const float* __restrict__ wfp,
                                                unsigned short* __restrict__ xb,
                                                float* __restrict__ wfv) {
    int bid = blockIdx.x;
    int tid = threadIdx.x;
    if (bid >= 32768) {                   // fusew2
        int i = (bid - 32768) * 256 + tid;
        wfv[i] = wfp[i] + wfp[DINNER + i] + wfp[2 * DINNER + i] + wfp[3 * DINNER + i];
        return;
    }
    int d = (bid & 1) * 256 + tid;
    int l = (bid >> 1) & (LSEQ - 1);
    int b = bid >> 10;
    int lm = (l + LSEQ - 1) & (LSEQ - 1);     // circular pad per reference
    int lp = (l + 1) & (LSEQ - 1);
    const float* r0 = xn + ((size_t)b * LSEQ + lm) * ENC_IN;
    const float* r1 = xn + ((size_t)b * LSEQ + l ) * ENC_IN;
    const float* r2 = xn + ((size_t)b * LSEQ + lp) * ENC_IN;
    const float* w  = convw + (size_t)d * (ENC_IN * 3);
    float acc = 0.f;
#pragma unroll
    for (int i = 0; i < ENC_IN; ++i)
        acc += r0[i] * w[i * 3 + 0] + r1[i] * w[i * 3 + 1] + r2[i] * w[i * 3 + 2];
    const float* tw = tempw + (size_t)d * MARKD;
    const float* xm = xmark + ((size_t)b * LSEQ + l) * MARKD;
    acc += xm[0] * tw[0] + xm[1] * tw[1] + xm[2] * tw[2] + xm[3] * tw[3];
    float freq = __expf(-(float)(d & ~1) * (9.210340371976184f / (float)DMODEL));
    float rev  = (float)l * freq * 0.15915494309189535f;   // radians -> revolutions
    rev = rev - floorf(rev);                                // v_fract reduction
    acc += (d & 1) ? __builtin_amdgcn_cosf(rev) : __builtin_amdgcn_sinf(rev);
    xb[((size_t)b * LSEQ + l) * DMODEL + d] = f2b(acc);
}

// ============ Kernel C: in_proj GEMM via bf16 MFMA ============
#define TP_STRIDE 136
__global__ __launch_bounds__(256) void k_gemm_inproj(const unsigned short* __restrict__ xb,
                                                     const unsigned short* __restrict__ wb,
                                                     unsigned short* __restrict__ xiT,
                                                     float* __restrict__ gsT) {
    int n0 = blockIdx.x * 128;
    int m0 = blockIdx.y * 128;
    if (n0 >= DINNER && (m0 & (LSEQ - 1)) != 384) return;

    __shared__ unsigned char smem[128 * TP_STRIDE * 2];
    uint4* As4 = (uint4*)smem;
    uint4* Bs4 = As4 + 512;
    unsigned short* T = (unsigned short*)smem;

    int tid  = threadIdx.x;
    int lane = tid & 63;
    int w    = tid >> 6;
    int wm   = (w & 1) * 64;
    int wn   = (w >> 1) * 64;
    f32x4 acc[4][4] = {};

    for (int k0 = 0; k0 < DMODEL; k0 += 32) {
#pragma unroll
        for (int hh = 0; hh < 2; ++hh) {
            int c  = tid + hh * 256;
            int im = c >> 6;
            int lc = c & 63;
            int r  = im * 16 + (lc & 15);
            int kq = lc >> 4;
            As4[c] = *(const uint4*)(xb + (size_t)(m0 + r) * DMODEL + k0 + kq * 8);
            Bs4[c] = *(const uint4*)(wb + (size_t)(n0 + r) * DMODEL + k0 + kq * 8);
        }
        __syncthreads();
        bf16_8 af[4], bf[4];
#pragma unroll
        for (int i = 0; i < 4; ++i) {
            af[i] = ((const bf16_8*)As4)[((wm >> 4) + i) * 64 + lane];
            bf[i] = ((const bf16_8*)Bs4)[((wn >> 4) + i) * 64 + lane];
        }
#pragma unroll
        for (int i = 0; i < 4; ++i)
#pragma unroll
            for (int j = 0; j < 4; ++j)
                acc[i][j] = __builtin_amdgcn_mfma_f32_16x16x32_bf16(af[i], bf[j], acc[i][j], 0, 0, 0);
        __syncthreads();
    }

    int col  = lane & 15;
    int quad = lane >> 4;
    if (n0 < DINNER) {
#pragma unroll
        for (int i = 0; i < 4; ++i) {
#pragma unroll
            for (int j = 0; j < 4; ++j) {
                int nn = wn + j * 16 + col;
                int mm = wm + i * 16 + quad * 4;
                ushort4 o;
                o.x = f2b(acc[i][j][0]); o.y = f2b(acc[i][j][1]);
                o.z = f2b(acc[i][j][2]); o.w = f2b(acc[i][j][3]);
                *(ushort4*)&T[nn * TP_STRIDE + mm] = o;
            }
        }
        __syncthreads();
        int bI = m0 >> 9;
        int tglob = m0 & (LSEQ - 1);
#pragma unroll
        for (int it = 0; it < 8; ++it) {
            int c  = tid + it * 256;
            int nn = c >> 4;
            int tc = c & 15;
            uint4 v = *(const uint4*)&T[nn * TP_STRIDE + tc * 8];
            *(uint4*)(xiT + ((size_t)bI * DINNER + n0 + nn) * LSEQ + tglob + tc * 8) = v;
        }
    } else {
#pragma unroll
        for (int i = 0; i < 4; ++i) {
#pragma unroll
            for (int j = 0; j < 4; ++j) {
                int m = m0 + wm + i * 16 + quad * 4;
                int t = m & (LSEQ - 1);
                if (t < TSTART) continue;
                int b = m >> 9;
                int nz = n0 - DINNER + wn + j * 16 + col;
                float4 g;
                float v0 = acc[i][j][0], v1 = acc[i][j][1], v2 = acc[i][j][2], v3 = acc[i][j][3];
                g.x = v0 / (1.f + __expf(-v0));
                g.y = v1 / (1.f + __expf(-v1));
                g.z = v2 / (1.f + __expf(-v2));
                g.w = v3 / (1.f + __expf(-v3));
                *(float4*)(gsT + ((size_t)b * DINNER + nz) * PREDLEN + (t - TSTART)) = g;
            }
        }
    }
}

// ============ Kernel D: depthwise conv + silu; gw=g*wf in place; c0=u*D*g*wf ============
__global__ __launch_bounds__(256) void k_dwconv_silu(const unsigned short* __restrict__ xiT,
                                                     const float* __restrict__ cw,
                                                     const float* __restrict__ cb,
                                                     const float* __restrict__ wfv,
                                                     const float* __restrict__ Dvec,
                                                     float* __restrict__ gsT,
                                                     unsigned short* __restrict__ c0,
                                                     unsigned short* __restrict__ uT) {
    int lane = threadIdx.x & 63;
    int w    = threadIdx.x >> 6;
    int d = blockIdx.x * 4 + w;
    int b = blockIdx.y;
    const unsigned short* src = xiT + ((size_t)b * DINNER + d) * LSEQ;
    uint4 cur = *(const uint4*)(src + lane * 8);
    unsigned pw = (unsigned)__shfl_up((int)cur.w, 1);
    unsigned pz = (unsigned)__shfl_up((int)cur.z, 1);
    if (lane == 0) { pw = 0u; pz = 0u; }
    float4 w4 = *(const float4*)(cw + (size_t)d * 4);
    float bias = cb[d];
    float win[11];
    win[0] = bhi(pz); win[1] = blo(pw); win[2] = bhi(pw);
    const unsigned* cp = (const unsigned*)&cur;
#pragma unroll
    for (int q = 0; q < 4; ++q) {
        win[3 + 2 * q] = blo(cp[q]);
        win[4 + 2 * q] = bhi(cp[q]);
    }
    float uvf[8];
    unsigned ov[4];
#pragma unroll
    for (int tt = 0; tt < 8; ++tt) {
        float a = bias + win[tt] * w4.x + win[tt + 1] * w4.y
                       + win[tt + 2] * w4.z + win[tt + 3] * w4.w;
        float uv = a / (1.f + __expf(-a));
        uvf[tt] = uv;
        unsigned short us = f2b(uv);
        if (tt & 1) ov[tt >> 1] |= ((unsigned)us) << 16;
        else        ov[tt >> 1]  = us;
    }
    *(uint4*)(uT + ((size_t)b * DINNER + d) * LSEQ + lane * 8) = *(uint4*)ov;
    if (lane >= 52) {
        int tl0 = lane * 8 - TSTART;
        float wfd = wfv[d];
        float Dd  = Dvec[d];
        float* gp = gsT + ((size_t)b * DINNER + d) * PREDLEN + tl0;
        float4 g0 = *(const float4*)gp;
        float4 g1 = *(const float4*)(gp + 4);
        float gg[8] = {g0.x, g0.y, g0.z, g0.w, g1.x, g1.y, g1.z, g1.w};
        unsigned cv[4];
#pragma unroll
        for (int j = 0; j < 8; ++j) {
            float gw = gg[j] * wfd;
            gg[j] = gw;
            unsigned short us = f2b(uvf[j] * Dd * gw);
            if (j & 1) cv[j >> 1] |= ((unsigned)us) << 16;
            else       cv[j >> 1]  = us;
        }
        *(float4*)gp       = make_float4(gg[0], gg[1], gg[2], gg[3]);
        *(float4*)(gp + 4) = make_float4(gg[4], gg[5], gg[6], gg[7]);
        *(uint4*)(c0 + ((size_t)b * DINNER + d) * PREDLEN + tl0) = *(uint4*)cv;
    }
}

// ============ Kernel E: x_proj GEMM via bf16 MFMA (dt_in written bf16) ============
#define XPS 66
__global__ __launch_bounds__(256) void k_gemm_xproj2(const unsigned short* __restrict__ uT,
                                                     const unsigned short* __restrict__ wbx,
                                                     unsigned short* __restrict__ dt_in,
                                                     float* __restrict__ Bt,
                                                     float* __restrict__ Ct) {
    __shared__ unsigned short Asl[32 * XPS];
    int tid  = threadIdx.x;
    int lane = tid & 63;
    int w    = tid >> 6;
    int quad = lane >> 4;
    int col  = lane & 15;
    int m0 = blockIdx.x * 64;
    int b  = m0 >> 9;
    int t0 = m0 & (LSEQ - 1);
    int sk  = tid >> 3;
    int smc = (tid & 7) * 8;
    f32x4 acc[4] = {};
    for (int k0 = 0; k0 < DINNER; k0 += 32) {
        uint4 v = *(const uint4*)(uT + ((size_t)b * DINNER + k0 + sk) * LSEQ + t0 + smc);
        unsigned* dst = (unsigned*)&Asl[sk * XPS + smc];
        dst[0] = v.x; dst[1] = v.y; dst[2] = v.z; dst[3] = v.w;
        __syncthreads();
        bf16_8 bf[4];
#pragma unroll
        for (int j = 0; j < 4; ++j)
            bf[j] = *((const bf16_8*)(wbx + (size_t)(j * 16 + col) * DINNER + k0 + quad * 8));
        union { bf16_8 v; unsigned short u[8]; } af;
#pragma unroll
        for (int j8 = 0; j8 < 8; ++j8)
            af.u[j8] = Asl[(quad * 8 + j8) * XPS + w * 16 + col];
#pragma unroll
        for (int j = 0; j < 4; ++j)
            acc[j] = __builtin_amdgcn_mfma_f32_16x16x32_bf16(af.v, bf[j], acc[j], 0, 0, 0);
        __syncthreads();
    }
    int mrow = m0 + w * 16 + quad * 4;
#pragma unroll
    for (int j = 0; j < 2; ++j)
#pragma unroll
        for (int r = 0; r < 4; ++r)
            dt_in[(size_t)(mrow + r) * DTRANK + j * 16 + col] = f2b(acc[j][r]);
    int t = t0 + w * 16 + quad * 4;
    *(float4*)(Bt + ((size_t)b * DSTATE + col) * LSEQ + t) =
        make_float4(acc[2][0], acc[2][1], acc[2][2], acc[2][3]);
    *(float4*)(Ct + ((size_t)b * DSTATE + col) * LSEQ + t) =
        make_float4(acc[3][0], acc[3][1], acc[3][2], acc[3][3]);
}

// ============ Kernel F: dt_proj as MFMA GEMM (K=32) + softplus + transpose store ============
// dtT[m, n] = softplus(dt_in[m,:] @ dpwb[n,:] + dpb[n]) -> dtT[b][d][t] coalesced.
__global__ __launch_bounds__(256) void k_dtproj2(const unsigned short* __restrict__ dt_in,
                                                 const unsigned short* __restrict__ dpwb,
                                                 const float* __restrict__ dpb,
                                                 unsigned short* __restrict__ dtT) {
    __shared__ unsigned char smem[128 * TP_STRIDE * 2];
    uint4* As4 = (uint4*)smem;
    uint4* Bs4 = As4 + 512;
    unsigned short* T = (unsigned short*)smem;
    int tid  = threadIdx.x;
    int lane = tid & 63;
    int w    = tid >> 6;
    int wm   = (w & 1) * 64;
    int wn   = (w >> 1) * 64;
    int n0 = blockIdx.x * 128;
    int m0 = blockIdx.y * 128;
    // stage A (dt_in 128x32) and B (dpwb 128x32) in fragment order, single K block
#pragma unroll
    for (int hh = 0; hh < 2; ++hh) {
        int c  = tid + hh * 256;
        int im = c >> 6;
        int lc = c & 63;
        int r  = im * 16 + (lc & 15);
        int kq = lc >> 4;              // 0..3 (K=32)
        As4[c] = *(const uint4*)(dt_in + (size_t)(m0 + r) * DTRANK + kq * 8);
        Bs4[c] = *(const uint4*)(dpwb + (size_t)(n0 + r) * DTRANK + kq * 8);
    }
    __syncthreads();
    f32x4 acc[4][4] = {};
    bf16_8 af[4], bf[4];
#pragma unroll
    for (int i = 0; i < 4; ++i) {
        af[i] = ((const bf16_8*)As4)[((wm >> 4) + i) * 64 + lane];
        bf[i] = ((const bf16_8*)Bs4)[((wn >> 4) + i) * 64 + lane];
    }
#pragma unroll
    for (int i = 0; i < 4; ++i)
#pragma unroll
        for (int j = 0; j < 4; ++j)
            acc[i][j] = __builtin_amdgcn_mfma_f32_16x16x32_bf16(af[i], bf[j], acc[i][j], 0, 0, 0);
    __syncthreads();
    int col  = lane & 15;
    int quad = lane >> 4;
#pragma unroll
    for (int i = 0; i < 4; ++i) {
#pragma unroll
        for (int j = 0; j < 4; ++j) {
            int nn = wn + j * 16 + col;
            int mm = wm + i * 16 + quad * 4;
            float bias = dpb[n0 + nn];
            ushort4 o;
            unsigned short* op = (unsigned short*)&o;
#pragma unroll
            for (int r = 0; r < 4; ++r) {
                float a = acc[i][j][r] + bias;
                float sp = (a > 20.f) ? a
                         : 0.6931471805599453f * LOG2F(1.f + EXP2F(a * 1.44269504088896f));
                op[r] = f2b(sp);
            }
            *(ushort4*)&T[nn * TP_STRIDE + mm] = o;
        }
    }
    __syncthreads();
    int bI = m0 >> 9;
    int tglob = m0 & (LSEQ - 1);
#pragma unroll
    for (int it = 0; it < 8; ++it) {
        int c  = tid + it * 256;
        int nn = c >> 4;
        int tc = c & 15;
        uint4 v = *(const uint4*)&T[nn * TP_STRIDE + tc * 8];
        *(uint4*)(dtT + ((size_t)bI * DINNER + n0 + nn) * LSEQ + tglob + tc * 8) = v;
    }
}

// ============ Kernel G1: scan phase 1 — 4 states per lane, 4 chunks ============
__global__ __launch_bounds__(256) void k_scan_p1(const unsigned short* __restrict__ uT,
                                                 const unsigned short* __restrict__ dtT,
                                                 const float* __restrict__ Bt,
                                                 const float* __restrict__ A_log,
                                                 float2* __restrict__ ab) {
    int b = blockIdx.y;
    int c = blockIdx.z;
    int tid  = threadIdx.x;
    int lane = tid & 63;
    int w    = tid >> 6;
    int q    = lane & 3;
    int dloc = lane >> 2;
    int d    = blockIdx.x * 64 + w * 16 + dloc;
    float4 al = *(const float4*)(A_log + (size_t)d * DSTATE + q * 4);
    float As2[4];
    As2[0] = -__expf(al.x) * 1.44269504088896f;
    As2[1] = -__expf(al.y) * 1.44269504088896f;
    As2[2] = -__expf(al.z) * 1.44269504088896f;
    As2[3] = -__expf(al.w) * 1.44269504088896f;
    float beta[4] = {0.f, 0.f, 0.f, 0.f};
    float asum = 0.f;
    const unsigned short* up = uT  + ((size_t)b * DINNER + d) * LSEQ;
    const unsigned short* dp = dtT + ((size_t)b * DINNER + d) * LSEQ;
    const float* Bp = Bt + ((size_t)b * DSTATE + q * 4) * LSEQ;
    int tbeg = c * 128;
    int tend = (c == 3) ? TSTART : (tbeg + 128);
    for (int t8 = tbeg; t8 < tend; t8 += 8) {
        uint4 uq = *(const uint4*)(up + t8);
        uint4 dq = *(const uint4*)(dp + t8);
        float uu[8], dd[8];
        const unsigned* uqp = (const unsigned*)&uq;
        const unsigned* dqp = (const unsigned*)&dq;
#pragma unroll
        for (int p = 0; p < 4; ++p) {
            uu[p * 2] = blo(uqp[p]); uu[p * 2 + 1] = bhi(uqp[p]);
            dd[p * 2] = blo(dqp[p]); dd[p * 2 + 1] = bhi(dqp[p]);
        }
#pragma unroll
        for (int hh = 0; hh < 2; ++hh) {
            float4 B0 = *(const float4*)(Bp + 0 * LSEQ + t8 + hh * 4);
            float4 B1 = *(const float4*)(Bp + 1 * LSEQ + t8 + hh * 4);
            float4 B2 = *(const float4*)(Bp + 2 * LSEQ + t8 + hh * 4);
            float4 B3 = *(const float4*)(Bp + 3 * LSEQ + t8 + hh * 4);
            float Bv0[4] = {B0.x, B0.y, B0.z, B0.w};
            float Bv1[4] = {B1.x, B1.y, B1.z, B1.w};
            float Bv2[4] = {B2.x, B2.y, B2.z, B2.w};
            float Bv3[4] = {B3.x, B3.y, B3.z, B3.w};
#pragma unroll
            for (int j = 0; j < 4; ++j) {
                int jj = hh * 4 + j;
                float du = dd[jj] * uu[jj];
                asum += dd[jj];
                beta[0] = EXP2F(dd[jj] * As2[0]) * beta[0] + du * Bv0[j];
                beta[1] = EXP2F(dd[jj] * As2[1]) * beta[1] + du * Bv1[j];
                beta[2] = EXP2F(dd[jj] * As2[2]) * beta[2] + du * Bv2[j];
                beta[3] = EXP2F(dd[jj] * As2[3]) * beta[3] + du * Bv3[j];
            }
        }
    }
    float2* abp = ab + ((size_t)(b * DINNER + d) * NCHUNK + c) * DSTATE + q * 4;
#pragma unroll
    for (int si = 0; si < 4; ++si)
        abp[si] = make_float2(EXP2F(asum * As2[si]), beta[si]);
}

// ============ Kernel G2: stitch h(416), run [416,512), batched reduce, in-place out ============
__global__ __launch_bounds__(256) void k_scan_p3(const unsigned short* __restrict__ uT,
                                                 const unsigned short* __restrict__ dtT,
                                                 const float* __restrict__ Bt,
                                                 const float* __restrict__ Ct,
                                                 const float* __restrict__ A_log,
                                                 float* __restrict__ gsT,
                                                 const unsigned short* __restrict__ c0,
                                                 const float2* __restrict__ ab) {
    int b    = blockIdx.y;
    int tid  = threadIdx.x;
    int s    = tid & 15;
    int dloc = tid >> 4;
    int d    = blockIdx.x * 16 + dloc;
    float As2 = -__expf(A_log[(size_t)d * DSTATE + s]) * 1.44269504088896f;
    const float2* abp = ab + (size_t)(b * DINNER + d) * NCHUNK * DSTATE + s;
    float h = 0.f;
#pragma unroll
    for (int c = 0; c < NCHUNK; ++c) {
        float2 v = abp[c * DSTATE];
        h = v.y + v.x * h;
    }
    const unsigned short* up = uT  + ((size_t)b * DINNER + d) * LSEQ;
    const unsigned short* dp = dtT + ((size_t)b * DINNER + d) * LSEQ;
    const float* Bp = Bt + ((size_t)b * DSTATE + s) * LSEQ;
    const float* Cp = Ct + ((size_t)b * DSTATE + s) * LSEQ;
    float* gp = gsT + ((size_t)b * DINNER + d) * PREDLEN;
    const unsigned short* cp0 = c0 + ((size_t)b * DINNER + d) * PREDLEN;
    for (int t8 = TSTART; t8 < LSEQ; t8 += 8) {
        int tl0 = t8 - TSTART;
        uint4 uq = *(const uint4*)(up + t8);
        uint4 dq = *(const uint4*)(dp + t8);
        float4 B0 = *(const float4*)(Bp + t8);
        float4 B1 = *(const float4*)(Bp + t8 + 4);
        float4 C0 = *(const float4*)(Cp + t8);
        float4 C1 = *(const float4*)(Cp + t8 + 4);
        float4 g0 = *(const float4*)(gp + tl0);
        float4 g1 = *(const float4*)(gp + tl0 + 4);
        uint4 cq = *(const uint4*)(cp0 + tl0);
        float uu[8], dd[8];
        const unsigned* uqp = (const unsigned*)&uq;
        const unsigned* dqp = (const unsigned*)&dq;
#pragma unroll
        for (int p = 0; p < 4; ++p) {
            uu[p * 2] = blo(uqp[p]); uu[p * 2 + 1] = bhi(uqp[p]);
            dd[p * 2] = blo(dqp[p]); dd[p * 2 + 1] = bhi(dqp[p]);
        }
        float Bv[8] = {B0.x, B0.y, B0.z, B0.w, B1.x, B1.y, B1.z, B1.w};
        float Cv[8] = {C0.x, C0.y, C0.z, C0.w, C1.x, C1.y, C1.z, C1.w};
        float y[8];
#pragma unroll
        for (int j = 0; j < 8; ++j) {
            h = EXP2F(dd[j] * As2) * h + (dd[j] * uu[j]) * Bv[j];
            y[j] = h * Cv[j];
        }
#pragma unroll
        for (int j = 0; j < 8; ++j) y[j] += __shfl_xor(y[j], 1);
#pragma unroll
        for (int j = 0; j < 8; ++j) y[j] += __shfl_xor(y[j], 2);
#pragma unroll
        for (int j = 0; j < 8; ++j) y[j] += __shfl_xor(y[j], 4);
#pragma unroll
        for (int j = 0; j < 8; ++j) y[j] += __shfl_xor(y[j], 8);
        if (s < 8) {
            float gv[8] = {g0.x, g0.y, g0.z, g0.w, g1.x, g1.y, g1.z, g1.w};
            const unsigned* cqp = (const unsigned*)&cq;
            float cf = (s & 1) ? bhi(cqp[s >> 1]) : blo(cqp[s >> 1]);
            gp[tl0 + s] = y[s] * gv[s] + cf;
        }
    }
}

// ============ Kernel H: reduce 1024 per-d outputs + de-normalize ============
__global__ __launch_bounds__(256) void k_final2(const float* __restrict__ gsT,
                                                const float* __restrict__ meanv,
                                                const float* __restrict__ stdv,
                                                float* __restrict__ out) {
    int tl = blockIdx.x;
    int b  = blockIdx.y;
    int tid = threadIdx.x;
    const float* gp = gsT + (size_t)b * DINNER * PREDLEN + tl;
    float acc = 0.f;
#pragma unroll
    for (int k = 0; k < 4; ++k)
        acc += gp[(size_t)(tid + k * 256) * PREDLEN];
#pragma unroll
    for (int off = 32; off; off >>= 1) acc += __shfl_xor(acc, off);
    __shared__ float red[4];
    if ((tid & 63) == 0) red[tid >> 6] = acc;
    __syncthreads();
    if (tid == 0) {
        float tot = red[0] + red[1] + red[2] + red[3];
        out[b * PREDLEN + tl] = tot * stdv[b * ENC_IN] + meanv[b * ENC_IN];
    }
}

// ---------------- launch ----------------
extern "C" void kernel_launch(void* const* d_in, const int* in_sizes, int n_in,
                              void* d_out, int out_size, void* d_ws, size_t ws_size,
                              hipStream_t stream) {
    const float* x_enc     = (const float*)d_in[0];
    const float* x_mark    = (const float*)d_in[1];
    const float* conv_w    = (const float*)d_in[2];
    const float* temp_w    = (const float*)d_in[3];
    const float* in_proj_w = (const float*)d_in[4];
    const float* conv1d_w  = (const float*)d_in[5];
    const float* conv1d_b  = (const float*)d_in[6];
    const float* x_proj_w  = (const float*)d_in[7];
    const float* dt_proj_w = (const float*)d_in[8];
    const float* dt_proj_b = (const float*)d_in[9];
    const float* A_log     = (const float*)d_in[10];
    const float* Dvec      = (const float*)d_in[11];
    const float* out_proj_w= (const float*)d_in[12];
    const float* out_w     = (const float*)d_in[13];
    float* ws  = (float*)d_ws;
    float* out = (float*)d_out;

    float* xn    = ws + OFF_XN;
    float* meanv = ws + OFF_MEAN;
    float* stdv  = ws + OFF_STD;
    float* wfv   = ws + OFF_WF;
    float* wfp   = ws + OFF_WFP;
    float* Btv   = ws + OFF_BT;
    float* Ctv   = ws + OFF_CT;
    float* gsT   = ws + OFF_GST;
    unsigned short* xb    = (unsigned short*)(ws + OFF_XB);
    unsigned short* wb    = (unsigned short*)(ws + OFF_WB);
    unsigned short* wbx   = (unsigned short*)(ws + OFF_WBX);
    unsigned short* dpwb  = (unsigned short*)(ws + OFF_DPWB);
    unsigned short* dtinb = (unsigned short*)(ws + OFF_DTIN);
    unsigned short* xiT   = (unsigned short*)(ws + OFF_XIT);
    unsigned short* uT    = (unsigned short*)(ws + OFF_UT);
    unsigned short* dtT   = (unsigned short*)(ws + OFF_DTT);
    unsigned short* c0    = (unsigned short*)(ws + OFF_C0);
    float2* ab = (float2*)(ws + OFF_AB);

    k_front<<<dim3(1200), 256, 0, stream>>>(out_proj_w, out_w, in_proj_w, x_proj_w, dt_proj_w,
                                            x_enc, wfp, wb, wbx, dpwb, xn, meanv, stdv);
    k_front2<<<dim3(32772), 256, 0, stream>>>(xn, x_mark, conv_w, temp_w, wfp, xb, wfv);
    k_gemm_inproj<<<dim3(16, 128), 256, 0, stream>>>(xb, wb, xiT, gsT);
    k_dwconv_silu<<<dim3(DINNER / 4, BATCH), 256, 0, stream>>>(xiT, conv1d_w, conv1d_b,
                                                               wfv, Dvec, gsT, c0, uT);
    k_gemm_xproj2<<<dim3(MROWS / 64), 256, 0, stream>>>(uT, wbx, dtinb, Btv, Ctv);
    k_dtproj2<<<dim3(8, 128), 256, 0, stream>>>(dtinb, dpwb, dt_proj_b, dtT);
    k_scan_p1<<<dim3(DINNER / 64, BATCH, NCHUNK), 256, 0, stream>>>(uT, dtT, Btv, A_log, ab);
    k_scan_p3<<<dim3(DINNER / 16, BATCH), 256, 0, stream>>>(uT, dtT, Btv, Ctv, A_log,
                                                            gsT, c0, ab);
    k_final2<<<dim3(PREDLEN, BATCH), 256, 0, stream>>>(gsT, meanv, stdv, out);
}

// Round 10
// 447.683 us; speedup vs baseline: 2.7424x; 1.0364x over previous
//
#include <hip/hip_runtime.h>
#include <hip/hip_bf16.h>
#include <math.h>

// ---------------- problem constants ----------------
#define BATCH   32
#define LSEQ    512
#define ENC_IN  8
#define MARKD   4
#define DMODEL  512
#define DSTATE  16
#define DINNER  1024
#define DTRANK  32
#define PREDLEN 96
#define MROWS   (BATCH * LSEQ)          // 16384
#define TSTART  (LSEQ - PREDLEN)        // 416
#define NCHUNK  4                       // balanced: 4 x 104 steps over [0,416)
#define CHUNKT  104

// ---------------- workspace layout (float units), total 107.5 MiB ----------------
#define OFF_XN    ((size_t)0)            // 131072
#define OFF_MEAN  ((size_t)131072)       // 256
#define OFF_STD   ((size_t)131328)       // 256
#define OFF_WF    ((size_t)131584)       // 1024
#define OFF_WBX   ((size_t)132608)       // x_proj_w bf16: 32768 f
#define OFF_DPWB  ((size_t)165376)       // dt_proj_w bf16: 16384 f
#define OFF_XB    ((size_t)919040)       // 16384x512 bf16 = 4194304 f (ab overlays)
#define OFF_WB    ((size_t)5113344)      // 2048x512 bf16 = 524288 f
#define OFF_DTIN  ((size_t)5637632)      // dt_in bf16 = 262144 f (wfp overlays early)
#define OFF_BT    ((size_t)6161920)      // 32x16x512 fp32 = 262144 f
#define OFF_CT    ((size_t)6424064)      // 262144 f
#define OFF_GST   ((size_t)6686208)      // 32x1024x96 fp32 (g -> gw -> outputs in place)
#define OFF_XIT   ((size_t)9831936)      // [b][d][t] bf16 = 8388608 f (dtT overlays)
#define OFF_UT    ((size_t)18220544)     // [b][d][t] bf16 = 8388608 f
#define OFF_C0    ((size_t)26609152)     // 32x1024x96 bf16 = 1572864 f
#define OFF_DTT   OFF_XIT
#define OFF_AB    OFF_XB                 // 4194304 f exact fit
#define OFF_WFP   OFF_DTIN
// end: 28182016 floats = 107.5 MiB

typedef __bf16 bf16_8 __attribute__((ext_vector_type(8)));
typedef float  f32x4  __attribute__((ext_vector_type(4)));

#define EXP2F(x) __builtin_amdgcn_exp2f(x)
#define LOG2F(x) __builtin_amdgcn_logf(x)

typedef __attribute__((address_space(3))) unsigned lds_u32;
typedef const __attribute__((address_space(1))) unsigned glb_u32;
#define ASYNC_LDS16(gsrc, ldst) \
    __builtin_amdgcn_global_load_lds((glb_u32*)(gsrc), (lds_u32*)(ldst), 16, 0, 0)

static __device__ __forceinline__ float b2f(unsigned short h) {
    union { float f; unsigned u; } v; v.u = ((unsigned)h) << 16; return v.f;
}
static __device__ __forceinline__ unsigned short f2b(float f) {
    __hip_bfloat16 h = __float2bfloat16(f);   // RNE
    union { __hip_bfloat16 b; unsigned short s; } v; v.b = h; return v.s;
}
static __device__ __forceinline__ float blo(unsigned v) {
    union { float f; unsigned u; } x; x.u = v << 16; return x.f;
}
static __device__ __forceinline__ float bhi(unsigned v) {
    union { float f; unsigned u; } x; x.u = v & 0xffff0000u; return x.f;
}

// ============ k_front: fusew-partials | w2b x3 | norm ============
__global__ __launch_bounds__(256) void k_front(const float* __restrict__ opw,
                                               const float* __restrict__ ow,
                                               const float* __restrict__ in_proj_w,
                                               const float* __restrict__ x_proj_w,
                                               const float* __restrict__ dpw,
                                               const float* __restrict__ xe,
                                               float* __restrict__ wfp,
                                               unsigned short* __restrict__ wb,
                                               unsigned short* __restrict__ wbx,
                                               unsigned short* __restrict__ dpwb,
                                               float* __restrict__ xn,
                                               float* __restrict__ meanv,
                                               float* __restrict__ stdv) {
    int bid = blockIdx.x;
    int tid = threadIdx.x;
    if (bid < 16) {
        int q = bid >> 2;
        int i = (bid & 3) * 256 + tid;
        float acc = 0.f;
        for (int dd = q * 128; dd < q * 128 + 128; ++dd)
            acc += opw[(size_t)dd * DINNER + i] * ow[dd];
        wfp[(size_t)q * DINNER + i] = acc;
    } else if (bid < 1040) {
        int i = ((bid - 16) * 256 + tid) * 4;
        float4 v = *(const float4*)(in_proj_w + i);
        ushort4 o; o.x = f2b(v.x); o.y = f2b(v.y); o.z = f2b(v.z); o.w = f2b(v.w);
        *(ushort4*)(wb + i) = o;
    } else if (bid < 1104) {
        int i = ((bid - 1040) * 256 + tid) * 4;
        float4 v = *(const float4*)(x_proj_w + i);
        ushort4 o; o.x = f2b(v.x); o.y = f2b(v.y); o.z = f2b(v.z); o.w = f2b(v.w);
        *(ushort4*)(wbx + i) = o;
    } else if (bid < 1136) {
        int i = ((bid - 1104) * 256 + tid) * 4;
        float4 v = *(const float4*)(dpw + i);
        ushort4 o; o.x = f2b(v.x); o.y = f2b(v.y); o.z = f2b(v.z); o.w = f2b(v.w);
        *(ushort4*)(dpwb + i) = o;
    } else {
        int wv   = tid >> 6;
        int lane = tid & 63;
        int idx  = (bid - 1136) * 4 + wv;
        int c = idx & 7, b = idx >> 3;
        const float* p = xe + ((size_t)b * LSEQ) * ENC_IN + c;
        float vals[8];
        float s = 0.f, s2 = 0.f;
#pragma unroll
        for (int i = 0; i < 8; ++i) {
            float v = p[(size_t)(lane + i * 64) * ENC_IN];
            vals[i] = v; s += v; s2 += v * v;
        }
#pragma unroll
        for (int off = 32; off; off >>= 1) {
            s  += __shfl_xor(s,  off);
            s2 += __shfl_xor(s2, off);
        }
        float mean = s * (1.f / LSEQ);
        float var  = s2 * (1.f / LSEQ) - mean * mean;
        float sd   = sqrtf(var + 1e-5f);
        float rstd = 1.f / sd;
        if (lane == 0) { meanv[b * ENC_IN + c] = mean; stdv[b * ENC_IN + c] = sd; }
#pragma unroll
        for (int i = 0; i < 8; ++i)
            xn[((size_t)b * LSEQ + lane + i * 64) * ENC_IN + c] = (vals[i] - mean) * rstd;
    }
}

// ============ k_front2: build_x + fusew2 ============
__global__ __launch_bounds__(256) void k_front2(const float* __restrict__ xn,
                                                const float* __restrict__ xmark,
                                                const float* __restrict__ convw,
                                                const float* __restrict__ tempw,
                                                const float* __restrict__ wfp,
                                                unsigned short* __restrict__ xb,
                                                float* __restrict__ wfv) {
    int bid = blockIdx.x;
    int tid = threadIdx.x;
    if (bid >= 32768) {
        int i = (bid - 32768) * 256 + tid;
        wfv[i] = wfp[i] + wfp[DINNER + i] + wfp[2 * DINNER + i] + wfp[3 * DINNER + i];
        return;
    }
    int d = (bid & 1) * 256 + tid;
    int l = (bid >> 1) & (LSEQ - 1);
    int b = bid >> 10;
    int lm = (l + LSEQ - 1) & (LSEQ - 1);
    int lp = (l + 1) & (LSEQ - 1);
    const float* r0 = xn + ((size_t)b * LSEQ + lm) * ENC_IN;
    const float* r1 = xn + ((size_t)b * LSEQ + l ) * ENC_IN;
    const float* r2 = xn + ((size_t)b * LSEQ + lp) * ENC_IN;
    const float* w  = convw + (size_t)d * (ENC_IN * 3);
    float acc = 0.f;
#pragma unroll
    for (int i = 0; i < ENC_IN; ++i)
        acc += r0[i] * w[i * 3 + 0] + r1[i] * w[i * 3 + 1] + r2[i] * w[i * 3 + 2];
    const float* tw = tempw + (size_t)d * MARKD;
    const float* xm = xmark + ((size_t)b * LSEQ + l) * MARKD;
    acc += xm[0] * tw[0] + xm[1] * tw[1] + xm[2] * tw[2] + xm[3] * tw[3];
    float freq = __expf(-(float)(d & ~1) * (9.210340371976184f / (float)DMODEL));
    float rev  = (float)l * freq * 0.15915494309189535f;
    rev = rev - floorf(rev);
    acc += (d & 1) ? __builtin_amdgcn_cosf(rev) : __builtin_amdgcn_sinf(rev);
    xb[((size_t)b * LSEQ + l) * DMODEL + d] = f2b(acc);
}

// ============ Kernel C: in_proj GEMM via bf16 MFMA (async LDS staging) ============
#define TP_STRIDE 136
__global__ __launch_bounds__(256) void k_gemm_inproj(const unsigned short* __restrict__ xb,
                                                     const unsigned short* __restrict__ wb,
                                                     unsigned short* __restrict__ xiT,
                                                     float* __restrict__ gsT) {
    int n0 = blockIdx.x * 128;
    int m0 = blockIdx.y * 128;
    if (n0 >= DINNER && (m0 & (LSEQ - 1)) != 384) return;

    __shared__ unsigned char smem[128 * TP_STRIDE * 2];
    uint4* As4 = (uint4*)smem;
    uint4* Bs4 = As4 + 512;
    unsigned short* T = (unsigned short*)smem;

    int tid  = threadIdx.x;
    int lane = tid & 63;
    int w    = tid >> 6;
    int wm   = (w & 1) * 64;
    int wn   = (w >> 1) * 64;
    f32x4 acc[4][4] = {};

    for (int k0 = 0; k0 < DMODEL; k0 += 32) {
#pragma unroll
        for (int hh = 0; hh < 2; ++hh) {
            int c  = tid + hh * 256;
            int im = c >> 6;
            int lc = c & 63;
            int r  = im * 16 + (lc & 15);
            int kq = lc >> 4;
            // dest: wave-uniform base + lane*16B (fragment order is lane-linear)
            ASYNC_LDS16(xb + (size_t)(m0 + r) * DMODEL + k0 + kq * 8,
                        As4 + (w * 64 + hh * 256));
            ASYNC_LDS16(wb + (size_t)(n0 + r) * DMODEL + k0 + kq * 8,
                        Bs4 + (w * 64 + hh * 256));
        }
        __syncthreads();
        bf16_8 af[4], bf[4];
#pragma unroll
        for (int i = 0; i < 4; ++i) {
            af[i] = ((const bf16_8*)As4)[((wm >> 4) + i) * 64 + lane];
            bf[i] = ((const bf16_8*)Bs4)[((wn >> 4) + i) * 64 + lane];
        }
#pragma unroll
        for (int i = 0; i < 4; ++i)
#pragma unroll
            for (int j = 0; j < 4; ++j)
                acc[i][j] = __builtin_amdgcn_mfma_f32_16x16x32_bf16(af[i], bf[j], acc[i][j], 0, 0, 0);
        __syncthreads();
    }

    int col  = lane & 15;
    int quad = lane >> 4;
    if (n0 < DINNER) {
#pragma unroll
        for (int i = 0; i < 4; ++i) {
#pragma unroll
            for (int j = 0; j < 4; ++j) {
                int nn = wn + j * 16 + col;
                int mm = wm + i * 16 + quad * 4;
                ushort4 o;
                o.x = f2b(acc[i][j][0]); o.y = f2b(acc[i][j][1]);
                o.z = f2b(acc[i][j][2]); o.w = f2b(acc[i][j][3]);
                *(ushort4*)&T[nn * TP_STRIDE + mm] = o;
            }
        }
        __syncthreads();
        int bI = m0 >> 9;
        int tglob = m0 & (LSEQ - 1);
#pragma unroll
        for (int it = 0; it < 8; ++it) {
            int c  = tid + it * 256;
            int nn = c >> 4;
            int tc = c & 15;
            uint4 v = *(const uint4*)&T[nn * TP_STRIDE + tc * 8];
            *(uint4*)(xiT + ((size_t)bI * DINNER + n0 + nn) * LSEQ + tglob + tc * 8) = v;
        }
    } else {
#pragma unroll
        for (int i = 0; i < 4; ++i) {
#pragma unroll
            for (int j = 0; j < 4; ++j) {
                int m = m0 + wm + i * 16 + quad * 4;
                int t = m & (LSEQ - 1);
                if (t < TSTART) continue;
                int b = m >> 9;
                int nz = n0 - DINNER + wn + j * 16 + col;
                float4 g;
                float v0 = acc[i][j][0], v1 = acc[i][j][1], v2 = acc[i][j][2], v3 = acc[i][j][3];
                g.x = v0 / (1.f + __expf(-v0));
                g.y = v1 / (1.f + __expf(-v1));
                g.z = v2 / (1.f + __expf(-v2));
                g.w = v3 / (1.f + __expf(-v3));
                *(float4*)(gsT + ((size_t)b * DINNER + nz) * PREDLEN + (t - TSTART)) = g;
            }
        }
    }
}

// ============ Kernel D: depthwise conv + silu; gw=g*wf in place; c0=u*D*g*wf ============
__global__ __launch_bounds__(256) void k_dwconv_silu(const unsigned short* __restrict__ xiT,
                                                     const float* __restrict__ cw,
                                                     const float* __restrict__ cb,
                                                     const float* __restrict__ wfv,
                                                     const float* __restrict__ Dvec,
                                                     float* __restrict__ gsT,
                                                     unsigned short* __restrict__ c0,
                                                     unsigned short* __restrict__ uT) {
    int lane = threadIdx.x & 63;
    int w    = threadIdx.x >> 6;
    int d = blockIdx.x * 4 + w;
    int b = blockIdx.y;
    const unsigned short* src = xiT + ((size_t)b * DINNER + d) * LSEQ;
    uint4 cur = *(const uint4*)(src + lane * 8);
    unsigned pw = (unsigned)__shfl_up((int)cur.w, 1);
    unsigned pz = (unsigned)__shfl_up((int)cur.z, 1);
    if (lane == 0) { pw = 0u; pz = 0u; }
    float4 w4 = *(const float4*)(cw + (size_t)d * 4);
    float bias = cb[d];
    float win[11];
    win[0] = bhi(pz); win[1] = blo(pw); win[2] = bhi(pw);
    const unsigned* cp = (const unsigned*)&cur;
#pragma unroll
    for (int q = 0; q < 4; ++q) {
        win[3 + 2 * q] = blo(cp[q]);
        win[4 + 2 * q] = bhi(cp[q]);
    }
    float uvf[8];
    unsigned ov[4];
#pragma unroll
    for (int tt = 0; tt < 8; ++tt) {
        float a = bias + win[tt] * w4.x + win[tt + 1] * w4.y
                       + win[tt + 2] * w4.z + win[tt + 3] * w4.w;
        float uv = a / (1.f + __expf(-a));
        uvf[tt] = uv;
        unsigned short us = f2b(uv);
        if (tt & 1) ov[tt >> 1] |= ((unsigned)us) << 16;
        else        ov[tt >> 1]  = us;
    }
    *(uint4*)(uT + ((size_t)b * DINNER + d) * LSEQ + lane * 8) = *(uint4*)ov;
    if (lane >= 52) {
        int tl0 = lane * 8 - TSTART;
        float wfd = wfv[d];
        float Dd  = Dvec[d];
        float* gp = gsT + ((size_t)b * DINNER + d) * PREDLEN + tl0;
        float4 g0 = *(const float4*)gp;
        float4 g1 = *(const float4*)(gp + 4);
        float gg[8] = {g0.x, g0.y, g0.z, g0.w, g1.x, g1.y, g1.z, g1.w};
        unsigned cv[4];
#pragma unroll
        for (int j = 0; j < 8; ++j) {
            float gw = gg[j] * wfd;
            gg[j] = gw;
            unsigned short us = f2b(uvf[j] * Dd * gw);
            if (j & 1) cv[j >> 1] |= ((unsigned)us) << 16;
            else       cv[j >> 1]  = us;
        }
        *(float4*)gp       = make_float4(gg[0], gg[1], gg[2], gg[3]);
        *(float4*)(gp + 4) = make_float4(gg[4], gg[5], gg[6], gg[7]);
        *(uint4*)(c0 + ((size_t)b * DINNER + d) * PREDLEN + tl0) = *(uint4*)cv;
    }
}

// ============ Kernel E: x_proj GEMM via bf16 MFMA ============
#define XPS 66
__global__ __launch_bounds__(256) void k_gemm_xproj2(const unsigned short* __restrict__ uT,
                                                     const unsigned short* __restrict__ wbx,
                                                     unsigned short* __restrict__ dt_in,
                                                     float* __restrict__ Bt,
                                                     float* __restrict__ Ct) {
    __shared__ unsigned short Asl[32 * XPS];
    int tid  = threadIdx.x;
    int lane = tid & 63;
    int w    = tid >> 6;
    int quad = lane >> 4;
    int col  = lane & 15;
    int m0 = blockIdx.x * 64;
    int b  = m0 >> 9;
    int t0 = m0 & (LSEQ - 1);
    int sk  = tid >> 3;
    int smc = (tid & 7) * 8;
    f32x4 acc[4] = {};
    for (int k0 = 0; k0 < DINNER; k0 += 32) {
        uint4 v = *(const uint4*)(uT + ((size_t)b * DINNER + k0 + sk) * LSEQ + t0 + smc);
        unsigned* dst = (unsigned*)&Asl[sk * XPS + smc];
        dst[0] = v.x; dst[1] = v.y; dst[2] = v.z; dst[3] = v.w;
        __syncthreads();
        bf16_8 bf[4];
#pragma unroll
        for (int j = 0; j < 4; ++j)
            bf[j] = *((const bf16_8*)(wbx + (size_t)(j * 16 + col) * DINNER + k0 + quad * 8));
        union { bf16_8 v; unsigned short u[8]; } af;
#pragma unroll
        for (int j8 = 0; j8 < 8; ++j8)
            af.u[j8] = Asl[(quad * 8 + j8) * XPS + w * 16 + col];
#pragma unroll
        for (int j = 0; j < 4; ++j)
            acc[j] = __builtin_amdgcn_mfma_f32_16x16x32_bf16(af.v, bf[j], acc[j], 0, 0, 0);
        __syncthreads();
    }
    int mrow = m0 + w * 16 + quad * 4;
#pragma unroll
    for (int j = 0; j < 2; ++j)
#pragma unroll
        for (int r = 0; r < 4; ++r)
            dt_in[(size_t)(mrow + r) * DTRANK + j * 16 + col] = f2b(acc[j][r]);
    int t = t0 + w * 16 + quad * 4;
    *(float4*)(Bt + ((size_t)b * DSTATE + col) * LSEQ + t) =
        make_float4(acc[2][0], acc[2][1], acc[2][2], acc[2][3]);
    *(float4*)(Ct + ((size_t)b * DSTATE + col) * LSEQ + t) =
        make_float4(acc[3][0], acc[3][1], acc[3][2], acc[3][3]);
}

// ============ Kernel F: dt_proj as MFMA GEMM (K=32) + softplus + transpose store ============
__global__ __launch_bounds__(256) void k_dtproj2(const unsigned short* __restrict__ dt_in,
                                                 const unsigned short* __restrict__ dpwb,
                                                 const float* __restrict__ dpb,
                                                 unsigned short* __restrict__ dtT) {
    __shared__ unsigned char smem[128 * TP_STRIDE * 2];
    uint4* As4 = (uint4*)smem;
    uint4* Bs4 = As4 + 512;
    unsigned short* T = (unsigned short*)smem;
    int tid  = threadIdx.x;
    int lane = tid & 63;
    int w    = tid >> 6;
    int wm   = (w & 1) * 64;
    int wn   = (w >> 1) * 64;
    int n0 = blockIdx.x * 128;
    int m0 = blockIdx.y * 128;
#pragma unroll
    for (int hh = 0; hh < 2; ++hh) {
        int c  = tid + hh * 256;
        int im = c >> 6;
        int lc = c & 63;
        int r  = im * 16 + (lc & 15);
        int kq = lc >> 4;
        As4[c] = *(const uint4*)(dt_in + (size_t)(m0 + r) * DTRANK + kq * 8);
        Bs4[c] = *(const uint4*)(dpwb + (size_t)(n0 + r) * DTRANK + kq * 8);
    }
    __syncthreads();
    f32x4 acc[4][4] = {};
    bf16_8 af[4], bf[4];
#pragma unroll
    for (int i = 0; i < 4; ++i) {
        af[i] = ((const bf16_8*)As4)[((wm >> 4) + i) * 64 + lane];
        bf[i] = ((const bf16_8*)Bs4)[((wn >> 4) + i) * 64 + lane];
    }
#pragma unroll
    for (int i = 0; i < 4; ++i)
#pragma unroll
        for (int j = 0; j < 4; ++j)
            acc[i][j] = __builtin_amdgcn_mfma_f32_16x16x32_bf16(af[i], bf[j], acc[i][j], 0, 0, 0);
    __syncthreads();
    int col  = lane & 15;
    int quad = lane >> 4;
#pragma unroll
    for (int i = 0; i < 4; ++i) {
#pragma unroll
        for (int j = 0; j < 4; ++j) {
            int nn = wn + j * 16 + col;
            int mm = wm + i * 16 + quad * 4;
            float bias = dpb[n0 + nn];
            ushort4 o;
            unsigned short* op = (unsigned short*)&o;
#pragma unroll
            for (int r = 0; r < 4; ++r) {
                float a = acc[i][j][r] + bias;
                float sp = (a > 20.f) ? a
                         : 0.6931471805599453f * LOG2F(1.f + EXP2F(a * 1.44269504088896f));
                op[r] = f2b(sp);
            }
            *(ushort4*)&T[nn * TP_STRIDE + mm] = o;
        }
    }
    __syncthreads();
    int bI = m0 >> 9;
    int tglob = m0 & (LSEQ - 1);
#pragma unroll
    for (int it = 0; it < 8; ++it) {
        int c  = tid + it * 256;
        int nn = c >> 4;
        int tc = c & 15;
        uint4 v = *(const uint4*)&T[nn * TP_STRIDE + tc * 8];
        *(uint4*)(dtT + ((size_t)bI * DINNER + n0 + nn) * LSEQ + tglob + tc * 8) = v;
    }
}

// ============ Kernel G1: scan phase 1 — group-parallel exp form, balanced chunks ============
// beta over an 8-group: prefix sums S_j, G=S_7; term_j = exp2(As2*(G-S_j))*du_j*B_j
// (all independent); combine: beta = exp2(As2*G)*beta + sum(term).
__global__ __launch_bounds__(256) void k_scan_p1(const unsigned short* __restrict__ uT,
                                                 const unsigned short* __restrict__ dtT,
                                                 const float* __restrict__ Bt,
                                                 const float* __restrict__ A_log,
                                                 float2* __restrict__ ab) {
    int b = blockIdx.y;
    int c = blockIdx.z;
    int tid  = threadIdx.x;
    int lane = tid & 63;
    int w    = tid >> 6;
    int q    = lane & 3;
    int dloc = lane >> 2;
    int d    = blockIdx.x * 64 + w * 16 + dloc;
    float4 al = *(const float4*)(A_log + (size_t)d * DSTATE + q * 4);
    float As2[4];
    As2[0] = -__expf(al.x) * 1.44269504088896f;
    As2[1] = -__expf(al.y) * 1.44269504088896f;
    As2[2] = -__expf(al.z) * 1.44269504088896f;
    As2[3] = -__expf(al.w) * 1.44269504088896f;
    float beta[4] = {0.f, 0.f, 0.f, 0.f};
    float asum = 0.f;
    const unsigned short* up = uT  + ((size_t)b * DINNER + d) * LSEQ;
    const unsigned short* dp = dtT + ((size_t)b * DINNER + d) * LSEQ;
    const float* Bp = Bt + ((size_t)b * DSTATE + q * 4) * LSEQ;
    int tbeg = c * CHUNKT;
    for (int t8 = tbeg; t8 < tbeg + CHUNKT; t8 += 8) {
        uint4 uq = *(const uint4*)(up + t8);
        uint4 dq = *(const uint4*)(dp + t8);
        float uu[8], dd[8];
        const unsigned* uqp = (const unsigned*)&uq;
        const unsigned* dqp = (const unsigned*)&dq;
#pragma unroll
        for (int p = 0; p < 4; ++p) {
            uu[p * 2] = blo(uqp[p]); uu[p * 2 + 1] = bhi(uqp[p]);
            dd[p * 2] = blo(dqp[p]); dd[p * 2 + 1] = bhi(dqp[p]);
        }
        float S[8];
        S[0] = dd[0];
#pragma unroll
        for (int j = 1; j < 8; ++j) S[j] = S[j - 1] + dd[j];
        float G = S[7];
        float w8[8], p8[8];
#pragma unroll
        for (int j = 0; j < 8; ++j) {
            w8[j] = dd[j] * uu[j];
            p8[j] = G - S[j];          // >= 0
        }
        float4 B00 = *(const float4*)(Bp + 0 * LSEQ + t8);
        float4 B01 = *(const float4*)(Bp + 0 * LSEQ + t8 + 4);
        float4 B10 = *(const float4*)(Bp + 1 * LSEQ + t8);
        float4 B11 = *(const float4*)(Bp + 1 * LSEQ + t8 + 4);
        float4 B20 = *(const float4*)(Bp + 2 * LSEQ + t8);
        float4 B21 = *(const float4*)(Bp + 2 * LSEQ + t8 + 4);
        float4 B30 = *(const float4*)(Bp + 3 * LSEQ + t8);
        float4 B31 = *(const float4*)(Bp + 3 * LSEQ + t8 + 4);
        float Bv0[8] = {B00.x, B00.y, B00.z, B00.w, B01.x, B01.y, B01.z, B01.w};
        float Bv1[8] = {B10.x, B10.y, B10.z, B10.w, B11.x, B11.y, B11.z, B11.w};
        float Bv2[8] = {B20.x, B20.y, B20.z, B20.w, B21.x, B21.y, B21.z, B21.w};
        float Bv3[8] = {B30.x, B30.y, B30.z, B30.w, B31.x, B31.y, B31.z, B31.w};
        float g0 = 0.f, g1 = 0.f, g2 = 0.f, g3 = 0.f;
#pragma unroll
        for (int j = 0; j < 8; ++j) {
            // 4 independent exp2 per j; no serial dependence within the group
            g0 += EXP2F(As2[0] * p8[j]) * (w8[j] * Bv0[j]);
            g1 += EXP2F(As2[1] * p8[j]) * (w8[j] * Bv1[j]);
            g2 += EXP2F(As2[2] * p8[j]) * (w8[j] * Bv2[j]);
            g3 += EXP2F(As2[3] * p8[j]) * (w8[j] * Bv3[j]);
        }
        beta[0] = EXP2F(As2[0] * G) * beta[0] + g0;
        beta[1] = EXP2F(As2[1] * G) * beta[1] + g1;
        beta[2] = EXP2F(As2[2] * G) * beta[2] + g2;
        beta[3] = EXP2F(As2[3] * G) * beta[3] + g3;
        asum += G;
    }
    float2* abp = ab + ((size_t)(b * DINNER + d) * NCHUNK + c) * DSTATE + q * 4;
#pragma unroll
    for (int si = 0; si < 4; ++si)
        abp[si] = make_float2(EXP2F(asum * As2[si]), beta[si]);
}

// ============ Kernel G2: stitch h(416), run [416,512), batched reduce, in-place out ============
__global__ __launch_bounds__(256) void k_scan_p3(const unsigned short* __restrict__ uT,
                                                 const unsigned short* __restrict__ dtT,
                                                 const float* __restrict__ Bt,
                                                 const float* __restrict__ Ct,
                                                 const float* __restrict__ A_log,
                                                 float* __restrict__ gsT,
                                                 const unsigned short* __restrict__ c0,
                                                 const float2* __restrict__ ab) {
    int b    = blockIdx.y;
    int tid  = threadIdx.x;
    int s    = tid & 15;
    int dloc = tid >> 4;
    int d    = blockIdx.x * 16 + dloc;
    float As2 = -__expf(A_log[(size_t)d * DSTATE + s]) * 1.44269504088896f;
    const float2* abp = ab + (size_t)(b * DINNER + d) * NCHUNK * DSTATE + s;
    float h = 0.f;
#pragma unroll
    for (int c = 0; c < NCHUNK; ++c) {
        float2 v = abp[c * DSTATE];
        h = v.y + v.x * h;
    }
    const unsigned short* up = uT  + ((size_t)b * DINNER + d) * LSEQ;
    const unsigned short* dp = dtT + ((size_t)b * DINNER + d) * LSEQ;
    const float* Bp = Bt + ((size_t)b * DSTATE + s) * LSEQ;
    const float* Cp = Ct + ((size_t)b * DSTATE + s) * LSEQ;
    float* gp = gsT + ((size_t)b * DINNER + d) * PREDLEN;
    const unsigned short* cp0 = c0 + ((size_t)b * DINNER + d) * PREDLEN;
    for (int t8 = TSTART; t8 < LSEQ; t8 += 8) {
        int tl0 = t8 - TSTART;
        uint4 uq = *(const uint4*)(up + t8);
        uint4 dq = *(const uint4*)(dp + t8);
        float4 B0 = *(const float4*)(Bp + t8);
        float4 B1 = *(const float4*)(Bp + t8 + 4);
        float4 C0 = *(const float4*)(Cp + t8);
        float4 C1 = *(const float4*)(Cp + t8 + 4);
        float4 g0 = *(const float4*)(gp + tl0);
        float4 g1 = *(const float4*)(gp + tl0 + 4);
        uint4 cq = *(const uint4*)(cp0 + tl0);
        float uu[8], dd[8];
        const unsigned* uqp = (const unsigned*)&uq;
        const unsigned* dqp = (const unsigned*)&dq;
#pragma unroll
        for (int p = 0; p < 4; ++p) {
            uu[p * 2] = blo(uqp[p]); uu[p * 2 + 1] = bhi(uqp[p]);
            dd[p * 2] = blo(dqp[p]); dd[p * 2 + 1] = bhi(dqp[p]);
        }
        float Bv[8] = {B0.x, B0.y, B0.z, B0.w, B1.x, B1.y, B1.z, B1.w};
        float Cv[8] = {C0.x, C0.y, C0.z, C0.w, C1.x, C1.y, C1.z, C1.w};
        float y[8];
#pragma unroll
        for (int j = 0; j < 8; ++j) {
            h = EXP2F(dd[j] * As2) * h + (dd[j] * uu[j]) * Bv[j];
            y[j] = h * Cv[j];
        }
#pragma unroll
        for (int j = 0; j < 8; ++j) y[j] += __shfl_xor(y[j], 1);
#pragma unroll
        for (int j = 0; j < 8; ++j) y[j] += __shfl_xor(y[j], 2);
#pragma unroll
        for (int j = 0; j < 8; ++j) y[j] += __shfl_xor(y[j], 4);
#pragma unroll
        for (int j = 0; j < 8; ++j) y[j] += __shfl_xor(y[j], 8);
        if (s < 8) {
            float gv[8] = {g0.x, g0.y, g0.z, g0.w, g1.x, g1.y, g1.z, g1.w};
            const unsigned* cqp = (const unsigned*)&cq;
            float cf = (s & 1) ? bhi(cqp[s >> 1]) : blo(cqp[s >> 1]);
            gp[tl0 + s] = y[s] * gv[s] + cf;
        }
    }
}

// ============ Kernel H: reduce 1024 per-d outputs + de-normalize ============
__global__ __launch_bounds__(256) void k_final2(const float* __restrict__ gsT,
                                                const float* __restrict__ meanv,
                                                const float* __restrict__ stdv,
                                                float* __restrict__ out) {
    int tl = blockIdx.x;
    int b  = blockIdx.y;
    int tid = threadIdx.x;
    const float* gp = gsT + (size_t)b * DINNER * PREDLEN + tl;
    float acc = 0.f;
#pragma unroll
    for (int k = 0; k < 4; ++k)
        acc += gp[(size_t)(tid + k * 256) * PREDLEN];
#pragma unroll
    for (int off = 32; off; off >>= 1) acc += __shfl_xor(acc, off);
    __shared__ float red[4];
    if ((tid & 63) == 0) red[tid >> 6] = acc;
    __syncthreads();
    if (tid == 0) {
        float tot = red[0] + red[1] + red[2] + red[3];
        out[b * PREDLEN + tl] = tot * stdv[b * ENC_IN] + meanv[b * ENC_IN];
    }
}

// ---------------- launch ----------------
extern "C" void kernel_launch(void* const* d_in, const int* in_sizes, int n_in,
                              void* d_out, int out_size, void* d_ws, size_t ws_size,
                              hipStream_t stream) {
    const float* x_enc     = (const float*)d_in[0];
    const float* x_mark    = (const float*)d_in[1];
    const float* conv_w    = (const float*)d_in[2];
    const float* temp_w    = (const float*)d_in[3];
    const float* in_proj_w = (const float*)d_in[4];
    const float* conv1d_w  = (const float*)d_in[5];
    const float* conv1d_b  = (const float*)d_in[6];
    const float* x_proj_w  = (const float*)d_in[7];
    const float* dt_proj_w = (const float*)d_in[8];
    const float* dt_proj_b = (const float*)d_in[9];
    const float* A_log     = (const float*)d_in[10];
    const float* Dvec      = (const float*)d_in[11];
    const float* out_proj_w= (const float*)d_in[12];
    const float* out_w     = (const float*)d_in[13];
    float* ws  = (float*)d_ws;
    float* out = (float*)d_out;

    float* xn    = ws + OFF_XN;
    float* meanv = ws + OFF_MEAN;
    float* stdv  = ws + OFF_STD;
    float* wfv   = ws + OFF_WF;
    float* wfp   = ws + OFF_WFP;
    float* Btv   = ws + OFF_BT;
    float* Ctv   = ws + OFF_CT;
    float* gsT   = ws + OFF_GST;
    unsigned short* xb    = (unsigned short*)(ws + OFF_XB);
    unsigned short* wb    = (unsigned short*)(ws + OFF_WB);
    unsigned short* wbx   = (unsigned short*)(ws + OFF_WBX);
    unsigned short* dpwb  = (unsigned short*)(ws + OFF_DPWB);
    unsigned short* dtinb = (unsigned short*)(ws + OFF_DTIN);
    unsigned short* xiT   = (unsigned short*)(ws + OFF_XIT);
    unsigned short* uT    = (unsigned short*)(ws + OFF_UT);
    unsigned short* dtT   = (unsigned short*)(ws + OFF_DTT);
    unsigned short* c0    = (unsigned short*)(ws + OFF_C0);
    float2* ab = (float2*)(ws + OFF_AB);

    k_front<<<dim3(1200), 256, 0, stream>>>(out_proj_w, out_w, in_proj_w, x_proj_w, dt_proj_w,
                                            x_enc, wfp, wb, wbx, dpwb, xn, meanv, stdv);
    k_front2<<<dim3(32772), 256, 0, stream>>>(xn, x_mark, conv_w, temp_w, wfp, xb, wfv);
    k_gemm_inproj<<<dim3(16, 128), 256, 0, stream>>>(xb, wb, xiT, gsT);
    k_dwconv_silu<<<dim3(DINNER / 4, BATCH), 256, 0, stream>>>(xiT, conv1d_w, conv1d_b,
                                                               wfv, Dvec, gsT, c0, uT);
    k_gemm_xproj2<<<dim3(MROWS / 64), 256, 0, stream>>>(uT, wbx, dtinb, Btv, Ctv);
    k_dtproj2<<<dim3(8, 128), 256, 0, stream>>>(dtinb, dpwb, dt_proj_b, dtT);
    k_scan_p1<<<dim3(DINNER / 64, BATCH, NCHUNK), 256, 0, stream>>>(uT, dtT, Btv, A_log, ab);
    k_scan_p3<<<dim3(DINNER / 16, BATCH), 256, 0, stream>>>(uT, dtT, Btv, Ctv, A_log,
                                                            gsT, c0, ab);
    k_final2<<<dim3(PREDLEN, BATCH), 256, 0, stream>>>(gsT, meanv, stdv, out);
}